// Round 1
// baseline (1007.867 us; speedup 1.0000x reference)
//
#include <hip/hip_runtime.h>
#include <math.h>

#define B_N   8
#define S_LEN 2048
#define D_DIM 512
#define M_TOT (B_N * S_LEN)   // 16384
#define WIN   30

typedef short bf16x8 __attribute__((ext_vector_type(8)));
typedef float f32x4  __attribute__((ext_vector_type(4)));
typedef unsigned short u16;
typedef unsigned int   u32;

__device__ __forceinline__ u16 f2bf(float f) {
    union { float f; u32 u; } v; v.f = f;
    u32 r = v.u + 0x7fffu + ((v.u >> 16) & 1u);
    return (u16)(r >> 16);
}
__device__ __forceinline__ float bf2f(u16 u) {
    union { u32 u; float f; } v; v.u = ((u32)u) << 16; return v.f;
}

__device__ __forceinline__ void gl2lds(const u16* g, u16* l) {
    __builtin_amdgcn_global_load_lds((const __attribute__((address_space(1))) void*)g,
                                     (__attribute__((address_space(3))) void*)l,
                                     16, 0, 0);
}

// ---------------- elementwise converts ----------------

__global__ __launch_bounds__(256) void convert_x(const float* __restrict__ X, u16* __restrict__ Xb) {
    size_t i = (size_t)blockIdx.x * 256 + threadIdx.x;
    float4 v = ((const float4*)X)[i];
    ushort4 o;
    o.x = f2bf(v.x); o.y = f2bf(v.y); o.z = f2bf(v.z); o.w = f2bf(v.w);
    ((ushort4*)Xb)[i] = o;
}

// Wt[n][k] = bf16(W[k][n]),  W is [512][512]
__global__ __launch_bounds__(256) void transpose_w(const float* __restrict__ W, u16* __restrict__ Wt) {
    __shared__ float t[32][33];
    int k0 = blockIdx.x * 32, n0 = blockIdx.y * 32;
    int tx = threadIdx.x & 31, ty = threadIdx.x >> 5;   // 32 x 8
#pragma unroll
    for (int r = ty; r < 32; r += 8) t[r][tx] = W[(size_t)(k0 + r) * D_DIM + n0 + tx];
    __syncthreads();
#pragma unroll
    for (int r = ty; r < 32; r += 8) Wt[(size_t)(n0 + r) * D_DIM + k0 + tx] = f2bf(t[tx][r]);
}

// gate[m] = sigmoid(X[m,:] . Wg + bg), one wave per row
__global__ __launch_bounds__(256) void gate_kernel(const float* __restrict__ X, const float* __restrict__ Wg,
                                                   const float* __restrict__ bg, float* __restrict__ gate) {
    int wave = threadIdx.x >> 6, lane = threadIdx.x & 63;
    int row = blockIdx.x * 4 + wave;
    const float4* x4 = (const float4*)(X + (size_t)row * D_DIM);
    const float4* w4 = (const float4*)Wg;
    float acc = 0.f;
#pragma unroll
    for (int j = 0; j < 2; j++) {
        float4 a = x4[lane * 2 + j], w = w4[lane * 2 + j];
        acc += a.x * w.x + a.y * w.y + a.z * w.z + a.w * w.w;
    }
#pragma unroll
    for (int o = 32; o; o >>= 1) acc += __shfl_xor(acc, o);
    if (lane == 0) gate[row] = 1.f / (1.f + __expf(-(acc + bg[0])));
}

// ---------------- the one GEMM: C = A * Bt^T ----------------
// A: bf16 [M][lda] (or f32 scores + exp-recompute when AEXP)
// Bt: bf16 [N][ldb]
// tile 128x128, BK=32, 4 waves (2x2), 16x16x32 bf16 MFMA, 4x4 frags/wave
// EPI 0: bf16 out + col bias | 1: bf16 out + row bias | 2: f32 out * scale
// EPI 3: f32 out += (1-gate[row]) * acc
template<int EPI, bool AEXP>
__global__ __launch_bounds__(256)
void gemm_bt(const u16* __restrict__ A, const float* __restrict__ Af,
             const u16* __restrict__ Bt, int lda, int ldb, int K,
             const float* __restrict__ stats, const float* __restrict__ bias,
             const float* __restrict__ gate, void* __restrict__ Cv, int ldc,
             float scale) {
    __shared__ u16 lA[128 * 32];
    __shared__ u16 lB[128 * 32];
    const int tid  = threadIdx.x;
    const int lane = tid & 63;
    const int wave = tid >> 6;
    const int wr = wave >> 1, wc = wave & 1;
    const int m0 = blockIdx.y * 128, n0 = blockIdx.x * 128;

    f32x4 acc[4][4];
#pragma unroll
    for (int i = 0; i < 4; i++)
#pragma unroll
        for (int j = 0; j < 4; j++) acc[i][j] = (f32x4){0.f, 0.f, 0.f, 0.f};

    // staging: 512 chunks of 16B; chunk c -> row c>>2, k-elems (c&3)*8
    const int c0 = tid, c1 = tid + 256;
    const int r0c = c0 >> 2, k0c = (c0 & 3) << 3;
    const int r1c = c1 >> 2, k1c = (c1 & 3) << 3;
    u16* lAw0 = lA + wave * 512;          // wave-uniform bases (lane*16B appended by HW)
    u16* lAw1 = lA + wave * 512 + 2048;
    u16* lBw0 = lB + wave * 512;
    u16* lBw1 = lB + wave * 512 + 2048;

    float stm0 = 0.f, sti0 = 0.f, stm1 = 0.f, sti1 = 0.f;
    if (AEXP) {
        stm0 = stats[2 * (m0 + r0c)];     sti0 = stats[2 * (m0 + r0c) + 1];
        stm1 = stats[2 * (m0 + r1c)];     sti1 = stats[2 * (m0 + r1c) + 1];
    }

    for (int k0 = 0; k0 < K; k0 += 32) {
        if (AEXP) {
            const float* s0 = Af + (size_t)(m0 + r0c) * lda + (k0 + k0c);
            const float* s1 = Af + (size_t)(m0 + r1c) * lda + (k0 + k1c);
            float4 va = ((const float4*)s0)[0];
            float4 vb = ((const float4*)s0)[1];
            float4 vc = ((const float4*)s1)[0];
            float4 vd = ((const float4*)s1)[1];
            uint4 p0, p1;
            p0.x = (u32)f2bf(__expf(va.x - stm0) * sti0) | ((u32)f2bf(__expf(va.y - stm0) * sti0) << 16);
            p0.y = (u32)f2bf(__expf(va.z - stm0) * sti0) | ((u32)f2bf(__expf(va.w - stm0) * sti0) << 16);
            p0.z = (u32)f2bf(__expf(vb.x - stm0) * sti0) | ((u32)f2bf(__expf(vb.y - stm0) * sti0) << 16);
            p0.w = (u32)f2bf(__expf(vb.z - stm0) * sti0) | ((u32)f2bf(__expf(vb.w - stm0) * sti0) << 16);
            p1.x = (u32)f2bf(__expf(vc.x - stm1) * sti1) | ((u32)f2bf(__expf(vc.y - stm1) * sti1) << 16);
            p1.y = (u32)f2bf(__expf(vc.z - stm1) * sti1) | ((u32)f2bf(__expf(vc.w - stm1) * sti1) << 16);
            p1.z = (u32)f2bf(__expf(vd.x - stm1) * sti1) | ((u32)f2bf(__expf(vd.y - stm1) * sti1) << 16);
            p1.w = (u32)f2bf(__expf(vd.z - stm1) * sti1) | ((u32)f2bf(__expf(vd.w - stm1) * sti1) << 16);
            ((uint4*)lA)[c0] = p0;
            ((uint4*)lA)[c1] = p1;
        } else {
            gl2lds(A + (size_t)(m0 + r0c) * lda + (k0 + k0c), lAw0);
            gl2lds(A + (size_t)(m0 + r1c) * lda + (k0 + k1c), lAw1);
        }
        gl2lds(Bt + (size_t)(n0 + r0c) * ldb + (k0 + k0c), lBw0);
        gl2lds(Bt + (size_t)(n0 + r1c) * ldb + (k0 + k1c), lBw1);
        __syncthreads();

        bf16x8 af[4], bfr[4];
#pragma unroll
        for (int m = 0; m < 4; m++)
            af[m] = *(const bf16x8*)&lA[(wr * 64 + m * 16 + (lane & 15)) * 32 + (lane >> 4) * 8];
#pragma unroll
        for (int n = 0; n < 4; n++)
            bfr[n] = *(const bf16x8*)&lB[(wc * 64 + n * 16 + (lane & 15)) * 32 + (lane >> 4) * 8];
#pragma unroll
        for (int m = 0; m < 4; m++)
#pragma unroll
            for (int n = 0; n < 4; n++)
                acc[m][n] = __builtin_amdgcn_mfma_f32_16x16x32_bf16(af[m], bfr[n], acc[m][n], 0, 0, 0);
        __syncthreads();
    }

    // epilogue: C/D map row=(lane>>4)*4+reg, col=lane&15  [verified m89]
#pragma unroll
    for (int m = 0; m < 4; m++) {
        int rbase = m0 + wr * 64 + m * 16 + ((lane >> 4) << 2);
#pragma unroll
        for (int n = 0; n < 4; n++) {
            int col = n0 + wc * 64 + n * 16 + (lane & 15);
#pragma unroll
            for (int rg = 0; rg < 4; rg++) {
                int row = rbase + rg;
                float v = acc[m][n][rg];
                if (EPI == 0) {
                    ((u16*)Cv)[(size_t)row * ldc + col] = f2bf(v + bias[col]);
                } else if (EPI == 1) {
                    ((u16*)Cv)[(size_t)row * ldc + col] = f2bf(v + bias[row]);
                } else if (EPI == 2) {
                    ((float*)Cv)[(size_t)row * ldc + col] = v * scale;
                } else {
                    float g = gate[row];
                    float* o = (float*)Cv + (size_t)row * ldc + col;
                    *o = *o + (1.f - g) * v;
                }
            }
        }
    }
}

// ---------------- softmax stats + local (banded) attention ----------------
// one block per query row i of one batch
__global__ __launch_bounds__(256)
void softmax_local(const float* __restrict__ sc, const u16* __restrict__ V,
                   const float* __restrict__ gate, float* __restrict__ stats,
                   float* __restrict__ outp) {
    const int i = blockIdx.x, tid = threadIdx.x;
    __shared__ float row[S_LEN];
    __shared__ float r0[4], r1[4], r2[4], r3[4];
    __shared__ float pl[64];

    const float4* s4 = (const float4*)(sc + (size_t)i * S_LEN);
    float4 a = s4[tid * 2], b = s4[tid * 2 + 1];
    ((float4*)row)[tid * 2] = a;
    ((float4*)row)[tid * 2 + 1] = b;

    float mx = fmaxf(fmaxf(fmaxf(a.x, a.y), fmaxf(a.z, a.w)),
                     fmaxf(fmaxf(b.x, b.y), fmaxf(b.z, b.w)));
#pragma unroll
    for (int o = 32; o; o >>= 1) mx = fmaxf(mx, __shfl_xor(mx, o));
    if ((tid & 63) == 0) r0[tid >> 6] = mx;
    __syncthreads();
    float mg = fmaxf(fmaxf(r0[0], r0[1]), fmaxf(r0[2], r0[3]));

    float se = __expf(a.x - mg) + __expf(a.y - mg) + __expf(a.z - mg) + __expf(a.w - mg)
             + __expf(b.x - mg) + __expf(b.y - mg) + __expf(b.z - mg) + __expf(b.w - mg);
#pragma unroll
    for (int o = 32; o; o >>= 1) se += __shfl_xor(se, o);
    if ((tid & 63) == 0) r1[tid >> 6] = se;
    __syncthreads();
    float lg = r1[0] + r1[1] + r1[2] + r1[3];
    if (tid == 0) { stats[2 * i] = mg; stats[2 * i + 1] = 1.f / lg; }

    // banded local softmax
    int jlo = i - WIN; if (jlo < 0) jlo = 0;
    int jhi = i + WIN; if (jhi > S_LEN - 1) jhi = S_LEN - 1;
    int cnt = jhi - jlo + 1;
    float bvv = (tid < cnt) ? row[jlo + tid] : -3.0e38f;
    float ml = bvv;
#pragma unroll
    for (int o = 32; o; o >>= 1) ml = fmaxf(ml, __shfl_xor(ml, o));
    if ((tid & 63) == 0) r2[tid >> 6] = ml;
    __syncthreads();
    ml = fmaxf(fmaxf(r2[0], r2[1]), fmaxf(r2[2], r2[3]));

    float e = (tid < cnt) ? __expf(bvv - ml) : 0.f;
    float s2 = e;
#pragma unroll
    for (int o = 32; o; o >>= 1) s2 += __shfl_xor(s2, o);
    if ((tid & 63) == 0) r3[tid >> 6] = s2;
    __syncthreads();
    float ll = r3[0] + r3[1] + r3[2] + r3[3];
    if (tid < cnt) pl[tid] = e / ll;
    __syncthreads();

    float g = gate[i];
    float acc0 = 0.f, acc1 = 0.f;
    for (int jj = 0; jj < cnt; jj++) {
        float p = pl[jj];
        const u16* vr = V + (size_t)(jlo + jj) * D_DIM;
        acc0 += p * bf2f(vr[tid]);
        acc1 += p * bf2f(vr[tid + 256]);
    }
    size_t ob = (size_t)i * D_DIM;
    outp[ob + tid]       = g * acc0;
    outp[ob + tid + 256] = g * acc1;
}

// ---------------- launch ----------------
extern "C" void kernel_launch(void* const* d_in, const int* in_sizes, int n_in,
                              void* d_out, int out_size, void* d_ws, size_t ws_size,
                              hipStream_t stream) {
    const float* X  = (const float*)d_in[0];
    const float* Wq = (const float*)d_in[1];
    const float* bq = (const float*)d_in[2];
    const float* Wk = (const float*)d_in[3];
    const float* bk = (const float*)d_in[4];
    const float* Wv = (const float*)d_in[5];
    const float* bv = (const float*)d_in[6];
    const float* Wg = (const float*)d_in[7];
    const float* bg = (const float*)d_in[8];
    float* out = (float*)d_out;

    char* p = (char*)d_ws;
    u16* Xb  = (u16*)p; p += (size_t)M_TOT * D_DIM * 2;
    u16* Wtq = (u16*)p; p += (size_t)D_DIM * D_DIM * 2;
    u16* Wtk = (u16*)p; p += (size_t)D_DIM * D_DIM * 2;
    u16* Wtv = (u16*)p; p += (size_t)D_DIM * D_DIM * 2;
    u16* Qb  = (u16*)p; p += (size_t)M_TOT * D_DIM * 2;
    u16* Kb  = (u16*)p; p += (size_t)M_TOT * D_DIM * 2;
    u16* Vb  = (u16*)p; p += (size_t)M_TOT * D_DIM * 2;
    u16* Vt  = (u16*)p; p += (size_t)M_TOT * D_DIM * 2;
    float* gate  = (float*)p; p += (size_t)M_TOT * 4;
    float* stats = (float*)p; p += (size_t)S_LEN * 2 * 4;
    float* scores = (float*)p; p += (size_t)S_LEN * S_LEN * 4;

    convert_x<<<dim3(M_TOT * D_DIM / 4 / 256), 256, 0, stream>>>(X, Xb);
    transpose_w<<<dim3(16, 16), 256, 0, stream>>>(Wq, Wtq);
    transpose_w<<<dim3(16, 16), 256, 0, stream>>>(Wk, Wtk);
    transpose_w<<<dim3(16, 16), 256, 0, stream>>>(Wv, Wtv);
    gate_kernel<<<dim3(M_TOT / 4), 256, 0, stream>>>(X, Wg, bg, gate);

    // Q/K/V projections: [16384 x 512] = Xb[16384x512] * Wt^T
    gemm_bt<0, false><<<dim3(4, 128), 256, 0, stream>>>(Xb, nullptr, Wtq, 512, 512, 512,
                                                        nullptr, bq, nullptr, Qb, 512, 1.f);
    gemm_bt<0, false><<<dim3(4, 128), 256, 0, stream>>>(Xb, nullptr, Wtk, 512, 512, 512,
                                                        nullptr, bk, nullptr, Kb, 512, 1.f);
    gemm_bt<0, false><<<dim3(4, 128), 256, 0, stream>>>(Xb, nullptr, Wtv, 512, 512, 512,
                                                        nullptr, bv, nullptr, Vb, 512, 1.f);
    // Vt[d][t_global] = (Wv^T X^T): A=Wtv[512x512], Bt=Xb[16384x512], row bias bv
    gemm_bt<1, false><<<dim3(128, 4), 256, 0, stream>>>(Wtv, nullptr, Xb, 512, 512, 512,
                                                        nullptr, bv, nullptr, Vt, M_TOT, 1.f);

    const float sc = 1.0f / sqrtf((float)D_DIM);
    for (int b = 0; b < B_N; b++) {
        const u16* Qb_b = Qb + (size_t)b * S_LEN * D_DIM;
        const u16* Kb_b = Kb + (size_t)b * S_LEN * D_DIM;
        const u16* Vb_b = Vb + (size_t)b * S_LEN * D_DIM;
        const u16* Vt_b = Vt + (size_t)b * S_LEN;          // column block of [512][16384]
        const float* gate_b = gate + (size_t)b * S_LEN;
        float* out_b = out + (size_t)b * S_LEN * D_DIM;

        // scores[s][t] = (Q.K^T)/sqrt(D), f32
        gemm_bt<2, false><<<dim3(16, 16), 256, 0, stream>>>(Qb_b, nullptr, Kb_b, 512, 512, 512,
                                                            nullptr, nullptr, nullptr, scores, S_LEN, sc);
        // global stats + banded local attention; writes d_out = g*local
        softmax_local<<<dim3(S_LEN), 256, 0, stream>>>(scores, Vb_b, gate_b, stats, out_b);
        // global PV: A = exp(scores-m)*invl (recomputed in staging), out += (1-g)*acc
        gemm_bt<3, true><<<dim3(4, 16), 256, 0, stream>>>(nullptr, scores, Vt_b, S_LEN, M_TOT, S_LEN,
                                                          stats, nullptr, gate_b, out_b, 512, 1.f);
    }
}

// Round 2
// 323.577 us; speedup vs baseline: 3.1148x; 3.1148x over previous
//
#include <hip/hip_runtime.h>
#include <math.h>

#define B_N   8
#define S_LEN 2048
#define D_DIM 512
#define M_TOT (B_N * S_LEN)   // 16384
#define WIN   30

typedef short bf16x8 __attribute__((ext_vector_type(8)));
typedef float f32x4  __attribute__((ext_vector_type(4)));
typedef unsigned short u16;
typedef unsigned int   u32;

__device__ __forceinline__ u16 f2bf(float f) {
    union { float f; u32 u; } v; v.f = f;
    u32 r = v.u + 0x7fffu + ((v.u >> 16) & 1u);
    return (u16)(r >> 16);
}
__device__ __forceinline__ float bf2f(u16 u) {
    union { u32 u; float f; } v; v.u = ((u32)u) << 16; return v.f;
}

__device__ __forceinline__ void gl2lds(const u16* g, u16* l) {
    __builtin_amdgcn_global_load_lds((const __attribute__((address_space(1))) void*)g,
                                     (__attribute__((address_space(3))) void*)l,
                                     16, 0, 0);
}

// ---------------- elementwise converts ----------------

__global__ __launch_bounds__(256) void convert_x(const float* __restrict__ X, u16* __restrict__ Xb) {
    size_t i = (size_t)blockIdx.x * 256 + threadIdx.x;
    float4 v = ((const float4*)X)[i];
    ushort4 o;
    o.x = f2bf(v.x); o.y = f2bf(v.y); o.z = f2bf(v.z); o.w = f2bf(v.w);
    ((ushort4*)Xb)[i] = o;
}

// Wt[n][k] = bf16(W[k][n]),  W is [512][512]
__global__ __launch_bounds__(256) void transpose_w(const float* __restrict__ W, u16* __restrict__ Wt) {
    __shared__ float t[32][33];
    int k0 = blockIdx.x * 32, n0 = blockIdx.y * 32;
    int tx = threadIdx.x & 31, ty = threadIdx.x >> 5;   // 32 x 8
#pragma unroll
    for (int r = ty; r < 32; r += 8) t[r][tx] = W[(size_t)(k0 + r) * D_DIM + n0 + tx];
    __syncthreads();
#pragma unroll
    for (int r = ty; r < 32; r += 8) Wt[(size_t)(n0 + r) * D_DIM + k0 + tx] = f2bf(t[tx][r]);
}

__global__ __launch_bounds__(256) void pack_bias(const float* __restrict__ bq, const float* __restrict__ bk,
                                                 const float* __restrict__ bv, float* __restrict__ b3) {
    int i = blockIdx.x * 256 + threadIdx.x;   // grid 2 -> i in [0,512)
    b3[i] = bq[i]; b3[512 + i] = bk[i]; b3[1024 + i] = bv[i];
}

// gate[m] = sigmoid(X[m,:] . Wg + bg), one wave per row
__global__ __launch_bounds__(256) void gate_kernel(const float* __restrict__ X, const float* __restrict__ Wg,
                                                   const float* __restrict__ bg, float* __restrict__ gate) {
    int wave = threadIdx.x >> 6, lane = threadIdx.x & 63;
    int row = blockIdx.x * 4 + wave;
    const float4* x4 = (const float4*)(X + (size_t)row * D_DIM);
    const float4* w4 = (const float4*)Wg;
    float acc = 0.f;
#pragma unroll
    for (int j = 0; j < 2; j++) {
        float4 a = x4[lane * 2 + j], w = w4[lane * 2 + j];
        acc += a.x * w.x + a.y * w.y + a.z * w.z + a.w * w.w;
    }
#pragma unroll
    for (int o = 32; o; o >>= 1) acc += __shfl_xor(acc, o);
    if (lane == 0) gate[row] = 1.f / (1.f + __expf(-(acc + bg[0])));
}

// ---------------- the one GEMM: C = A * Bt^T, batched over blockIdx.z ----------------
// A: bf16 [M][lda], Bt: bf16 [N][ldb]
// tile 128x128, BK=32, 4 waves (2x2), 16x16x32 bf16 MFMA, 4x4 frags/wave
// EPI 0: bf16 out + col bias(aux) | 1: bf16 out + row bias(aux) | 2: f32 out * scale
// EPI 3: f32 out += (1-aux[row]) * acc   (aux = gate)
template<int EPI>
__global__ __launch_bounds__(256)
void gemm_bt(const u16* __restrict__ A, const u16* __restrict__ Bt,
             int lda, int ldb, int K,
             const float* __restrict__ aux, void* __restrict__ Cv, int ldc, float scale,
             long long zA, long long zB, long long zC, long long zAux) {
    const int z = blockIdx.z;
    A   += zA * z;
    Bt  += zB * z;
    if (aux) aux += zAux * z;

    __shared__ u16 lA[128 * 32];
    __shared__ u16 lB[128 * 32];
    const int tid  = threadIdx.x;
    const int lane = tid & 63;
    const int wave = tid >> 6;
    const int wr = wave >> 1, wc = wave & 1;
    const int m0 = blockIdx.y * 128, n0 = blockIdx.x * 128;

    f32x4 acc[4][4];
#pragma unroll
    for (int i = 0; i < 4; i++)
#pragma unroll
        for (int j = 0; j < 4; j++) acc[i][j] = (f32x4){0.f, 0.f, 0.f, 0.f};

    // staging: 512 chunks of 16B; chunk c -> row c>>2, k-elems (c&3)*8
    const int c0 = tid, c1 = tid + 256;
    const int r0c = c0 >> 2, k0c = (c0 & 3) << 3;
    const int r1c = c1 >> 2, k1c = (c1 & 3) << 3;
    u16* lAw0 = lA + wave * 512;          // wave-uniform bases (lane*16B appended by HW)
    u16* lAw1 = lA + wave * 512 + 2048;
    u16* lBw0 = lB + wave * 512;
    u16* lBw1 = lB + wave * 512 + 2048;

    for (int k0 = 0; k0 < K; k0 += 32) {
        gl2lds(A + (size_t)(m0 + r0c) * lda + (k0 + k0c), lAw0);
        gl2lds(A + (size_t)(m0 + r1c) * lda + (k0 + k1c), lAw1);
        gl2lds(Bt + (size_t)(n0 + r0c) * ldb + (k0 + k0c), lBw0);
        gl2lds(Bt + (size_t)(n0 + r1c) * ldb + (k0 + k1c), lBw1);
        __syncthreads();

        bf16x8 af[4], bfr[4];
#pragma unroll
        for (int m = 0; m < 4; m++)
            af[m] = *(const bf16x8*)&lA[(wr * 64 + m * 16 + (lane & 15)) * 32 + (lane >> 4) * 8];
#pragma unroll
        for (int n = 0; n < 4; n++)
            bfr[n] = *(const bf16x8*)&lB[(wc * 64 + n * 16 + (lane & 15)) * 32 + (lane >> 4) * 8];
#pragma unroll
        for (int m = 0; m < 4; m++)
#pragma unroll
            for (int n = 0; n < 4; n++)
                acc[m][n] = __builtin_amdgcn_mfma_f32_16x16x32_bf16(af[m], bfr[n], acc[m][n], 0, 0, 0);
        __syncthreads();
    }

    u16*   Cb = (EPI <= 1) ? ((u16*)Cv + zC * z) : nullptr;
    float* Cf = (EPI >= 2) ? ((float*)Cv + zC * z) : nullptr;

    // epilogue: C/D map row=(lane>>4)*4+reg, col=lane&15  [verified m89]
#pragma unroll
    for (int m = 0; m < 4; m++) {
        int rbase = m0 + wr * 64 + m * 16 + ((lane >> 4) << 2);
#pragma unroll
        for (int n = 0; n < 4; n++) {
            int col = n0 + wc * 64 + n * 16 + (lane & 15);
#pragma unroll
            for (int rg = 0; rg < 4; rg++) {
                int row = rbase + rg;
                float v = acc[m][n][rg];
                if (EPI == 0) {
                    Cb[(size_t)row * ldc + col] = f2bf(v + aux[col]);
                } else if (EPI == 1) {
                    Cb[(size_t)row * ldc + col] = f2bf(v + aux[row]);
                } else if (EPI == 2) {
                    Cf[(size_t)row * ldc + col] = v * scale;
                } else {
                    float g = aux[row];
                    float* o = Cf + (size_t)row * ldc + col;
                    *o = *o + (1.f - g) * v;
                }
            }
        }
    }
}

// ---------------- softmax + banded local attention ----------------
// grid (S_LEN, gcnt). Reads f32 scores row, writes normalized P row as bf16 IN PLACE
// (first 4KB of the 8KB row), writes out = gate*local_out.
__global__ __launch_bounds__(256)
void softmax_local(float* __restrict__ sc, const u16* __restrict__ V,
                   const float* __restrict__ gate, float* __restrict__ outp) {
    const int i = blockIdx.x, tid = threadIdx.x;
    const int z = blockIdx.y;
    sc   += (size_t)z * S_LEN * S_LEN;
    V    += (size_t)z * S_LEN * D_DIM;
    gate += (size_t)z * S_LEN;
    outp += (size_t)z * S_LEN * D_DIM;

    __shared__ float row[S_LEN];
    __shared__ float r0[4], r1[4], r2[4], r3[4];
    __shared__ float pl[64];

    float* scrow = sc + (size_t)i * S_LEN;
    const float4* s4 = (const float4*)scrow;
    float4 a = s4[tid * 2], b = s4[tid * 2 + 1];
    ((float4*)row)[tid * 2] = a;
    ((float4*)row)[tid * 2 + 1] = b;

    float mx = fmaxf(fmaxf(fmaxf(a.x, a.y), fmaxf(a.z, a.w)),
                     fmaxf(fmaxf(b.x, b.y), fmaxf(b.z, b.w)));
#pragma unroll
    for (int o = 32; o; o >>= 1) mx = fmaxf(mx, __shfl_xor(mx, o));
    if ((tid & 63) == 0) r0[tid >> 6] = mx;
    __syncthreads();
    float mg = fmaxf(fmaxf(r0[0], r0[1]), fmaxf(r0[2], r0[3]));

    float e0 = __expf(a.x - mg), e1 = __expf(a.y - mg), e2 = __expf(a.z - mg), e3 = __expf(a.w - mg);
    float e4 = __expf(b.x - mg), e5 = __expf(b.y - mg), e6 = __expf(b.z - mg), e7 = __expf(b.w - mg);
    float se = e0 + e1 + e2 + e3 + e4 + e5 + e6 + e7;
#pragma unroll
    for (int o = 32; o; o >>= 1) se += __shfl_xor(se, o);
    if ((tid & 63) == 0) r1[tid >> 6] = se;
    __syncthreads();
    float invl = 1.f / (r1[0] + r1[1] + r1[2] + r1[3]);

    // write normalized P (bf16) in place over the scores row
    uint4 pw;
    pw.x = (u32)f2bf(e0 * invl) | ((u32)f2bf(e1 * invl) << 16);
    pw.y = (u32)f2bf(e2 * invl) | ((u32)f2bf(e3 * invl) << 16);
    pw.z = (u32)f2bf(e4 * invl) | ((u32)f2bf(e5 * invl) << 16);
    pw.w = (u32)f2bf(e6 * invl) | ((u32)f2bf(e7 * invl) << 16);
    ((uint4*)scrow)[tid] = pw;   // safe: all row loads complete before first __syncthreads

    // banded local softmax
    int jlo = i - WIN; if (jlo < 0) jlo = 0;
    int jhi = i + WIN; if (jhi > S_LEN - 1) jhi = S_LEN - 1;
    int cnt = jhi - jlo + 1;
    float bvv = (tid < cnt) ? row[jlo + tid] : -3.0e38f;
    float ml = bvv;
#pragma unroll
    for (int o = 32; o; o >>= 1) ml = fmaxf(ml, __shfl_xor(ml, o));
    if ((tid & 63) == 0) r2[tid >> 6] = ml;
    __syncthreads();
    ml = fmaxf(fmaxf(r2[0], r2[1]), fmaxf(r2[2], r2[3]));

    float e = (tid < cnt) ? __expf(bvv - ml) : 0.f;
    float s2 = e;
#pragma unroll
    for (int o = 32; o; o >>= 1) s2 += __shfl_xor(s2, o);
    if ((tid & 63) == 0) r3[tid >> 6] = s2;
    __syncthreads();
    float ll = r3[0] + r3[1] + r3[2] + r3[3];
    if (tid < cnt) pl[tid] = e / ll;
    __syncthreads();

    float g = gate[i];
    float acc0 = 0.f, acc1 = 0.f;
    for (int jj = 0; jj < cnt; jj++) {
        float p = pl[jj];
        const u16* vr = V + (size_t)(jlo + jj) * D_DIM;
        acc0 += p * bf2f(vr[tid]);
        acc1 += p * bf2f(vr[tid + 256]);
    }
    size_t ob = (size_t)i * D_DIM;
    outp[ob + tid]       = g * acc0;
    outp[ob + tid + 256] = g * acc1;
}

// ---------------- launch ----------------
extern "C" void kernel_launch(void* const* d_in, const int* in_sizes, int n_in,
                              void* d_out, int out_size, void* d_ws, size_t ws_size,
                              hipStream_t stream) {
    const float* X  = (const float*)d_in[0];
    const float* Wq = (const float*)d_in[1];
    const float* bq = (const float*)d_in[2];
    const float* Wk = (const float*)d_in[3];
    const float* bk = (const float*)d_in[4];
    const float* Wv = (const float*)d_in[5];
    const float* bv = (const float*)d_in[6];
    const float* Wg = (const float*)d_in[7];
    const float* bg = (const float*)d_in[8];
    float* out = (float*)d_out;

    char* p = (char*)d_ws;
    u16* Xb    = (u16*)p;  p += (size_t)M_TOT * D_DIM * 2;           // 16 MB
    u16* Wt3   = (u16*)p;  p += (size_t)3 * D_DIM * D_DIM * 2;       // 1.5 MB
    u16* QKV   = (u16*)p;  p += (size_t)3 * M_TOT * D_DIM * 2;       // 48 MB
    u16* Vt    = (u16*)p;  p += (size_t)M_TOT * D_DIM * 2;           // 16 MB
    float* gate  = (float*)p; p += (size_t)M_TOT * 4;                // 64 KB
    float* bias3 = (float*)p; p += (size_t)3 * D_DIM * 4;            // 6 KB
    float* scores = (float*)p;                                       // nbuf * 16 MB
    size_t base_used = (size_t)(p - (char*)d_ws);
    size_t per_batch = (size_t)S_LEN * S_LEN * 4;
    int nbuf = (int)((ws_size - base_used) / per_batch);
    if (nbuf > B_N) nbuf = B_N;
    if (nbuf < 1) nbuf = 1;

    u16* Qb = QKV;
    u16* Kb = QKV + (size_t)M_TOT * D_DIM;
    u16* Vb = QKV + (size_t)2 * M_TOT * D_DIM;

    convert_x<<<dim3(M_TOT * D_DIM / 4 / 256), 256, 0, stream>>>(X, Xb);
    transpose_w<<<dim3(16, 16), 256, 0, stream>>>(Wq, Wt3);
    transpose_w<<<dim3(16, 16), 256, 0, stream>>>(Wk, Wt3 + (size_t)D_DIM * D_DIM);
    transpose_w<<<dim3(16, 16), 256, 0, stream>>>(Wv, Wt3 + (size_t)2 * D_DIM * D_DIM);
    pack_bias<<<dim3(2), 256, 0, stream>>>(bq, bk, bv, bias3);
    gate_kernel<<<dim3(M_TOT / 4), 256, 0, stream>>>(X, Wg, bg, gate);

    // Q/K/V projections in one dispatch: z selects weight/bias/output
    gemm_bt<0><<<dim3(4, 128, 3), 256, 0, stream>>>(
        Xb, Wt3, 512, 512, 512, bias3, QKV, 512, 1.f,
        0LL, (long long)D_DIM * D_DIM, (long long)M_TOT * D_DIM, (long long)D_DIM);

    // Vt[d][t_global] = (Wv^T X^T) + bv[d]
    gemm_bt<1><<<dim3(128, 4, 1), 256, 0, stream>>>(
        Wt3 + (size_t)2 * D_DIM * D_DIM, Xb, 512, 512, 512, bv, Vt, M_TOT, 1.f,
        0LL, 0LL, 0LL, 0LL);

    const float sc = 1.0f / sqrtf((float)D_DIM);
    for (int g0 = 0; g0 < B_N; g0 += nbuf) {
        int gcnt = B_N - g0 < nbuf ? B_N - g0 : nbuf;
        // scores[z][s][t] = (Q.K^T)/sqrt(D), f32
        gemm_bt<2><<<dim3(16, 16, gcnt), 256, 0, stream>>>(
            Qb + (size_t)g0 * S_LEN * D_DIM, Kb + (size_t)g0 * S_LEN * D_DIM,
            512, 512, 512, nullptr, scores, S_LEN, sc,
            (long long)S_LEN * D_DIM, (long long)S_LEN * D_DIM,
            (long long)S_LEN * S_LEN, 0LL);
        // softmax: writes bf16 P in place + d_out = g*local
        softmax_local<<<dim3(S_LEN, gcnt), 256, 0, stream>>>(
            scores, Vb + (size_t)g0 * S_LEN * D_DIM, gate + (size_t)g0 * S_LEN,
            out + (size_t)g0 * S_LEN * D_DIM);
        // global PV: plain bf16 GEMM on P (lda counts u16 within the f32 rows)
        gemm_bt<3><<<dim3(4, 16, gcnt), 256, 0, stream>>>(
            (const u16*)scores, Vt + (size_t)g0 * S_LEN,
            2 * S_LEN, M_TOT, S_LEN, gate + (size_t)g0 * S_LEN,
            out + (size_t)g0 * S_LEN * D_DIM, 512, 1.f,
            (long long)S_LEN * 2 * S_LEN, (long long)S_LEN,
            (long long)S_LEN * D_DIM, (long long)S_LEN);
    }
}

// Round 3
// 299.797 us; speedup vs baseline: 3.3618x; 1.0793x over previous
//
#include <hip/hip_runtime.h>
#include <math.h>

#define B_N   8
#define S_LEN 2048
#define D_DIM 512
#define M_TOT (B_N * S_LEN)   // 16384
#define WIN   30

typedef short bf16x8 __attribute__((ext_vector_type(8)));
typedef float f32x4  __attribute__((ext_vector_type(4)));
typedef unsigned short u16;
typedef unsigned int   u32;

__device__ __forceinline__ u16 f2bf(float f) {
    union { float f; u32 u; } v; v.f = f;
    u32 r = v.u + 0x7fffu + ((v.u >> 16) & 1u);
    return (u16)(r >> 16);
}
__device__ __forceinline__ float bf2f(u16 u) {
    union { u32 u; float f; } v; v.u = ((u32)u) << 16; return v.f;
}

__device__ __forceinline__ void gl2lds(const u16* g, u16* l) {
    __builtin_amdgcn_global_load_lds((const __attribute__((address_space(1))) void*)g,
                                     (__attribute__((address_space(3))) void*)l,
                                     16, 0, 0);
}

// bijective chunked XCD swizzle: hw block hb -> logical index such that
// XCD (hb%8) owns one contiguous logical chunk. Requires gridDim.x % 8 == 0.
__device__ __forceinline__ int xcd_logical() {
    const int n = gridDim.x;
    const int hb = blockIdx.x;
    return (hb & 7) * (n >> 3) + (hb >> 3);
}

// ---------------- elementwise converts ----------------

__global__ __launch_bounds__(256) void convert_x(const float* __restrict__ X, u16* __restrict__ Xb) {
    size_t i = (size_t)blockIdx.x * 256 + threadIdx.x;
    float4 v = ((const float4*)X)[i];
    ushort4 o;
    o.x = f2bf(v.x); o.y = f2bf(v.y); o.z = f2bf(v.z); o.w = f2bf(v.w);
    ((ushort4*)Xb)[i] = o;
}

// Wt[n][k] = bf16(W[k][n]),  W is [512][512]
__global__ __launch_bounds__(256) void transpose_w(const float* __restrict__ W, u16* __restrict__ Wt) {
    __shared__ float t[32][33];
    int k0 = blockIdx.x * 32, n0 = blockIdx.y * 32;
    int tx = threadIdx.x & 31, ty = threadIdx.x >> 5;   // 32 x 8
#pragma unroll
    for (int r = ty; r < 32; r += 8) t[r][tx] = W[(size_t)(k0 + r) * D_DIM + n0 + tx];
    __syncthreads();
#pragma unroll
    for (int r = ty; r < 32; r += 8) Wt[(size_t)(n0 + r) * D_DIM + k0 + tx] = f2bf(t[tx][r]);
}

__global__ __launch_bounds__(256) void pack_bias(const float* __restrict__ bq, const float* __restrict__ bk,
                                                 const float* __restrict__ bv, float* __restrict__ b3) {
    int i = blockIdx.x * 256 + threadIdx.x;   // grid 2 -> i in [0,512)
    b3[i] = bq[i]; b3[512 + i] = bk[i]; b3[1024 + i] = bv[i];
}

// gate[m] = sigmoid(X[m,:] . Wg + bg), one wave per row
__global__ __launch_bounds__(256) void gate_kernel(const float* __restrict__ X, const float* __restrict__ Wg,
                                                   const float* __restrict__ bg, float* __restrict__ gate) {
    int wave = threadIdx.x >> 6, lane = threadIdx.x & 63;
    int row = blockIdx.x * 4 + wave;
    const float4* x4 = (const float4*)(X + (size_t)row * D_DIM);
    const float4* w4 = (const float4*)Wg;
    float acc = 0.f;
#pragma unroll
    for (int j = 0; j < 2; j++) {
        float4 a = x4[lane * 2 + j], w = w4[lane * 2 + j];
        acc += a.x * w.x + a.y * w.y + a.z * w.z + a.w * w.w;
    }
#pragma unroll
    for (int o = 32; o; o >>= 1) acc += __shfl_xor(acc, o);
    if (lane == 0) gate[row] = 1.f / (1.f + __expf(-(acc + bg[0])));
}

// ---------------- the one GEMM: C = A * Bt^T, 1D grid, XCD-swizzled ----------------
// logical = x + nx*y + nx*ny*z  (x fastest, z slowest -> one batch per XCD chunk)
// A: bf16 [M][lda], Bt: bf16 [N][ldb]
// tile 128x128, BK=32, 4 waves (2x2), 16x16x32 bf16 MFMA, 4x4 frags/wave
// EPI 0: bf16 out + col bias(aux) | 1: bf16 out + row bias(aux) | 2: f32 out * scale
// EPI 3: f32 out += (1-aux[row]) * acc   (aux = gate)
template<int EPI>
__global__ __launch_bounds__(256)
void gemm_bt(const u16* __restrict__ A, const u16* __restrict__ Bt,
             int lda, int ldb, int K, int nx, int ny,
             const float* __restrict__ aux, void* __restrict__ Cv, int ldc, float scale,
             long long zA, long long zB, long long zC, long long zAux) {
    const int logical = xcd_logical();
    const int x = logical % nx;
    const int t2 = logical / nx;
    const int y = t2 % ny;
    const int z = t2 / ny;

    A   += zA * z;
    Bt  += zB * z;
    if (aux) aux += zAux * z;

    __shared__ u16 lA[128 * 32];
    __shared__ u16 lB[128 * 32];
    const int tid  = threadIdx.x;
    const int lane = tid & 63;
    const int wave = tid >> 6;
    const int wr = wave >> 1, wc = wave & 1;
    const int m0 = y * 128, n0 = x * 128;

    f32x4 acc[4][4];
#pragma unroll
    for (int i = 0; i < 4; i++)
#pragma unroll
        for (int j = 0; j < 4; j++) acc[i][j] = (f32x4){0.f, 0.f, 0.f, 0.f};

    // staging: 512 chunks of 16B; chunk c -> row c>>2, k-elems (c&3)*8
    const int c0 = tid, c1 = tid + 256;
    const int r0c = c0 >> 2, k0c = (c0 & 3) << 3;
    const int r1c = c1 >> 2, k1c = (c1 & 3) << 3;
    u16* lAw0 = lA + wave * 512;          // wave-uniform bases (lane*16B appended by HW)
    u16* lAw1 = lA + wave * 512 + 2048;
    u16* lBw0 = lB + wave * 512;
    u16* lBw1 = lB + wave * 512 + 2048;

    for (int k0 = 0; k0 < K; k0 += 32) {
        gl2lds(A + (size_t)(m0 + r0c) * lda + (k0 + k0c), lAw0);
        gl2lds(A + (size_t)(m0 + r1c) * lda + (k0 + k1c), lAw1);
        gl2lds(Bt + (size_t)(n0 + r0c) * ldb + (k0 + k0c), lBw0);
        gl2lds(Bt + (size_t)(n0 + r1c) * ldb + (k0 + k1c), lBw1);
        __syncthreads();

        bf16x8 af[4], bfr[4];
#pragma unroll
        for (int m = 0; m < 4; m++)
            af[m] = *(const bf16x8*)&lA[(wr * 64 + m * 16 + (lane & 15)) * 32 + (lane >> 4) * 8];
#pragma unroll
        for (int n = 0; n < 4; n++)
            bfr[n] = *(const bf16x8*)&lB[(wc * 64 + n * 16 + (lane & 15)) * 32 + (lane >> 4) * 8];
#pragma unroll
        for (int m = 0; m < 4; m++)
#pragma unroll
            for (int n = 0; n < 4; n++)
                acc[m][n] = __builtin_amdgcn_mfma_f32_16x16x32_bf16(af[m], bfr[n], acc[m][n], 0, 0, 0);
        __syncthreads();
    }

    u16*   Cb = (EPI <= 1) ? ((u16*)Cv + zC * z) : nullptr;
    float* Cf = (EPI >= 2) ? ((float*)Cv + zC * z) : nullptr;

    // epilogue: C/D map row=(lane>>4)*4+reg, col=lane&15  [verified m89]
#pragma unroll
    for (int m = 0; m < 4; m++) {
        int rbase = m0 + wr * 64 + m * 16 + ((lane >> 4) << 2);
#pragma unroll
        for (int n = 0; n < 4; n++) {
            int col = n0 + wc * 64 + n * 16 + (lane & 15);
#pragma unroll
            for (int rg = 0; rg < 4; rg++) {
                int row = rbase + rg;
                float v = acc[m][n][rg];
                if (EPI == 0) {
                    Cb[(size_t)row * ldc + col] = f2bf(v + aux[col]);
                } else if (EPI == 1) {
                    Cb[(size_t)row * ldc + col] = f2bf(v + aux[row]);
                } else if (EPI == 2) {
                    Cf[(size_t)row * ldc + col] = v * scale;
                } else {
                    float g = aux[row];
                    float* o = Cf + (size_t)row * ldc + col;
                    *o = *o + (1.f - g) * v;
                }
            }
        }
    }
}

// ---------------- softmax + banded local attention ----------------
// 1D grid (S_LEN * gcnt), XCD-swizzled so each XCD owns one batch (V L2-resident).
// Reads f32 scores row, writes normalized P row as bf16 IN PLACE
// (first 4KB of the 8KB row), writes out = gate*local_out.
__global__ __launch_bounds__(256)
void softmax_local(float* __restrict__ sc, const u16* __restrict__ V,
                   const float* __restrict__ gate, float* __restrict__ outp) {
    const int logical = xcd_logical();
    const int i = logical & (S_LEN - 1);
    const int z = logical >> 11;
    const int tid = threadIdx.x;
    sc   += (size_t)z * S_LEN * S_LEN;
    V    += (size_t)z * S_LEN * D_DIM;
    gate += (size_t)z * S_LEN;
    outp += (size_t)z * S_LEN * D_DIM;

    __shared__ float row[S_LEN];
    __shared__ float r0[4], r1[4], r2[4], r3[4];
    __shared__ float pl[64];

    float* scrow = sc + (size_t)i * S_LEN;
    const float4* s4 = (const float4*)scrow;
    float4 a = s4[tid * 2], b = s4[tid * 2 + 1];
    ((float4*)row)[tid * 2] = a;
    ((float4*)row)[tid * 2 + 1] = b;

    float mx = fmaxf(fmaxf(fmaxf(a.x, a.y), fmaxf(a.z, a.w)),
                     fmaxf(fmaxf(b.x, b.y), fmaxf(b.z, b.w)));
#pragma unroll
    for (int o = 32; o; o >>= 1) mx = fmaxf(mx, __shfl_xor(mx, o));
    if ((tid & 63) == 0) r0[tid >> 6] = mx;
    __syncthreads();
    float mg = fmaxf(fmaxf(r0[0], r0[1]), fmaxf(r0[2], r0[3]));

    float e0 = __expf(a.x - mg), e1 = __expf(a.y - mg), e2 = __expf(a.z - mg), e3 = __expf(a.w - mg);
    float e4 = __expf(b.x - mg), e5 = __expf(b.y - mg), e6 = __expf(b.z - mg), e7 = __expf(b.w - mg);
    float se = e0 + e1 + e2 + e3 + e4 + e5 + e6 + e7;
#pragma unroll
    for (int o = 32; o; o >>= 1) se += __shfl_xor(se, o);
    if ((tid & 63) == 0) r1[tid >> 6] = se;
    __syncthreads();
    float invl = 1.f / (r1[0] + r1[1] + r1[2] + r1[3]);

    // write normalized P (bf16) in place over the scores row
    uint4 pw;
    pw.x = (u32)f2bf(e0 * invl) | ((u32)f2bf(e1 * invl) << 16);
    pw.y = (u32)f2bf(e2 * invl) | ((u32)f2bf(e3 * invl) << 16);
    pw.z = (u32)f2bf(e4 * invl) | ((u32)f2bf(e5 * invl) << 16);
    pw.w = (u32)f2bf(e6 * invl) | ((u32)f2bf(e7 * invl) << 16);
    ((uint4*)scrow)[tid] = pw;   // safe: all row loads complete before first __syncthreads

    // banded local softmax
    int jlo = i - WIN; if (jlo < 0) jlo = 0;
    int jhi = i + WIN; if (jhi > S_LEN - 1) jhi = S_LEN - 1;
    int cnt = jhi - jlo + 1;
    float bvv = (tid < cnt) ? row[jlo + tid] : -3.0e38f;
    float ml = bvv;
#pragma unroll
    for (int o = 32; o; o >>= 1) ml = fmaxf(ml, __shfl_xor(ml, o));
    if ((tid & 63) == 0) r2[tid >> 6] = ml;
    __syncthreads();
    ml = fmaxf(fmaxf(r2[0], r2[1]), fmaxf(r2[2], r2[3]));

    float e = (tid < cnt) ? __expf(bvv - ml) : 0.f;
    float s2 = e;
#pragma unroll
    for (int o = 32; o; o >>= 1) s2 += __shfl_xor(s2, o);
    if ((tid & 63) == 0) r3[tid >> 6] = s2;
    __syncthreads();
    float ll = r3[0] + r3[1] + r3[2] + r3[3];
    if (tid < cnt) pl[tid] = e / ll;
    __syncthreads();

    float g = gate[i];
    float acc0 = 0.f, acc1 = 0.f;
    for (int jj = 0; jj < cnt; jj++) {
        float p = pl[jj];
        const u16* vr = V + (size_t)(jlo + jj) * D_DIM;
        acc0 += p * bf2f(vr[tid]);
        acc1 += p * bf2f(vr[tid + 256]);
    }
    size_t ob = (size_t)i * D_DIM;
    outp[ob + tid]       = g * acc0;
    outp[ob + tid + 256] = g * acc1;
}

// ---------------- launch ----------------
extern "C" void kernel_launch(void* const* d_in, const int* in_sizes, int n_in,
                              void* d_out, int out_size, void* d_ws, size_t ws_size,
                              hipStream_t stream) {
    const float* X  = (const float*)d_in[0];
    const float* Wq = (const float*)d_in[1];
    const float* bq = (const float*)d_in[2];
    const float* Wk = (const float*)d_in[3];
    const float* bk = (const float*)d_in[4];
    const float* Wv = (const float*)d_in[5];
    const float* bv = (const float*)d_in[6];
    const float* Wg = (const float*)d_in[7];
    const float* bg = (const float*)d_in[8];
    float* out = (float*)d_out;

    char* p = (char*)d_ws;
    u16* Xb    = (u16*)p;  p += (size_t)M_TOT * D_DIM * 2;           // 16 MB
    u16* Wt3   = (u16*)p;  p += (size_t)3 * D_DIM * D_DIM * 2;       // 1.5 MB
    u16* QKV   = (u16*)p;  p += (size_t)3 * M_TOT * D_DIM * 2;       // 48 MB
    u16* Vt    = (u16*)p;  p += (size_t)M_TOT * D_DIM * 2;           // 16 MB
    float* gate  = (float*)p; p += (size_t)M_TOT * 4;                // 64 KB
    float* bias3 = (float*)p; p += (size_t)3 * D_DIM * 4;            // 6 KB
    float* scores = (float*)p;                                       // nbuf * 16 MB
    size_t base_used = (size_t)(p - (char*)d_ws);
    size_t per_batch = (size_t)S_LEN * S_LEN * 4;
    int nbuf = (int)((ws_size - base_used) / per_batch);
    if (nbuf > B_N) nbuf = B_N;
    if (nbuf < 1) nbuf = 1;

    u16* Qb = QKV;
    u16* Kb = QKV + (size_t)M_TOT * D_DIM;
    u16* Vb = QKV + (size_t)2 * M_TOT * D_DIM;

    convert_x<<<dim3(M_TOT * D_DIM / 4 / 256), 256, 0, stream>>>(X, Xb);
    transpose_w<<<dim3(16, 16), 256, 0, stream>>>(Wq, Wt3);
    transpose_w<<<dim3(16, 16), 256, 0, stream>>>(Wk, Wt3 + (size_t)D_DIM * D_DIM);
    transpose_w<<<dim3(16, 16), 256, 0, stream>>>(Wv, Wt3 + (size_t)2 * D_DIM * D_DIM);
    pack_bias<<<dim3(2), 256, 0, stream>>>(bq, bk, bv, bias3);
    gate_kernel<<<dim3(M_TOT / 4), 256, 0, stream>>>(X, Wg, bg, gate);

    // Q/K/V projections in one dispatch: z selects weight/bias/output (1536 blocks)
    gemm_bt<0><<<dim3(4 * 128 * 3), 256, 0, stream>>>(
        Xb, Wt3, 512, 512, 512, 4, 128, bias3, QKV, 512, 1.f,
        0LL, (long long)D_DIM * D_DIM, (long long)M_TOT * D_DIM, (long long)D_DIM);

    // Vt[d][t_global] = (Wv^T X^T) + bv[d]   (512 blocks)
    gemm_bt<1><<<dim3(128 * 4), 256, 0, stream>>>(
        Wt3 + (size_t)2 * D_DIM * D_DIM, Xb, 512, 512, 512, 128, 4, bv, Vt, M_TOT, 1.f,
        0LL, 0LL, 0LL, 0LL);

    const float sc = 1.0f / sqrtf((float)D_DIM);
    for (int g0 = 0; g0 < B_N; g0 += nbuf) {
        int gcnt = B_N - g0 < nbuf ? B_N - g0 : nbuf;
        // scores[z][s][t] = (Q.K^T)/sqrt(D), f32  (256 blocks/batch -> one XCD each)
        gemm_bt<2><<<dim3(16 * 16 * gcnt), 256, 0, stream>>>(
            Qb + (size_t)g0 * S_LEN * D_DIM, Kb + (size_t)g0 * S_LEN * D_DIM,
            512, 512, 512, 16, 16, nullptr, scores, S_LEN, sc,
            (long long)S_LEN * D_DIM, (long long)S_LEN * D_DIM,
            (long long)S_LEN * S_LEN, 0LL);
        // softmax: writes bf16 P in place + d_out = g*local (2048 blocks/batch -> one XCD)
        softmax_local<<<dim3(S_LEN * gcnt), 256, 0, stream>>>(
            scores, Vb + (size_t)g0 * S_LEN * D_DIM, gate + (size_t)g0 * S_LEN,
            out + (size_t)g0 * S_LEN * D_DIM);
        // global PV: plain bf16 GEMM on P (lda counts u16 within the f32 rows)
        // (64 blocks/batch -> one XCD; Vt panel 2MB/batch L2-resident)
        gemm_bt<3><<<dim3(4 * 16 * gcnt), 256, 0, stream>>>(
            (const u16*)scores, Vt + (size_t)g0 * S_LEN,
            2 * S_LEN, M_TOT, S_LEN, 4, 16, gate + (size_t)g0 * S_LEN,
            out + (size_t)g0 * S_LEN * D_DIM, 512, 1.f,
            (long long)S_LEN * 2 * S_LEN, (long long)S_LEN,
            (long long)S_LEN * D_DIM, (long long)S_LEN);
    }
}

// Round 4
// 290.603 us; speedup vs baseline: 3.4682x; 1.0316x over previous
//
#include <hip/hip_runtime.h>
#include <math.h>

#define B_N   8
#define S_LEN 2048
#define D_DIM 512
#define M_TOT (B_N * S_LEN)   // 16384
#define WIN   30

typedef short bf16x8 __attribute__((ext_vector_type(8)));
typedef float f32x4  __attribute__((ext_vector_type(4)));
typedef unsigned short u16;
typedef unsigned int   u32;

__device__ __forceinline__ u16 f2bf(float f) {
    union { float f; u32 u; } v; v.f = f;
    u32 r = v.u + 0x7fffu + ((v.u >> 16) & 1u);
    return (u16)(r >> 16);
}
__device__ __forceinline__ float bf2f(u16 u) {
    union { u32 u; float f; } v; v.u = ((u32)u) << 16; return v.f;
}
__device__ __forceinline__ float bf_lo(u32 p) {   // low bf16 of packed u32
    union { u32 u; float f; } v; v.u = p << 16; return v.f;
}
__device__ __forceinline__ float bf_hi(u32 p) {   // high bf16 of packed u32
    union { u32 u; float f; } v; v.u = p & 0xffff0000u; return v.f;
}

__device__ __forceinline__ void gl2lds(const u16* g, u16* l) {
    __builtin_amdgcn_global_load_lds((const __attribute__((address_space(1))) void*)g,
                                     (__attribute__((address_space(3))) void*)l,
                                     16, 0, 0);
}

// bijective chunked XCD swizzle: hw block hb -> logical index such that
// XCD (hb%8) owns one contiguous logical chunk. Requires gridDim.x % 8 == 0.
__device__ __forceinline__ int xcd_logical() {
    const int n = gridDim.x;
    const int hb = blockIdx.x;
    return (hb & 7) * (n >> 3) + (hb >> 3);
}

// ---------------- elementwise converts ----------------

__global__ __launch_bounds__(256) void convert_x(const float* __restrict__ X, u16* __restrict__ Xb) {
    size_t i = (size_t)blockIdx.x * 256 + threadIdx.x;
    float4 v = ((const float4*)X)[i];
    ushort4 o;
    o.x = f2bf(v.x); o.y = f2bf(v.y); o.z = f2bf(v.z); o.w = f2bf(v.w);
    ((ushort4*)Xb)[i] = o;
}

// Wt[n][k] = bf16(W[k][n]),  W is [512][512]
__global__ __launch_bounds__(256) void transpose_w(const float* __restrict__ W, u16* __restrict__ Wt) {
    __shared__ float t[32][33];
    int k0 = blockIdx.x * 32, n0 = blockIdx.y * 32;
    int tx = threadIdx.x & 31, ty = threadIdx.x >> 5;   // 32 x 8
#pragma unroll
    for (int r = ty; r < 32; r += 8) t[r][tx] = W[(size_t)(k0 + r) * D_DIM + n0 + tx];
    __syncthreads();
#pragma unroll
    for (int r = ty; r < 32; r += 8) Wt[(size_t)(n0 + r) * D_DIM + k0 + tx] = f2bf(t[tx][r]);
}

__global__ __launch_bounds__(256) void pack_bias(const float* __restrict__ bq, const float* __restrict__ bk,
                                                 const float* __restrict__ bv, float* __restrict__ b3) {
    int i = blockIdx.x * 256 + threadIdx.x;   // grid 2 -> i in [0,512)
    b3[i] = bq[i]; b3[512 + i] = bk[i]; b3[1024 + i] = bv[i];
}

// gate[m] = sigmoid(X[m,:] . Wg + bg), one wave per row
__global__ __launch_bounds__(256) void gate_kernel(const float* __restrict__ X, const float* __restrict__ Wg,
                                                   const float* __restrict__ bg, float* __restrict__ gate) {
    int wave = threadIdx.x >> 6, lane = threadIdx.x & 63;
    int row = blockIdx.x * 4 + wave;
    const float4* x4 = (const float4*)(X + (size_t)row * D_DIM);
    const float4* w4 = (const float4*)Wg;
    float acc = 0.f;
#pragma unroll
    for (int j = 0; j < 2; j++) {
        float4 a = x4[lane * 2 + j], w = w4[lane * 2 + j];
        acc += a.x * w.x + a.y * w.y + a.z * w.z + a.w * w.w;
    }
#pragma unroll
    for (int o = 32; o; o >>= 1) acc += __shfl_xor(acc, o);
    if (lane == 0) gate[row] = 1.f / (1.f + __expf(-(acc + bg[0])));
}

// ---------------- the one GEMM: C = A * Bt^T, 1D grid, XCD-swizzled ----------------
// logical = x + nx*y + nx*ny*z  (x fastest, z slowest -> one batch per XCD chunk)
// A: bf16 [M][lda], Bt: bf16 [N][ldb]
// tile 128x128, BK=32, 4 waves (2x2), 16x16x32 bf16 MFMA, 4x4 frags/wave
// EPI 0: bf16 out + col bias(aux) | 1: bf16 out + row bias(aux) | 2: f32 out * scale
// EPI 3: f32 out += (1-aux[row]) * acc   (aux = gate)
template<int EPI>
__global__ __launch_bounds__(256)
void gemm_bt(const u16* __restrict__ A, const u16* __restrict__ Bt,
             int lda, int ldb, int K, int nx, int ny,
             const float* __restrict__ aux, void* __restrict__ Cv, int ldc, float scale,
             long long zA, long long zB, long long zC, long long zAux) {
    const int logical = xcd_logical();
    const int x = logical % nx;
    const int t2 = logical / nx;
    const int y = t2 % ny;
    const int z = t2 / ny;

    A   += zA * z;
    Bt  += zB * z;
    if (aux) aux += zAux * z;

    __shared__ u16 lA[128 * 32];
    __shared__ u16 lB[128 * 32];
    const int tid  = threadIdx.x;
    const int lane = tid & 63;
    const int wave = tid >> 6;
    const int wr = wave >> 1, wc = wave & 1;
    const int m0 = y * 128, n0 = x * 128;

    f32x4 acc[4][4];
#pragma unroll
    for (int i = 0; i < 4; i++)
#pragma unroll
        for (int j = 0; j < 4; j++) acc[i][j] = (f32x4){0.f, 0.f, 0.f, 0.f};

    // staging: 512 chunks of 16B; chunk c -> row c>>2, k-elems (c&3)*8
    const int c0 = tid, c1 = tid + 256;
    const int r0c = c0 >> 2, k0c = (c0 & 3) << 3;
    const int r1c = c1 >> 2, k1c = (c1 & 3) << 3;
    u16* lAw0 = lA + wave * 512;          // wave-uniform bases (lane*16B appended by HW)
    u16* lAw1 = lA + wave * 512 + 2048;
    u16* lBw0 = lB + wave * 512;
    u16* lBw1 = lB + wave * 512 + 2048;

    for (int k0 = 0; k0 < K; k0 += 32) {
        gl2lds(A + (size_t)(m0 + r0c) * lda + (k0 + k0c), lAw0);
        gl2lds(A + (size_t)(m0 + r1c) * lda + (k0 + k1c), lAw1);
        gl2lds(Bt + (size_t)(n0 + r0c) * ldb + (k0 + k0c), lBw0);
        gl2lds(Bt + (size_t)(n0 + r1c) * ldb + (k0 + k1c), lBw1);
        __syncthreads();

        bf16x8 af[4], bfr[4];
#pragma unroll
        for (int m = 0; m < 4; m++)
            af[m] = *(const bf16x8*)&lA[(wr * 64 + m * 16 + (lane & 15)) * 32 + (lane >> 4) * 8];
#pragma unroll
        for (int n = 0; n < 4; n++)
            bfr[n] = *(const bf16x8*)&lB[(wc * 64 + n * 16 + (lane & 15)) * 32 + (lane >> 4) * 8];
#pragma unroll
        for (int m = 0; m < 4; m++)
#pragma unroll
            for (int n = 0; n < 4; n++)
                acc[m][n] = __builtin_amdgcn_mfma_f32_16x16x32_bf16(af[m], bfr[n], acc[m][n], 0, 0, 0);
        __syncthreads();
    }

    u16*   Cb = (EPI <= 1) ? ((u16*)Cv + zC * z) : nullptr;
    float* Cf = (EPI >= 2) ? ((float*)Cv + zC * z) : nullptr;

    // epilogue: C/D map row=(lane>>4)*4+reg, col=lane&15  [verified m89]
#pragma unroll
    for (int m = 0; m < 4; m++) {
        int rbase = m0 + wr * 64 + m * 16 + ((lane >> 4) << 2);
#pragma unroll
        for (int n = 0; n < 4; n++) {
            int col = n0 + wc * 64 + n * 16 + (lane & 15);
#pragma unroll
            for (int rg = 0; rg < 4; rg++) {
                int row = rbase + rg;
                float v = acc[m][n][rg];
                if (EPI == 0) {
                    Cb[(size_t)row * ldc + col] = f2bf(v + aux[col]);
                } else if (EPI == 1) {
                    Cb[(size_t)row * ldc + col] = f2bf(v + aux[row]);
                } else if (EPI == 2) {
                    Cf[(size_t)row * ldc + col] = v * scale;
                } else {
                    float g = aux[row];
                    float* o = Cf + (size_t)row * ldc + col;
                    *o = *o + (1.f - g) * v;
                }
            }
        }
    }
}

// ---------------- softmax + banded local attention ----------------
// 1D grid (S_LEN * gcnt), XCD-swizzled so each XCD owns one batch (V L2-resident).
// Reads f32 scores row, writes normalized P row as bf16 IN PLACE (first 4KB of the
// 8KB row; barriers order all pre-barrier loads before the post-barrier stores),
// writes out = gate*local_out.
__global__ __launch_bounds__(256)
void softmax_local(float* __restrict__ sc, const u16* __restrict__ V,
                   const float* __restrict__ gate, float* __restrict__ outp) {
    const int logical = xcd_logical();
    const int i = logical & (S_LEN - 1);
    const int z = logical >> 11;
    const int tid = threadIdx.x;
    const int wv = tid >> 6, lane = tid & 63;
    sc   += (size_t)z * S_LEN * S_LEN;
    V    += (size_t)z * S_LEN * D_DIM;
    gate += (size_t)z * S_LEN;
    outp += (size_t)z * S_LEN * D_DIM;

    __shared__ float part[4][D_DIM];   // band-PV partials
    __shared__ float pl[64];           // band probabilities
    __shared__ float r0[4], r1[4];

    float* scrow = sc + (size_t)i * S_LEN;
    const float4* s4 = (const float4*)scrow;
    float4 a = s4[tid * 2], b = s4[tid * 2 + 1];

    // band bounds; grab band scores straight from the (L1-hot) global row
    int jlo = i - WIN; if (jlo < 0) jlo = 0;
    int jhi = i + WIN; if (jhi > S_LEN - 1) jhi = S_LEN - 1;
    int cnt = jhi - jlo + 1;
    float bvv = (tid < cnt) ? scrow[jlo + tid] : -3.0e38f;

    // global row max
    float mx = fmaxf(fmaxf(fmaxf(a.x, a.y), fmaxf(a.z, a.w)),
                     fmaxf(fmaxf(b.x, b.y), fmaxf(b.z, b.w)));
#pragma unroll
    for (int o = 32; o; o >>= 1) mx = fmaxf(mx, __shfl_xor(mx, o));
    if (lane == 0) r0[wv] = mx;
    __syncthreads();
    float mg = fmaxf(fmaxf(r0[0], r0[1]), fmaxf(r0[2], r0[3]));

    float e0 = __expf(a.x - mg), e1 = __expf(a.y - mg), e2 = __expf(a.z - mg), e3 = __expf(a.w - mg);
    float e4 = __expf(b.x - mg), e5 = __expf(b.y - mg), e6 = __expf(b.z - mg), e7 = __expf(b.w - mg);
    float se = e0 + e1 + e2 + e3 + e4 + e5 + e6 + e7;
#pragma unroll
    for (int o = 32; o; o >>= 1) se += __shfl_xor(se, o);
    if (lane == 0) r1[wv] = se;
    __syncthreads();
    float invl = 1.f / (r1[0] + r1[1] + r1[2] + r1[3]);

    // write normalized P (bf16) in place over the scores row (post-barrier: safe)
    uint4 pw;
    pw.x = (u32)f2bf(e0 * invl) | ((u32)f2bf(e1 * invl) << 16);
    pw.y = (u32)f2bf(e2 * invl) | ((u32)f2bf(e3 * invl) << 16);
    pw.z = (u32)f2bf(e4 * invl) | ((u32)f2bf(e5 * invl) << 16);
    pw.w = (u32)f2bf(e6 * invl) | ((u32)f2bf(e7 * invl) << 16);
    ((uint4*)scrow)[tid] = pw;

    // band softmax stats: wave 0 alone (cnt <= 61)
    if (wv == 0) {
        float ml = bvv;
#pragma unroll
        for (int o = 32; o; o >>= 1) ml = fmaxf(ml, __shfl_xor(ml, o));
        float e = (lane < cnt) ? __expf(bvv - ml) : 0.f;
        float s2 = e;
#pragma unroll
        for (int o = 32; o; o >>= 1) s2 += __shfl_xor(s2, o);
        pl[lane] = e / s2;
    }
    __syncthreads();

    // band PV: wave wv handles jj = wv, wv+4, ...; each lane owns 8 cols
    const int d0 = lane * 8;
    float acc[8];
#pragma unroll
    for (int k = 0; k < 8; k++) acc[k] = 0.f;
    for (int jj = wv; jj < cnt; jj += 4) {
        float p = pl[jj];
        uint4 vv = *(const uint4*)&V[(size_t)(jlo + jj) * D_DIM + d0];
        acc[0] += p * bf_lo(vv.x); acc[1] += p * bf_hi(vv.x);
        acc[2] += p * bf_lo(vv.y); acc[3] += p * bf_hi(vv.y);
        acc[4] += p * bf_lo(vv.z); acc[5] += p * bf_hi(vv.z);
        acc[6] += p * bf_lo(vv.w); acc[7] += p * bf_hi(vv.w);
    }
#pragma unroll
    for (int k = 0; k < 4; k++) {
        ((float4*)&part[wv][d0])[0] = (float4){acc[0], acc[1], acc[2], acc[3]};
        ((float4*)&part[wv][d0 + 4])[0] = (float4){acc[4], acc[5], acc[6], acc[7]};
    }
    __syncthreads();

    float g = gate[i];
    int c = tid * 2;
    float o0 = g * (part[0][c] + part[1][c] + part[2][c] + part[3][c]);
    float o1 = g * (part[0][c + 1] + part[1][c + 1] + part[2][c + 1] + part[3][c + 1]);
    ((float2*)(outp + (size_t)i * D_DIM))[tid] = (float2){o0, o1};
}

// ---------------- launch ----------------
extern "C" void kernel_launch(void* const* d_in, const int* in_sizes, int n_in,
                              void* d_out, int out_size, void* d_ws, size_t ws_size,
                              hipStream_t stream) {
    const float* X  = (const float*)d_in[0];
    const float* Wq = (const float*)d_in[1];
    const float* bq = (const float*)d_in[2];
    const float* Wk = (const float*)d_in[3];
    const float* bk = (const float*)d_in[4];
    const float* Wv = (const float*)d_in[5];
    const float* bv = (const float*)d_in[6];
    const float* Wg = (const float*)d_in[7];
    const float* bg = (const float*)d_in[8];
    float* out = (float*)d_out;

    char* p = (char*)d_ws;
    u16* Xb    = (u16*)p;  p += (size_t)M_TOT * D_DIM * 2;           // 16 MB
    u16* Wt3   = (u16*)p;  p += (size_t)3 * D_DIM * D_DIM * 2;       // 1.5 MB
    u16* QKV   = (u16*)p;  p += (size_t)3 * M_TOT * D_DIM * 2;       // 48 MB
    u16* Vt    = (u16*)p;  p += (size_t)M_TOT * D_DIM * 2;           // 16 MB
    float* gate  = (float*)p; p += (size_t)M_TOT * 4;                // 64 KB
    float* bias3 = (float*)p; p += (size_t)3 * D_DIM * 4;            // 6 KB
    float* scores = (float*)p;                                       // nbuf * 16 MB
    size_t base_used = (size_t)(p - (char*)d_ws);
    size_t per_batch = (size_t)S_LEN * S_LEN * 4;
    int nbuf = (int)((ws_size - base_used) / per_batch);
    if (nbuf > B_N) nbuf = B_N;
    if (nbuf < 1) nbuf = 1;

    u16* Qb = QKV;
    u16* Kb = QKV + (size_t)M_TOT * D_DIM;
    u16* Vb = QKV + (size_t)2 * M_TOT * D_DIM;

    convert_x<<<dim3(M_TOT * D_DIM / 4 / 256), 256, 0, stream>>>(X, Xb);
    transpose_w<<<dim3(16, 16), 256, 0, stream>>>(Wq, Wt3);
    transpose_w<<<dim3(16, 16), 256, 0, stream>>>(Wk, Wt3 + (size_t)D_DIM * D_DIM);
    transpose_w<<<dim3(16, 16), 256, 0, stream>>>(Wv, Wt3 + (size_t)2 * D_DIM * D_DIM);
    pack_bias<<<dim3(2), 256, 0, stream>>>(bq, bk, bv, bias3);
    gate_kernel<<<dim3(M_TOT / 4), 256, 0, stream>>>(X, Wg, bg, gate);

    // Q/K/V projections in one dispatch: z selects weight/bias/output (1536 blocks)
    gemm_bt<0><<<dim3(4 * 128 * 3), 256, 0, stream>>>(
        Xb, Wt3, 512, 512, 512, 4, 128, bias3, QKV, 512, 1.f,
        0LL, (long long)D_DIM * D_DIM, (long long)M_TOT * D_DIM, (long long)D_DIM);

    // Vt[d][t_global] = (Wv^T X^T) + bv[d]   (512 blocks)
    gemm_bt<1><<<dim3(128 * 4), 256, 0, stream>>>(
        Wt3 + (size_t)2 * D_DIM * D_DIM, Xb, 512, 512, 512, 128, 4, bv, Vt, M_TOT, 1.f,
        0LL, 0LL, 0LL, 0LL);

    const float sc = 1.0f / sqrtf((float)D_DIM);
    for (int g0 = 0; g0 < B_N; g0 += nbuf) {
        int gcnt = B_N - g0 < nbuf ? B_N - g0 : nbuf;
        // scores[z][s][t] = (Q.K^T)/sqrt(D), f32  (256 blocks/batch -> one XCD each)
        gemm_bt<2><<<dim3(16 * 16 * gcnt), 256, 0, stream>>>(
            Qb + (size_t)g0 * S_LEN * D_DIM, Kb + (size_t)g0 * S_LEN * D_DIM,
            512, 512, 512, 16, 16, nullptr, scores, S_LEN, sc,
            (long long)S_LEN * D_DIM, (long long)S_LEN * D_DIM,
            (long long)S_LEN * S_LEN, 0LL);
        // softmax: writes bf16 P in place + d_out = g*local (2048 blocks/batch -> one XCD)
        softmax_local<<<dim3(S_LEN * gcnt), 256, 0, stream>>>(
            scores, Vb + (size_t)g0 * S_LEN * D_DIM, gate + (size_t)g0 * S_LEN,
            out + (size_t)g0 * S_LEN * D_DIM);
        // global PV: plain bf16 GEMM on P (lda counts u16 within the f32 rows)
        // (64 blocks/batch -> one XCD; Vt panel 2MB/batch L2-resident)
        gemm_bt<3><<<dim3(4 * 16 * gcnt), 256, 0, stream>>>(
            (const u16*)scores, Vt + (size_t)g0 * S_LEN,
            2 * S_LEN, M_TOT, S_LEN, 4, 16, gate + (size_t)g0 * S_LEN,
            out + (size_t)g0 * S_LEN * D_DIM, 512, 1.f,
            (long long)S_LEN * 2 * S_LEN, (long long)S_LEN,
            (long long)S_LEN * D_DIM, (long long)S_LEN);
    }
}

// Round 5
// 280.348 us; speedup vs baseline: 3.5951x; 1.0366x over previous
//
#include <hip/hip_runtime.h>
#include <math.h>

#define B_N   8
#define S_LEN 2048
#define D_DIM 512
#define M_TOT (B_N * S_LEN)   // 16384
#define WIN   30

typedef short bf16x8 __attribute__((ext_vector_type(8)));
typedef float f32x4  __attribute__((ext_vector_type(4)));
typedef unsigned short u16;
typedef unsigned int   u32;

__device__ __forceinline__ u16 f2bf(float f) {
    union { float f; u32 u; } v; v.f = f;
    u32 r = v.u + 0x7fffu + ((v.u >> 16) & 1u);
    return (u16)(r >> 16);
}
__device__ __forceinline__ float bf2f(u16 u) {
    union { u32 u; float f; } v; v.u = ((u32)u) << 16; return v.f;
}
__device__ __forceinline__ float bf_lo(u32 p) {
    union { u32 u; float f; } v; v.u = p << 16; return v.f;
}
__device__ __forceinline__ float bf_hi(u32 p) {
    union { u32 u; float f; } v; v.u = p & 0xffff0000u; return v.f;
}

__device__ __forceinline__ void gl2lds(const u16* g, u16* l) {
    __builtin_amdgcn_global_load_lds((const __attribute__((address_space(1))) void*)g,
                                     (__attribute__((address_space(3))) void*)l,
                                     16, 0, 0);
}

// bijective chunked XCD swizzle: hw block hb -> logical index such that
// XCD (hb%8) owns one contiguous logical chunk. Requires gridDim.x % 8 == 0.
__device__ __forceinline__ int xcd_logical() {
    const int n = gridDim.x;
    const int hb = blockIdx.x;
    return (hb & 7) * (n >> 3) + (hb >> 3);
}

// ---------------- elementwise converts ----------------

__global__ __launch_bounds__(256) void convert_x(const float* __restrict__ X, u16* __restrict__ Xb) {
    size_t i = (size_t)blockIdx.x * 256 + threadIdx.x;
    float4 v = ((const float4*)X)[i];
    ushort4 o;
    o.x = f2bf(v.x); o.y = f2bf(v.y); o.z = f2bf(v.z); o.w = f2bf(v.w);
    ((ushort4*)Xb)[i] = o;
}

// Wt[n][k] = bf16(W[k][n]),  W is [512][512]
__global__ __launch_bounds__(256) void transpose_w(const float* __restrict__ W, u16* __restrict__ Wt) {
    __shared__ float t[32][33];
    int k0 = blockIdx.x * 32, n0 = blockIdx.y * 32;
    int tx = threadIdx.x & 31, ty = threadIdx.x >> 5;   // 32 x 8
#pragma unroll
    for (int r = ty; r < 32; r += 8) t[r][tx] = W[(size_t)(k0 + r) * D_DIM + n0 + tx];
    __syncthreads();
#pragma unroll
    for (int r = ty; r < 32; r += 8) Wt[(size_t)(n0 + r) * D_DIM + k0 + tx] = f2bf(t[tx][r]);
}

__global__ __launch_bounds__(256) void pack_bias(const float* __restrict__ bq, const float* __restrict__ bk,
                                                 const float* __restrict__ bv, float* __restrict__ b3) {
    int i = blockIdx.x * 256 + threadIdx.x;   // grid 2 -> i in [0,512)
    b3[i] = bq[i]; b3[512 + i] = bk[i]; b3[1024 + i] = bv[i];
}

// gate[m] = sigmoid(X[m,:] . Wg + bg), one wave per row
__global__ __launch_bounds__(256) void gate_kernel(const float* __restrict__ X, const float* __restrict__ Wg,
                                                   const float* __restrict__ bg, float* __restrict__ gate) {
    int wave = threadIdx.x >> 6, lane = threadIdx.x & 63;
    int row = blockIdx.x * 4 + wave;
    const float4* x4 = (const float4*)(X + (size_t)row * D_DIM);
    const float4* w4 = (const float4*)Wg;
    float acc = 0.f;
#pragma unroll
    for (int j = 0; j < 2; j++) {
        float4 a = x4[lane * 2 + j], w = w4[lane * 2 + j];
        acc += a.x * w.x + a.y * w.y + a.z * w.z + a.w * w.w;
    }
#pragma unroll
    for (int o = 32; o; o >>= 1) acc += __shfl_xor(acc, o);
    if (lane == 0) gate[row] = 1.f / (1.f + __expf(-(acc + bg[0])));
}

// ---------------- the one GEMM: C = A * Bt^T, 1D grid, XCD-swizzled ----------------
// logical = x + nx*y + nx*ny*z  (x fastest, z slowest -> one batch per XCD chunk)
// A: bf16 [M][lda], Bt: bf16 [N][ldb]
// tile 128xBN (BN=128 or 64), BK=32, 4 waves (2x2), 16x16x32 bf16 MFMA
// LDS k-slot XOR swizzle (slot ^= (row>>1)&3): pre-swizzled global source
// (gl2lds dest must stay linear) + swizzled ds_read slot. Kills the 8-way
// bank conflict of the 64B-row-stride layout (-> 2-way, free).
// EPI 0: bf16 out + col bias(aux) | 1: bf16 out + row bias(aux) | 2: f32 out * scale
// EPI 3: f32 out += (1-aux[row]) * acc   (aux = gate)
template<int EPI, int BN>
__global__ __launch_bounds__(256)
void gemm_bt(const u16* __restrict__ A, const u16* __restrict__ Bt,
             int lda, int ldb, int K, int nx, int ny,
             const float* __restrict__ aux, void* __restrict__ Cv, int ldc, float scale,
             long long zA, long long zB, long long zC, long long zAux) {
    const int logical = xcd_logical();
    const int x = logical % nx;
    const int t2 = logical / nx;
    const int y = t2 % ny;
    const int z = t2 / ny;

    A   += zA * z;
    Bt  += zB * z;
    if (aux) aux += zAux * z;

    constexpr int NFR = BN / 32;       // 4 (BN=128) or 2 (BN=64)
    constexpr int WCOL = BN / 2;       // wave col coverage

    __shared__ u16 lA[128 * 32];
    __shared__ u16 lB[BN * 32];
    const int tid  = threadIdx.x;
    const int lane = tid & 63;
    const int wave = tid >> 6;
    const int wr = wave >> 1, wc = wave & 1;
    const int m0 = y * 128, n0 = x * BN;

    f32x4 acc[4][NFR];
#pragma unroll
    for (int i = 0; i < 4; i++)
#pragma unroll
        for (int j = 0; j < NFR; j++) acc[i][j] = (f32x4){0.f, 0.f, 0.f, 0.f};

    // staging: chunk c (16B) -> LDS linear offset c*16B = (row=c>>2, slot=c&3);
    // global k-slot loaded = slot ^ ((row>>1)&3) = (c&3)^((c>>3)&3)  [swizzle]
    const int c0 = tid, c1 = tid + 256;
    const int r0c = c0 >> 2, k0c = (((c0 & 3) ^ ((c0 >> 3) & 3)) << 3);
    const int r1c = c1 >> 2, k1c = (((c1 & 3) ^ ((c1 >> 3) & 3)) << 3);
    u16* lAw0 = lA + wave * 512;          // wave-uniform bases (lane*16B appended by HW)
    u16* lAw1 = lA + wave * 512 + 2048;
    u16* lBw0 = lB + wave * 512;
    u16* lBw1 = lB + wave * 512 + 2048;   // used only when BN==128

    for (int k0 = 0; k0 < K; k0 += 32) {
        gl2lds(A + (size_t)(m0 + r0c) * lda + (k0 + k0c), lAw0);
        gl2lds(A + (size_t)(m0 + r1c) * lda + (k0 + k1c), lAw1);
        gl2lds(Bt + (size_t)(n0 + r0c) * ldb + (k0 + k0c), lBw0);
        if (BN == 128)
            gl2lds(Bt + (size_t)(n0 + r1c) * ldb + (k0 + k1c), lBw1);
        __syncthreads();

        const int ks = lane >> 4;
        bf16x8 af[4], bfr[NFR];
#pragma unroll
        for (int m = 0; m < 4; m++) {
            int r = wr * 64 + m * 16 + (lane & 15);
            int s = ks ^ ((r >> 1) & 3);
            af[m] = *(const bf16x8*)&lA[r * 32 + s * 8];
        }
#pragma unroll
        for (int n = 0; n < NFR; n++) {
            int r = wc * WCOL + n * 16 + (lane & 15);
            int s = ks ^ ((r >> 1) & 3);
            bfr[n] = *(const bf16x8*)&lB[r * 32 + s * 8];
        }
#pragma unroll
        for (int m = 0; m < 4; m++)
#pragma unroll
            for (int n = 0; n < NFR; n++)
                acc[m][n] = __builtin_amdgcn_mfma_f32_16x16x32_bf16(af[m], bfr[n], acc[m][n], 0, 0, 0);
        __syncthreads();
    }

    u16*   Cb = (EPI <= 1) ? ((u16*)Cv + zC * z) : nullptr;
    float* Cf = (EPI >= 2) ? ((float*)Cv + zC * z) : nullptr;

    // epilogue: C/D map row=(lane>>4)*4+reg, col=lane&15  [verified m89]
#pragma unroll
    for (int m = 0; m < 4; m++) {
        int rbase = m0 + wr * 64 + m * 16 + ((lane >> 4) << 2);
#pragma unroll
        for (int n = 0; n < NFR; n++) {
            int col = n0 + wc * WCOL + n * 16 + (lane & 15);
#pragma unroll
            for (int rg = 0; rg < 4; rg++) {
                int row = rbase + rg;
                float v = acc[m][n][rg];
                if (EPI == 0) {
                    Cb[(size_t)row * ldc + col] = f2bf(v + aux[col]);
                } else if (EPI == 1) {
                    Cb[(size_t)row * ldc + col] = f2bf(v + aux[row]);
                } else if (EPI == 2) {
                    Cf[(size_t)row * ldc + col] = v * scale;
                } else {
                    float g = aux[row];
                    float* o = Cf + (size_t)row * ldc + col;
                    *o = *o + (1.f - g) * v;
                }
            }
        }
    }
}

// ---------------- softmax + banded local attention ----------------
// 1D grid (S_LEN * gcnt), XCD-swizzled so each XCD owns one batch (V L2-resident).
// Reads f32 scores row, writes normalized P row as bf16 IN PLACE (first 4KB of the
// 8KB row; barriers order all pre-barrier loads before the post-barrier stores),
// writes out = gate*local_out.
__global__ __launch_bounds__(256)
void softmax_local(float* __restrict__ sc, const u16* __restrict__ V,
                   const float* __restrict__ gate, float* __restrict__ outp) {
    const int logical = xcd_logical();
    const int i = logical & (S_LEN - 1);
    const int z = logical >> 11;
    const int tid = threadIdx.x;
    const int wv = tid >> 6, lane = tid & 63;
    sc   += (size_t)z * S_LEN * S_LEN;
    V    += (size_t)z * S_LEN * D_DIM;
    gate += (size_t)z * S_LEN;
    outp += (size_t)z * S_LEN * D_DIM;

    __shared__ float part[4][D_DIM];   // band-PV partials
    __shared__ float pl[64];           // band probabilities
    __shared__ float r0[4], r1[4];

    float* scrow = sc + (size_t)i * S_LEN;
    const float4* s4 = (const float4*)scrow;
    float4 a = s4[tid * 2], b = s4[tid * 2 + 1];

    // band bounds; grab band scores straight from the (L1-hot) global row
    int jlo = i - WIN; if (jlo < 0) jlo = 0;
    int jhi = i + WIN; if (jhi > S_LEN - 1) jhi = S_LEN - 1;
    int cnt = jhi - jlo + 1;
    float bvv = (tid < cnt) ? scrow[jlo + tid] : -3.0e38f;

    // global row max
    float mx = fmaxf(fmaxf(fmaxf(a.x, a.y), fmaxf(a.z, a.w)),
                     fmaxf(fmaxf(b.x, b.y), fmaxf(b.z, b.w)));
#pragma unroll
    for (int o = 32; o; o >>= 1) mx = fmaxf(mx, __shfl_xor(mx, o));
    if (lane == 0) r0[wv] = mx;
    __syncthreads();
    float mg = fmaxf(fmaxf(r0[0], r0[1]), fmaxf(r0[2], r0[3]));

    float e0 = __expf(a.x - mg), e1 = __expf(a.y - mg), e2 = __expf(a.z - mg), e3 = __expf(a.w - mg);
    float e4 = __expf(b.x - mg), e5 = __expf(b.y - mg), e6 = __expf(b.z - mg), e7 = __expf(b.w - mg);
    float se = e0 + e1 + e2 + e3 + e4 + e5 + e6 + e7;
#pragma unroll
    for (int o = 32; o; o >>= 1) se += __shfl_xor(se, o);
    if (lane == 0) r1[wv] = se;
    __syncthreads();
    float invl = 1.f / (r1[0] + r1[1] + r1[2] + r1[3]);

    // write normalized P (bf16) in place over the scores row (post-barrier: safe)
    uint4 pw;
    pw.x = (u32)f2bf(e0 * invl) | ((u32)f2bf(e1 * invl) << 16);
    pw.y = (u32)f2bf(e2 * invl) | ((u32)f2bf(e3 * invl) << 16);
    pw.z = (u32)f2bf(e4 * invl) | ((u32)f2bf(e5 * invl) << 16);
    pw.w = (u32)f2bf(e6 * invl) | ((u32)f2bf(e7 * invl) << 16);
    ((uint4*)scrow)[tid] = pw;

    // band softmax stats: wave 0 alone (cnt <= 61)
    if (wv == 0) {
        float ml = bvv;
#pragma unroll
        for (int o = 32; o; o >>= 1) ml = fmaxf(ml, __shfl_xor(ml, o));
        float e = (lane < cnt) ? __expf(bvv - ml) : 0.f;
        float s2 = e;
#pragma unroll
        for (int o = 32; o; o >>= 1) s2 += __shfl_xor(s2, o);
        pl[lane] = e / s2;
    }
    __syncthreads();

    // band PV: wave wv handles jj = wv, wv+4, ...; each lane owns 8 cols
    const int d0 = lane * 8;
    float acc[8];
#pragma unroll
    for (int k = 0; k < 8; k++) acc[k] = 0.f;
    for (int jj = wv; jj < cnt; jj += 4) {
        float p = pl[jj];
        uint4 vv = *(const uint4*)&V[(size_t)(jlo + jj) * D_DIM + d0];
        acc[0] += p * bf_lo(vv.x); acc[1] += p * bf_hi(vv.x);
        acc[2] += p * bf_lo(vv.y); acc[3] += p * bf_hi(vv.y);
        acc[4] += p * bf_lo(vv.z); acc[5] += p * bf_hi(vv.z);
        acc[6] += p * bf_lo(vv.w); acc[7] += p * bf_hi(vv.w);
    }
    ((float4*)&part[wv][d0])[0] = (float4){acc[0], acc[1], acc[2], acc[3]};
    ((float4*)&part[wv][d0 + 4])[0] = (float4){acc[4], acc[5], acc[6], acc[7]};
    __syncthreads();

    float g = gate[i];
    int c = tid * 2;
    float o0 = g * (part[0][c] + part[1][c] + part[2][c] + part[3][c]);
    float o1 = g * (part[0][c + 1] + part[1][c + 1] + part[2][c + 1] + part[3][c + 1]);
    ((float2*)(outp + (size_t)i * D_DIM))[tid] = (float2){o0, o1};
}

// ---------------- launch ----------------
extern "C" void kernel_launch(void* const* d_in, const int* in_sizes, int n_in,
                              void* d_out, int out_size, void* d_ws, size_t ws_size,
                              hipStream_t stream) {
    const float* X  = (const float*)d_in[0];
    const float* Wq = (const float*)d_in[1];
    const float* bq = (const float*)d_in[2];
    const float* Wk = (const float*)d_in[3];
    const float* bk = (const float*)d_in[4];
    const float* Wv = (const float*)d_in[5];
    const float* bv = (const float*)d_in[6];
    const float* Wg = (const float*)d_in[7];
    const float* bg = (const float*)d_in[8];
    float* out = (float*)d_out;

    char* p = (char*)d_ws;
    u16* Xb    = (u16*)p;  p += (size_t)M_TOT * D_DIM * 2;           // 16 MB
    u16* Wt3   = (u16*)p;  p += (size_t)3 * D_DIM * D_DIM * 2;       // 1.5 MB
    u16* QKV   = (u16*)p;  p += (size_t)3 * M_TOT * D_DIM * 2;       // 48 MB
    u16* Vt    = (u16*)p;  p += (size_t)M_TOT * D_DIM * 2;           // 16 MB
    float* gate  = (float*)p; p += (size_t)M_TOT * 4;                // 64 KB
    float* bias3 = (float*)p; p += (size_t)3 * D_DIM * 4;            // 6 KB
    float* scores = (float*)p;                                       // nbuf * 16 MB
    size_t base_used = (size_t)(p - (char*)d_ws);
    size_t per_batch = (size_t)S_LEN * S_LEN * 4;
    int nbuf = (int)((ws_size - base_used) / per_batch);
    if (nbuf > B_N) nbuf = B_N;
    if (nbuf < 1) nbuf = 1;

    u16* Qb = QKV;
    u16* Kb = QKV + (size_t)M_TOT * D_DIM;
    u16* Vb = QKV + (size_t)2 * M_TOT * D_DIM;

    convert_x<<<dim3(M_TOT * D_DIM / 4 / 256), 256, 0, stream>>>(X, Xb);
    transpose_w<<<dim3(16, 16), 256, 0, stream>>>(Wq, Wt3);
    transpose_w<<<dim3(16, 16), 256, 0, stream>>>(Wk, Wt3 + (size_t)D_DIM * D_DIM);
    transpose_w<<<dim3(16, 16), 256, 0, stream>>>(Wv, Wt3 + (size_t)2 * D_DIM * D_DIM);
    pack_bias<<<dim3(2), 256, 0, stream>>>(bq, bk, bv, bias3);
    gate_kernel<<<dim3(M_TOT / 4), 256, 0, stream>>>(X, Wg, bg, gate);

    // Q/K/V projections in one dispatch: z selects weight/bias/output (1536 blocks)
    gemm_bt<0, 128><<<dim3(4 * 128 * 3), 256, 0, stream>>>(
        Xb, Wt3, 512, 512, 512, 4, 128, bias3, QKV, 512, 1.f,
        0LL, (long long)D_DIM * D_DIM, (long long)M_TOT * D_DIM, (long long)D_DIM);

    // Vt[d][t_global] = (Wv^T X^T) + bv[d]   (512 blocks)
    gemm_bt<1, 128><<<dim3(128 * 4), 256, 0, stream>>>(
        Wt3 + (size_t)2 * D_DIM * D_DIM, Xb, 512, 512, 512, 128, 4, bv, Vt, M_TOT, 1.f,
        0LL, 0LL, 0LL, 0LL);

    const float sc = 1.0f / sqrtf((float)D_DIM);
    for (int g0 = 0; g0 < B_N; g0 += nbuf) {
        int gcnt = B_N - g0 < nbuf ? B_N - g0 : nbuf;
        // scores[z][s][t] = (Q.K^T)/sqrt(D), f32  (256 blocks/batch -> one XCD each)
        gemm_bt<2, 128><<<dim3(16 * 16 * gcnt), 256, 0, stream>>>(
            Qb + (size_t)g0 * S_LEN * D_DIM, Kb + (size_t)g0 * S_LEN * D_DIM,
            512, 512, 512, 16, 16, nullptr, scores, S_LEN, sc,
            (long long)S_LEN * D_DIM, (long long)S_LEN * D_DIM,
            (long long)S_LEN * S_LEN, 0LL);
        // softmax: writes bf16 P in place + d_out = g*local (2048 blocks/batch -> one XCD)
        softmax_local<<<dim3(S_LEN * gcnt), 256, 0, stream>>>(
            scores, Vb + (size_t)g0 * S_LEN * D_DIM, gate + (size_t)g0 * S_LEN,
            out + (size_t)g0 * S_LEN * D_DIM);
        // global PV: plain bf16 GEMM on P (lda counts u16 within the f32 rows)
        // 128x64 tile -> 128 blocks/batch (4 blocks/CU) for latency hiding
        gemm_bt<3, 64><<<dim3(8 * 16 * gcnt), 256, 0, stream>>>(
            (const u16*)scores, Vt + (size_t)g0 * S_LEN,
            2 * S_LEN, M_TOT, S_LEN, 8, 16, gate + (size_t)g0 * S_LEN,
            out + (size_t)g0 * S_LEN * D_DIM, 512, 1.f,
            (long long)S_LEN * 2 * S_LEN, (long long)S_LEN,
            (long long)S_LEN * D_DIM, (long long)S_LEN);
    }
}

// Round 6
// 231.547 us; speedup vs baseline: 4.3527x; 1.2108x over previous
//
#include <hip/hip_runtime.h>
#include <math.h>

#define B_N   8
#define S_LEN 2048
#define D_DIM 512
#define M_TOT (B_N * S_LEN)   // 16384
#define WIN   30

typedef short bf16x8 __attribute__((ext_vector_type(8)));
typedef float f32x4  __attribute__((ext_vector_type(4)));
typedef unsigned short u16;
typedef unsigned int   u32;

__device__ __forceinline__ u16 f2bf(float f) {
    union { float f; u32 u; } v; v.f = f;
    u32 r = v.u + 0x7fffu + ((v.u >> 16) & 1u);
    return (u16)(r >> 16);
}
__device__ __forceinline__ float bf2f(u16 u) {
    union { u32 u; float f; } v; v.u = ((u32)u) << 16; return v.f;
}

__device__ __forceinline__ void gl2lds(const u16* g, u16* l) {
    __builtin_amdgcn_global_load_lds((const __attribute__((address_space(1))) void*)g,
                                     (__attribute__((address_space(3))) void*)l,
                                     16, 0, 0);
}

// bijective chunked XCD swizzle: hw block hb -> logical index such that
// XCD (hb%8) owns one contiguous logical chunk. Requires gridDim.x % 8 == 0.
__device__ __forceinline__ int xcd_logical() {
    const int n = gridDim.x;
    const int hb = blockIdx.x;
    return (hb & 7) * (n >> 3) + (hb >> 3);
}

// ---------------- elementwise converts ----------------

__global__ __launch_bounds__(256) void convert_x(const float* __restrict__ X, u16* __restrict__ Xb) {
    size_t i = (size_t)blockIdx.x * 256 + threadIdx.x;
    float4 v = ((const float4*)X)[i];
    ushort4 o;
    o.x = f2bf(v.x); o.y = f2bf(v.y); o.z = f2bf(v.z); o.w = f2bf(v.w);
    ((ushort4*)Xb)[i] = o;
}

// Wt[n][k] = bf16(W[k][n]),  W is [512][512]
__global__ __launch_bounds__(256) void transpose_w(const float* __restrict__ W, u16* __restrict__ Wt) {
    __shared__ float t[32][33];
    int k0 = blockIdx.x * 32, n0 = blockIdx.y * 32;
    int tx = threadIdx.x & 31, ty = threadIdx.x >> 5;   // 32 x 8
#pragma unroll
    for (int r = ty; r < 32; r += 8) t[r][tx] = W[(size_t)(k0 + r) * D_DIM + n0 + tx];
    __syncthreads();
#pragma unroll
    for (int r = ty; r < 32; r += 8) Wt[(size_t)(n0 + r) * D_DIM + k0 + tx] = f2bf(t[tx][r]);
}

__global__ __launch_bounds__(256) void pack_bias(const float* __restrict__ bq, const float* __restrict__ bk,
                                                 const float* __restrict__ bv, float* __restrict__ b3) {
    int i = blockIdx.x * 256 + threadIdx.x;   // grid 2 -> i in [0,512)
    b3[i] = bq[i]; b3[512 + i] = bk[i]; b3[1024 + i] = bv[i];
}

// gate[m] = sigmoid(X[m,:] . Wg + bg), one wave per row
__global__ __launch_bounds__(256) void gate_kernel(const float* __restrict__ X, const float* __restrict__ Wg,
                                                   const float* __restrict__ bg, float* __restrict__ gate) {
    int wave = threadIdx.x >> 6, lane = threadIdx.x & 63;
    int row = blockIdx.x * 4 + wave;
    const float4* x4 = (const float4*)(X + (size_t)row * D_DIM);
    const float4* w4 = (const float4*)Wg;
    float acc = 0.f;
#pragma unroll
    for (int j = 0; j < 2; j++) {
        float4 a = x4[lane * 2 + j], w = w4[lane * 2 + j];
        acc += a.x * w.x + a.y * w.y + a.z * w.z + a.w * w.w;
    }
#pragma unroll
    for (int o = 32; o; o >>= 1) acc += __shfl_xor(acc, o);
    if (lane == 0) gate[row] = 1.f / (1.f + __expf(-(acc + bg[0])));
}

// ---------------- the one GEMM: C = A * Bt^T, 1D grid, XCD-swizzled ----------------
// logical = x + nx*y + nx*ny*z  (x fastest, z slowest -> one batch per XCD chunk)
// A: bf16 [M][lda], Bt: bf16 [N][ldb]
// tile 128xBN (BN=128 or 64), BK=32, 4 waves (2x2), 16x16x32 bf16 MFMA
// LDS k-slot XOR swizzle (slot ^= (row>>1)&3): pre-swizzled global source
// (gl2lds dest must stay linear) + swizzled ds_read slot.
// EPI 0: bf16 out + col bias(aux) | 1: bf16 out + row bias(aux) | 2: f32 out * scale
template<int EPI, int BN>
__global__ __launch_bounds__(256)
void gemm_bt(const u16* __restrict__ A, const u16* __restrict__ Bt,
             int lda, int ldb, int K, int nx, int ny,
             const float* __restrict__ aux, void* __restrict__ Cv, int ldc, float scale,
             long long zA, long long zB, long long zC, long long zAux) {
    const int logical = xcd_logical();
    const int x = logical % nx;
    const int t2 = logical / nx;
    const int y = t2 % ny;
    const int z = t2 / ny;

    A   += zA * z;
    Bt  += zB * z;
    if (aux) aux += zAux * z;

    constexpr int NFR = BN / 32;       // 4 (BN=128) or 2 (BN=64)
    constexpr int WCOL = BN / 2;       // wave col coverage

    __shared__ u16 lA[128 * 32];
    __shared__ u16 lB[BN * 32];
    const int tid  = threadIdx.x;
    const int lane = tid & 63;
    const int wave = tid >> 6;
    const int wr = wave >> 1, wc = wave & 1;
    const int m0 = y * 128, n0 = x * BN;

    f32x4 acc[4][NFR];
#pragma unroll
    for (int i = 0; i < 4; i++)
#pragma unroll
        for (int j = 0; j < NFR; j++) acc[i][j] = (f32x4){0.f, 0.f, 0.f, 0.f};

    // staging: chunk c (16B) -> LDS linear offset c*16B = (row=c>>2, slot=c&3);
    // global k-slot loaded = slot ^ ((row>>1)&3) = (c&3)^((c>>3)&3)  [swizzle]
    const int c0 = tid, c1 = tid + 256;
    const int r0c = c0 >> 2, k0c = (((c0 & 3) ^ ((c0 >> 3) & 3)) << 3);
    const int r1c = c1 >> 2, k1c = (((c1 & 3) ^ ((c1 >> 3) & 3)) << 3);
    u16* lAw0 = lA + wave * 512;          // wave-uniform bases (lane*16B appended by HW)
    u16* lAw1 = lA + wave * 512 + 2048;
    u16* lBw0 = lB + wave * 512;
    u16* lBw1 = lB + wave * 512 + 2048;   // used only when BN==128

    for (int k0 = 0; k0 < K; k0 += 32) {
        gl2lds(A + (size_t)(m0 + r0c) * lda + (k0 + k0c), lAw0);
        gl2lds(A + (size_t)(m0 + r1c) * lda + (k0 + k1c), lAw1);
        gl2lds(Bt + (size_t)(n0 + r0c) * ldb + (k0 + k0c), lBw0);
        if (BN == 128)
            gl2lds(Bt + (size_t)(n0 + r1c) * ldb + (k0 + k1c), lBw1);
        __syncthreads();

        const int ks = lane >> 4;
        bf16x8 af[4], bfr[NFR];
#pragma unroll
        for (int m = 0; m < 4; m++) {
            int r = wr * 64 + m * 16 + (lane & 15);
            int s = ks ^ ((r >> 1) & 3);
            af[m] = *(const bf16x8*)&lA[r * 32 + s * 8];
        }
#pragma unroll
        for (int n = 0; n < NFR; n++) {
            int r = wc * WCOL + n * 16 + (lane & 15);
            int s = ks ^ ((r >> 1) & 3);
            bfr[n] = *(const bf16x8*)&lB[r * 32 + s * 8];
        }
#pragma unroll
        for (int m = 0; m < 4; m++)
#pragma unroll
            for (int n = 0; n < NFR; n++)
                acc[m][n] = __builtin_amdgcn_mfma_f32_16x16x32_bf16(af[m], bfr[n], acc[m][n], 0, 0, 0);
        __syncthreads();
    }

    u16*   Cb = (EPI <= 1) ? ((u16*)Cv + zC * z) : nullptr;
    float* Cf = (EPI >= 2) ? ((float*)Cv + zC * z) : nullptr;

    // epilogue: C/D map row=(lane>>4)*4+reg, col=lane&15  [verified m89]
#pragma unroll
    for (int m = 0; m < 4; m++) {
        int rbase = m0 + wr * 64 + m * 16 + ((lane >> 4) << 2);
#pragma unroll
        for (int n = 0; n < NFR; n++) {
            int col = n0 + wc * WCOL + n * 16 + (lane & 15);
#pragma unroll
            for (int rg = 0; rg < 4; rg++) {
                int row = rbase + rg;
                float v = acc[m][n][rg];
                if (EPI == 0) {
                    Cb[(size_t)row * ldc + col] = f2bf(v + aux[col]);
                } else if (EPI == 1) {
                    Cb[(size_t)row * ldc + col] = f2bf(v + aux[row]);
                } else {
                    Cf[(size_t)row * ldc + col] = v * scale;
                }
            }
        }
    }
}

// ---------------- fused softmax: R = (1-g)*P_glob + g*P_loc, bf16 in place ----------------
// 1D grid (S_LEN * gcnt), XCD-swizzled. Reads the f32 scores row, computes both
// softmaxes' stats, writes the COMBINED gated probability row R as bf16 in place
// (first 4KB of the 8KB row). The PV GEMM then produces the final output directly.
__global__ __launch_bounds__(256)
void softmax_fuse(float* __restrict__ sc, const float* __restrict__ gate) {
    const int logical = xcd_logical();
    const int i = logical & (S_LEN - 1);
    const int z = logical >> 11;
    const int tid = threadIdx.x;
    const int wv = tid >> 6, lane = tid & 63;
    sc   += (size_t)z * S_LEN * S_LEN;
    gate += (size_t)z * S_LEN;

    __shared__ float r0[4], r1[4], mll[2];

    float* scrow = sc + (size_t)i * S_LEN;
    const float4* s4 = (const float4*)scrow;
    float4 a = s4[tid * 2], b = s4[tid * 2 + 1];

    // band bounds; band scores read pre-barrier (in-row only, no cross-block hazard)
    int jlo = i - WIN; if (jlo < 0) jlo = 0;
    int jhi = i + WIN; if (jhi > S_LEN - 1) jhi = S_LEN - 1;
    int cnt = jhi - jlo + 1;
    float bvv = (tid < cnt) ? scrow[jlo + tid] : -3.0e38f;
    float g = gate[i];

    float sv[8] = {a.x, a.y, a.z, a.w, b.x, b.y, b.z, b.w};

    // global row max
    float mx = fmaxf(fmaxf(fmaxf(sv[0], sv[1]), fmaxf(sv[2], sv[3])),
                     fmaxf(fmaxf(sv[4], sv[5]), fmaxf(sv[6], sv[7])));
#pragma unroll
    for (int o = 32; o; o >>= 1) mx = fmaxf(mx, __shfl_xor(mx, o));
    if (lane == 0) r0[wv] = mx;
    __syncthreads();
    float mg = fmaxf(fmaxf(r0[0], r0[1]), fmaxf(r0[2], r0[3]));

    float ev[8];
#pragma unroll
    for (int k = 0; k < 8; k++) ev[k] = __expf(sv[k] - mg);
    float se = ev[0] + ev[1] + ev[2] + ev[3] + ev[4] + ev[5] + ev[6] + ev[7];
#pragma unroll
    for (int o = 32; o; o >>= 1) se += __shfl_xor(se, o);
    if (lane == 0) r1[wv] = se;

    // band softmax stats: wave 0 alone (cnt <= 61, register-resident)
    if (wv == 0) {
        float ml = bvv;
#pragma unroll
        for (int o = 32; o; o >>= 1) ml = fmaxf(ml, __shfl_xor(ml, o));
        float e = (lane < cnt) ? __expf(bvv - ml) : 0.f;
        float s2 = e;
#pragma unroll
        for (int o = 32; o; o >>= 1) s2 += __shfl_xor(s2, o);
        if (lane == 0) { mll[0] = ml; mll[1] = 1.f / s2; }
    }
    __syncthreads();
    float invl = (1.f - g) / (r1[0] + r1[1] + r1[2] + r1[3]);
    float ml  = mll[0];
    float ill = g * mll[1];

    // R[col] = (1-g)*exp(s-mg)/lg + [|col-i|<=WIN] * g*exp(s-ml)/ll, bf16 in place
    const int c0 = tid * 8;
    u32 pk_[4];
#pragma unroll
    for (int h = 0; h < 4; h++) {
        float rA = ev[2 * h] * invl;
        float rB = ev[2 * h + 1] * invl;
        int colA = c0 + 2 * h;
        if ((u32)(colA - i + WIN) <= 2u * WIN)     rA += __expf(sv[2 * h] - ml) * ill;
        if ((u32)(colA + 1 - i + WIN) <= 2u * WIN) rB += __expf(sv[2 * h + 1] - ml) * ill;
        pk_[h] = (u32)f2bf(rA) | ((u32)f2bf(rB) << 16);
    }
    uint4 pw = {pk_[0], pk_[1], pk_[2], pk_[3]};
    ((uint4*)scrow)[tid] = pw;   // post-barrier: all row reads drained at barrier
}

// ---------------- launch ----------------
extern "C" void kernel_launch(void* const* d_in, const int* in_sizes, int n_in,
                              void* d_out, int out_size, void* d_ws, size_t ws_size,
                              hipStream_t stream) {
    const float* X  = (const float*)d_in[0];
    const float* Wq = (const float*)d_in[1];
    const float* bq = (const float*)d_in[2];
    const float* Wk = (const float*)d_in[3];
    const float* bk = (const float*)d_in[4];
    const float* Wv = (const float*)d_in[5];
    const float* bv = (const float*)d_in[6];
    const float* Wg = (const float*)d_in[7];
    const float* bg = (const float*)d_in[8];
    float* out = (float*)d_out;

    char* p = (char*)d_ws;
    u16* Xb    = (u16*)p;  p += (size_t)M_TOT * D_DIM * 2;           // 16 MB
    u16* Wt3   = (u16*)p;  p += (size_t)3 * D_DIM * D_DIM * 2;       // 1.5 MB
    u16* QKV   = (u16*)p;  p += (size_t)3 * M_TOT * D_DIM * 2;       // 48 MB
    u16* Vt    = (u16*)p;  p += (size_t)M_TOT * D_DIM * 2;           // 16 MB
    float* gate  = (float*)p; p += (size_t)M_TOT * 4;                // 64 KB
    float* bias3 = (float*)p; p += (size_t)3 * D_DIM * 4;            // 6 KB
    float* scores = (float*)p;                                       // nbuf * 16 MB
    size_t base_used = (size_t)(p - (char*)d_ws);
    size_t per_batch = (size_t)S_LEN * S_LEN * 4;
    int nbuf = (int)((ws_size - base_used) / per_batch);
    if (nbuf > B_N) nbuf = B_N;
    if (nbuf < 1) nbuf = 1;

    u16* Qb = QKV;
    u16* Kb = QKV + (size_t)M_TOT * D_DIM;

    convert_x<<<dim3(M_TOT * D_DIM / 4 / 256), 256, 0, stream>>>(X, Xb);
    transpose_w<<<dim3(16, 16), 256, 0, stream>>>(Wq, Wt3);
    transpose_w<<<dim3(16, 16), 256, 0, stream>>>(Wk, Wt3 + (size_t)D_DIM * D_DIM);
    transpose_w<<<dim3(16, 16), 256, 0, stream>>>(Wv, Wt3 + (size_t)2 * D_DIM * D_DIM);
    pack_bias<<<dim3(2), 256, 0, stream>>>(bq, bk, bv, bias3);
    gate_kernel<<<dim3(M_TOT / 4), 256, 0, stream>>>(X, Wg, bg, gate);

    // Q/K/V projections in one dispatch: z selects weight/bias/output (1536 blocks)
    gemm_bt<0, 128><<<dim3(4 * 128 * 3), 256, 0, stream>>>(
        Xb, Wt3, 512, 512, 512, 4, 128, bias3, QKV, 512, 1.f,
        0LL, (long long)D_DIM * D_DIM, (long long)M_TOT * D_DIM, (long long)D_DIM);

    // Vt[d][t_global] = (Wv^T X^T) + bv[d]   (512 blocks)
    gemm_bt<1, 128><<<dim3(128 * 4), 256, 0, stream>>>(
        Wt3 + (size_t)2 * D_DIM * D_DIM, Xb, 512, 512, 512, 128, 4, bv, Vt, M_TOT, 1.f,
        0LL, 0LL, 0LL, 0LL);

    const float sc = 1.0f / sqrtf((float)D_DIM);
    for (int g0 = 0; g0 < B_N; g0 += nbuf) {
        int gcnt = B_N - g0 < nbuf ? B_N - g0 : nbuf;
        // scores[z][s][t] = (Q.K^T)/sqrt(D), f32  (256 blocks/batch -> one XCD each)
        gemm_bt<2, 128><<<dim3(16 * 16 * gcnt), 256, 0, stream>>>(
            Qb + (size_t)g0 * S_LEN * D_DIM, Kb + (size_t)g0 * S_LEN * D_DIM,
            512, 512, 512, 16, 16, nullptr, scores, S_LEN, sc,
            (long long)S_LEN * D_DIM, (long long)S_LEN * D_DIM,
            (long long)S_LEN * S_LEN, 0LL);
        // fused softmax: R = (1-g)*P_glob + g*P_loc, bf16 in place over scores
        softmax_fuse<<<dim3(S_LEN * gcnt), 256, 0, stream>>>(
            scores, gate + (size_t)g0 * S_LEN);
        // out = R * V  (single PV GEMM produces the final gated output, f32)
        // 128x64 tile -> 128 blocks/batch (4 blocks/CU) for latency hiding
        gemm_bt<2, 64><<<dim3(8 * 16 * gcnt), 256, 0, stream>>>(
            (const u16*)scores, Vt + (size_t)g0 * S_LEN,
            2 * S_LEN, M_TOT, S_LEN, 8, 16, nullptr,
            out + (size_t)g0 * S_LEN * D_DIM, 512, 1.f,
            (long long)S_LEN * 2 * S_LEN, (long long)S_LEN,
            (long long)S_LEN * D_DIM, 0LL);
    }
}

// Round 7
// 205.357 us; speedup vs baseline: 4.9079x; 1.1275x over previous
//
#include <hip/hip_runtime.h>
#include <math.h>

#define B_N   8
#define S_LEN 2048
#define D_DIM 512
#define M_TOT (B_N * S_LEN)   // 16384
#define WIN   30

typedef short bf16x8 __attribute__((ext_vector_type(8)));
typedef float f32x4  __attribute__((ext_vector_type(4)));
typedef unsigned short u16;
typedef unsigned int   u32;

__device__ __forceinline__ u16 f2bf(float f) {
    union { float f; u32 u; } v; v.f = f;
    u32 r = v.u + 0x7fffu + ((v.u >> 16) & 1u);
    return (u16)(r >> 16);
}

__device__ __forceinline__ void gl2lds(const u16* g, u16* l) {
    __builtin_amdgcn_global_load_lds((const __attribute__((address_space(1))) void*)g,
                                     (__attribute__((address_space(3))) void*)l,
                                     16, 0, 0);
}

// bijective chunked XCD swizzle: hw block hb -> logical index such that
// XCD (hb%8) owns one contiguous logical chunk. Requires gridDim.x % 8 == 0.
__device__ __forceinline__ int xcd_logical() {
    const int n = gridDim.x;
    const int hb = blockIdx.x;
    return (hb & 7) * (n >> 3) + (hb >> 3);
}

// ---------------- elementwise converts ----------------

__global__ __launch_bounds__(256) void convert_x(const float* __restrict__ X, u16* __restrict__ Xb) {
    size_t i = (size_t)blockIdx.x * 256 + threadIdx.x;
    float4 v = ((const float4*)X)[i];
    ushort4 o;
    o.x = f2bf(v.x); o.y = f2bf(v.y); o.z = f2bf(v.z); o.w = f2bf(v.w);
    ((ushort4*)Xb)[i] = o;
}

// Wt3[z][n][k] = bf16(W_z[k][n]); grid (16,16,3)
__global__ __launch_bounds__(256) void transpose_w3(const float* __restrict__ Wq, const float* __restrict__ Wk,
                                                    const float* __restrict__ Wv, u16* __restrict__ Wt3) {
    const float* W = blockIdx.z == 0 ? Wq : (blockIdx.z == 1 ? Wk : Wv);
    u16* Wt = Wt3 + (size_t)blockIdx.z * D_DIM * D_DIM;
    __shared__ float t[32][33];
    int k0 = blockIdx.x * 32, n0 = blockIdx.y * 32;
    int tx = threadIdx.x & 31, ty = threadIdx.x >> 5;   // 32 x 8
#pragma unroll
    for (int r = ty; r < 32; r += 8) t[r][tx] = W[(size_t)(k0 + r) * D_DIM + n0 + tx];
    __syncthreads();
#pragma unroll
    for (int r = ty; r < 32; r += 8) Wt[(size_t)(n0 + r) * D_DIM + k0 + tx] = f2bf(t[tx][r]);
}

__global__ __launch_bounds__(256) void pack_bias(const float* __restrict__ bq, const float* __restrict__ bk,
                                                 const float* __restrict__ bv, float* __restrict__ b3) {
    int i = blockIdx.x * 256 + threadIdx.x;   // grid 2 -> i in [0,512)
    b3[i] = bq[i]; b3[512 + i] = bk[i]; b3[1024 + i] = bv[i];
}

// gate[m] = sigmoid(X[m,:] . Wg + bg), one wave per row
__global__ __launch_bounds__(256) void gate_kernel(const float* __restrict__ X, const float* __restrict__ Wg,
                                                   const float* __restrict__ bg, float* __restrict__ gate) {
    int wave = threadIdx.x >> 6, lane = threadIdx.x & 63;
    int row = blockIdx.x * 4 + wave;
    const float4* x4 = (const float4*)(X + (size_t)row * D_DIM);
    const float4* w4 = (const float4*)Wg;
    float acc = 0.f;
#pragma unroll
    for (int j = 0; j < 2; j++) {
        float4 a = x4[lane * 2 + j], w = w4[lane * 2 + j];
        acc += a.x * w.x + a.y * w.y + a.z * w.z + a.w * w.w;
    }
#pragma unroll
    for (int o = 32; o; o >>= 1) acc += __shfl_xor(acc, o);
    if (lane == 0) gate[row] = 1.f / (1.f + __expf(-(acc + bg[0])));
}

// ---------------- the one GEMM: C = A * Bt^T, 1D grid, XCD-swizzled ----------------
// logical = x + nx*y + nx*ny*z  (x fastest, z slowest -> one batch per XCD chunk)
// A: bf16 [M][lda], Bt: bf16 [N][ldb]
// tile 128xBN (BN=128 or 64), BK=32, 4 waves (2x2), 16x16x32 bf16 MFMA
// 2-PHASE double-buffered K-loop: stage tile t+1 into buf[cur^1] BEFORE
// computing tile t from buf[cur]; single barrier per K-step (its implicit
// vmcnt(0) lands after ds_read+MFMA, overlapping staging with compute).
// LDS k-slot XOR swizzle (slot ^= (row>>1)&3): pre-swizzled global source
// (gl2lds dest stays linear) + swizzled ds_read slot -> zero bank conflicts.
// EPI 0: bf16 out + col bias(aux) | 1: bf16 out + row bias(aux) | 2: f32 out * scale
template<int EPI, int BN>
__global__ __launch_bounds__(256)
void gemm_bt(const u16* __restrict__ A, const u16* __restrict__ Bt,
             int lda, int ldb, int K, int nx, int ny,
             const float* __restrict__ aux, void* __restrict__ Cv, int ldc, float scale,
             long long zA, long long zB, long long zC, long long zAux) {
    const int logical = xcd_logical();
    const int x = logical % nx;
    const int t2 = logical / nx;
    const int y = t2 % ny;
    const int z = t2 / ny;

    A   += zA * z;
    Bt  += zB * z;
    if (aux) aux += zAux * z;

    constexpr int NFR = BN / 32;       // 4 (BN=128) or 2 (BN=64)
    constexpr int WCOL = BN / 2;       // wave col coverage

    __shared__ u16 lA0[128 * 32], lA1[128 * 32];
    __shared__ u16 lB0[BN * 32],  lB1[BN * 32];
    const int tid  = threadIdx.x;
    const int lane = tid & 63;
    const int wave = tid >> 6;
    const int wr = wave >> 1, wc = wave & 1;
    const int m0 = y * 128, n0 = x * BN;

    f32x4 acc[4][NFR];
#pragma unroll
    for (int i = 0; i < 4; i++)
#pragma unroll
        for (int j = 0; j < NFR; j++) acc[i][j] = (f32x4){0.f, 0.f, 0.f, 0.f};

    // staging: chunk c (16B) -> LDS linear offset c*16B = (row=c>>2, slot=c&3);
    // global k-slot loaded = slot ^ ((row>>1)&3) = (c&3)^((c>>3)&3)  [swizzle]
    const int c0 = tid, c1 = tid + 256;
    const int r0c = c0 >> 2, k0c = (((c0 & 3) ^ ((c0 >> 3) & 3)) << 3);
    const int r1c = c1 >> 2, k1c = (((c1 & 3) ^ ((c1 >> 3) & 3)) << 3);

    auto stage = [&](u16* dA, u16* dB, int k0) {
        gl2lds(A + (size_t)(m0 + r0c) * lda + (k0 + k0c), dA + wave * 512);
        gl2lds(A + (size_t)(m0 + r1c) * lda + (k0 + k1c), dA + wave * 512 + 2048);
        gl2lds(Bt + (size_t)(n0 + r0c) * ldb + (k0 + k0c), dB + wave * 512);
        if (BN == 128)
            gl2lds(Bt + (size_t)(n0 + r1c) * ldb + (k0 + k1c), dB + wave * 512 + 2048);
    };
    auto compute = [&](const u16* bA, const u16* bB) {
        const int ks = lane >> 4;
        bf16x8 af[4], bfr[NFR];
#pragma unroll
        for (int m = 0; m < 4; m++) {
            int r = wr * 64 + m * 16 + (lane & 15);
            int s = ks ^ ((r >> 1) & 3);
            af[m] = *(const bf16x8*)&bA[r * 32 + s * 8];
        }
#pragma unroll
        for (int n = 0; n < NFR; n++) {
            int r = wc * WCOL + n * 16 + (lane & 15);
            int s = ks ^ ((r >> 1) & 3);
            bfr[n] = *(const bf16x8*)&bB[r * 32 + s * 8];
        }
#pragma unroll
        for (int m = 0; m < 4; m++)
#pragma unroll
            for (int n = 0; n < NFR; n++)
                acc[m][n] = __builtin_amdgcn_mfma_f32_16x16x32_bf16(af[m], bfr[n], acc[m][n], 0, 0, 0);
    };

    // prologue: stage tile 0 into buf0 (barrier's vmcnt(0) drains it)
    stage(lA0, lB0, 0);
    __syncthreads();

    const int nt = K >> 5;   // all K here are multiples of 64 -> nt even
    for (int t = 0; t < nt; t += 2) {
        if (t + 1 < nt) stage(lA1, lB1, (t + 1) << 5);
        compute(lA0, lB0);
        __syncthreads();
        if (t + 2 < nt) stage(lA0, lB0, (t + 2) << 5);
        compute(lA1, lB1);
        __syncthreads();
    }

    u16*   Cb = (EPI <= 1) ? ((u16*)Cv + zC * z) : nullptr;
    float* Cf = (EPI >= 2) ? ((float*)Cv + zC * z) : nullptr;

    // epilogue: C/D map row=(lane>>4)*4+reg, col=lane&15  [verified m89]
#pragma unroll
    for (int m = 0; m < 4; m++) {
        int rbase = m0 + wr * 64 + m * 16 + ((lane >> 4) << 2);
#pragma unroll
        for (int n = 0; n < NFR; n++) {
            int col = n0 + wc * WCOL + n * 16 + (lane & 15);
#pragma unroll
            for (int rg = 0; rg < 4; rg++) {
                int row = rbase + rg;
                float v = acc[m][n][rg];
                if (EPI == 0) {
                    Cb[(size_t)row * ldc + col] = f2bf(v + aux[col]);
                } else if (EPI == 1) {
                    Cb[(size_t)row * ldc + col] = f2bf(v + aux[row]);
                } else {
                    Cf[(size_t)row * ldc + col] = v * scale;
                }
            }
        }
    }
}

// ---------------- fused softmax: R = (1-g)*P_glob + g*P_loc, bf16 in place ----------------
// 1D grid (S_LEN * gcnt), XCD-swizzled. Reads the f32 scores row, computes both
// softmaxes' stats, writes the COMBINED gated probability row R as bf16 in place
// (first 4KB of the 8KB row). The PV GEMM then produces the final output directly.
__global__ __launch_bounds__(256)
void softmax_fuse(float* __restrict__ sc, const float* __restrict__ gate) {
    const int logical = xcd_logical();
    const int i = logical & (S_LEN - 1);
    const int z = logical >> 11;
    const int tid = threadIdx.x;
    const int wv = tid >> 6, lane = tid & 63;
    sc   += (size_t)z * S_LEN * S_LEN;
    gate += (size_t)z * S_LEN;

    __shared__ float r0[4], r1[4], mll[2];

    float* scrow = sc + (size_t)i * S_LEN;
    const float4* s4 = (const float4*)scrow;
    float4 a = s4[tid * 2], b = s4[tid * 2 + 1];

    // band bounds; band scores read pre-barrier (in-row only, no cross-block hazard)
    int jlo = i - WIN; if (jlo < 0) jlo = 0;
    int jhi = i + WIN; if (jhi > S_LEN - 1) jhi = S_LEN - 1;
    int cnt = jhi - jlo + 1;
    float bvv = (tid < cnt) ? scrow[jlo + tid] : -3.0e38f;
    float g = gate[i];

    float sv[8] = {a.x, a.y, a.z, a.w, b.x, b.y, b.z, b.w};

    // global row max
    float mx = fmaxf(fmaxf(fmaxf(sv[0], sv[1]), fmaxf(sv[2], sv[3])),
                     fmaxf(fmaxf(sv[4], sv[5]), fmaxf(sv[6], sv[7])));
#pragma unroll
    for (int o = 32; o; o >>= 1) mx = fmaxf(mx, __shfl_xor(mx, o));
    if (lane == 0) r0[wv] = mx;
    __syncthreads();
    float mg = fmaxf(fmaxf(r0[0], r0[1]), fmaxf(r0[2], r0[3]));

    float ev[8];
#pragma unroll
    for (int k = 0; k < 8; k++) ev[k] = __expf(sv[k] - mg);
    float se = ev[0] + ev[1] + ev[2] + ev[3] + ev[4] + ev[5] + ev[6] + ev[7];
#pragma unroll
    for (int o = 32; o; o >>= 1) se += __shfl_xor(se, o);
    if (lane == 0) r1[wv] = se;

    // band softmax stats: wave 0 alone (cnt <= 61, register-resident)
    if (wv == 0) {
        float ml = bvv;
#pragma unroll
        for (int o = 32; o; o >>= 1) ml = fmaxf(ml, __shfl_xor(ml, o));
        float e = (lane < cnt) ? __expf(bvv - ml) : 0.f;
        float s2 = e;
#pragma unroll
        for (int o = 32; o; o >>= 1) s2 += __shfl_xor(s2, o);
        if (lane == 0) { mll[0] = ml; mll[1] = 1.f / s2; }
    }
    __syncthreads();
    float invl = (1.f - g) / (r1[0] + r1[1] + r1[2] + r1[3]);
    float ml  = mll[0];
    float ill = g * mll[1];

    // R[col] = (1-g)*exp(s-mg)/lg + [|col-i|<=WIN] * g*exp(s-ml)/ll, bf16 in place
    const int c0 = tid * 8;
    u32 pk_[4];
#pragma unroll
    for (int h = 0; h < 4; h++) {
        float rA = ev[2 * h] * invl;
        float rB = ev[2 * h + 1] * invl;
        int colA = c0 + 2 * h;
        if ((u32)(colA - i + WIN) <= 2u * WIN)     rA += __expf(sv[2 * h] - ml) * ill;
        if ((u32)(colA + 1 - i + WIN) <= 2u * WIN) rB += __expf(sv[2 * h + 1] - ml) * ill;
        pk_[h] = (u32)f2bf(rA) | ((u32)f2bf(rB) << 16);
    }
    uint4 pw = {pk_[0], pk_[1], pk_[2], pk_[3]};
    ((uint4*)scrow)[tid] = pw;   // post-barrier: all row reads drained at barrier
}

// ---------------- launch ----------------
extern "C" void kernel_launch(void* const* d_in, const int* in_sizes, int n_in,
                              void* d_out, int out_size, void* d_ws, size_t ws_size,
                              hipStream_t stream) {
    const float* X  = (const float*)d_in[0];
    const float* Wq = (const float*)d_in[1];
    const float* bq = (const float*)d_in[2];
    const float* Wk = (const float*)d_in[3];
    const float* bk = (const float*)d_in[4];
    const float* Wv = (const float*)d_in[5];
    const float* bv = (const float*)d_in[6];
    const float* Wg = (const float*)d_in[7];
    const float* bg = (const float*)d_in[8];
    float* out = (float*)d_out;

    char* p = (char*)d_ws;
    u16* Xb    = (u16*)p;  p += (size_t)M_TOT * D_DIM * 2;           // 16 MB
    u16* Wt3   = (u16*)p;  p += (size_t)3 * D_DIM * D_DIM * 2;       // 1.5 MB
    u16* QKV   = (u16*)p;  p += (size_t)3 * M_TOT * D_DIM * 2;       // 48 MB
    u16* Vt    = (u16*)p;  p += (size_t)M_TOT * D_DIM * 2;           // 16 MB
    float* gate  = (float*)p; p += (size_t)M_TOT * 4;                // 64 KB
    float* bias3 = (float*)p; p += (size_t)3 * D_DIM * 4;            // 6 KB
    float* scores = (float*)p;                                       // nbuf * 16 MB
    size_t base_used = (size_t)(p - (char*)d_ws);
    size_t per_batch = (size_t)S_LEN * S_LEN * 4;
    int nbuf = (int)((ws_size - base_used) / per_batch);
    if (nbuf > B_N) nbuf = B_N;
    if (nbuf < 1) nbuf = 1;

    u16* Qb = QKV;
    u16* Kb = QKV + (size_t)M_TOT * D_DIM;

    convert_x<<<dim3(M_TOT * D_DIM / 4 / 256), 256, 0, stream>>>(X, Xb);
    transpose_w3<<<dim3(16, 16, 3), 256, 0, stream>>>(Wq, Wk, Wv, Wt3);
    pack_bias<<<dim3(2), 256, 0, stream>>>(bq, bk, bv, bias3);
    gate_kernel<<<dim3(M_TOT / 4), 256, 0, stream>>>(X, Wg, bg, gate);

    // Q/K/V projections in one dispatch: z selects weight/bias/output (1536 blocks)
    gemm_bt<0, 128><<<dim3(4 * 128 * 3), 256, 0, stream>>>(
        Xb, Wt3, 512, 512, 512, 4, 128, bias3, QKV, 512, 1.f,
        0LL, (long long)D_DIM * D_DIM, (long long)M_TOT * D_DIM, (long long)D_DIM);

    // Vt[d][t_global] = (Wv^T X^T) + bv[d]   (512 blocks)
    gemm_bt<1, 128><<<dim3(128 * 4), 256, 0, stream>>>(
        Wt3 + (size_t)2 * D_DIM * D_DIM, Xb, 512, 512, 512, 128, 4, bv, Vt, M_TOT, 1.f,
        0LL, 0LL, 0LL, 0LL);

    const float sc = 1.0f / sqrtf((float)D_DIM);
    for (int g0 = 0; g0 < B_N; g0 += nbuf) {
        int gcnt = B_N - g0 < nbuf ? B_N - g0 : nbuf;
        // scores[z][s][t] = (Q.K^T)/sqrt(D), f32  (256 blocks/batch -> one XCD each)
        gemm_bt<2, 128><<<dim3(16 * 16 * gcnt), 256, 0, stream>>>(
            Qb + (size_t)g0 * S_LEN * D_DIM, Kb + (size_t)g0 * S_LEN * D_DIM,
            512, 512, 512, 16, 16, nullptr, scores, S_LEN, sc,
            (long long)S_LEN * D_DIM, (long long)S_LEN * D_DIM,
            (long long)S_LEN * S_LEN, 0LL);
        // fused softmax: R = (1-g)*P_glob + g*P_loc, bf16 in place over scores
        softmax_fuse<<<dim3(S_LEN * gcnt), 256, 0, stream>>>(
            scores, gate + (size_t)g0 * S_LEN);
        // out = R * V  (single PV GEMM produces the final gated output, f32)
        // 128x128 tile -> 64 blocks/batch (2 blocks/CU), 16 MFMA/K-step/wave
        gemm_bt<2, 128><<<dim3(4 * 16 * gcnt), 256, 0, stream>>>(
            (const u16*)scores, Vt + (size_t)g0 * S_LEN,
            2 * S_LEN, M_TOT, S_LEN, 4, 16, nullptr,
            out + (size_t)g0 * S_LEN * D_DIM, 512, 1.f,
            (long long)S_LEN * 2 * S_LEN, (long long)S_LEN,
            (long long)S_LEN * D_DIM, 0LL);
    }
}

// Round 8
// 202.503 us; speedup vs baseline: 4.9770x; 1.0141x over previous
//
#include <hip/hip_runtime.h>
#include <math.h>

#define B_N   8
#define S_LEN 2048
#define D_DIM 512
#define M_TOT (B_N * S_LEN)   // 16384
#define WIN   30

typedef short bf16x8 __attribute__((ext_vector_type(8)));
typedef float f32x4  __attribute__((ext_vector_type(4)));
typedef unsigned short u16;
typedef unsigned int   u32;

__device__ __forceinline__ u16 f2bf(float f) {
    union { float f; u32 u; } v; v.f = f;
    u32 r = v.u + 0x7fffu + ((v.u >> 16) & 1u);
    return (u16)(r >> 16);
}

__device__ __forceinline__ void gl2lds(const u16* g, u16* l) {
    __builtin_amdgcn_global_load_lds((const __attribute__((address_space(1))) void*)g,
                                     (__attribute__((address_space(3))) void*)l,
                                     16, 0, 0);
}

// bijective chunked XCD swizzle: hw block hb -> logical index such that
// XCD (hb%8) owns one contiguous logical chunk. Requires gridDim.x % 8 == 0.
__device__ __forceinline__ int xcd_logical() {
    const int n = gridDim.x;
    const int hb = blockIdx.x;
    return (hb & 7) * (n >> 3) + (hb >> 3);
}

// ---------------- fused convert + gate: Xb = bf16(X); gate = sigmoid(X.Wg+bg) ----------------
// one wave per row (grid M_TOT/4, 256 thr)
__global__ __launch_bounds__(256)
void convert_gate(const float* __restrict__ X, const float* __restrict__ Wg,
                  const float* __restrict__ bg, u16* __restrict__ Xb, float* __restrict__ gate) {
    int wv = threadIdx.x >> 6, lane = threadIdx.x & 63;
    int row = blockIdx.x * 4 + wv;
    const float4* x4 = (const float4*)(X + (size_t)row * D_DIM);
    const float4* w4 = (const float4*)Wg;
    float acc = 0.f;
    ushort4 o0, o1;
    {
        float4 a = x4[lane * 2], w = w4[lane * 2];
        acc += a.x * w.x + a.y * w.y + a.z * w.z + a.w * w.w;
        o0.x = f2bf(a.x); o0.y = f2bf(a.y); o0.z = f2bf(a.z); o0.w = f2bf(a.w);
        float4 b = x4[lane * 2 + 1], v = w4[lane * 2 + 1];
        acc += b.x * v.x + b.y * v.y + b.z * v.z + b.w * v.w;
        o1.x = f2bf(b.x); o1.y = f2bf(b.y); o1.z = f2bf(b.z); o1.w = f2bf(b.w);
    }
    ushort4* xb4 = (ushort4*)(Xb + (size_t)row * D_DIM);
    xb4[lane * 2] = o0;
    xb4[lane * 2 + 1] = o1;
#pragma unroll
    for (int o = 32; o; o >>= 1) acc += __shfl_xor(acc, o);
    if (lane == 0) gate[row] = 1.f / (1.f + __expf(-(acc + bg[0])));
}

// Wt3[z][n][k] = bf16(W_z[k][n]); grid (16,16,3)
__global__ __launch_bounds__(256) void transpose_w3(const float* __restrict__ Wq, const float* __restrict__ Wk,
                                                    const float* __restrict__ Wv, u16* __restrict__ Wt3) {
    const float* W = blockIdx.z == 0 ? Wq : (blockIdx.z == 1 ? Wk : Wv);
    u16* Wt = Wt3 + (size_t)blockIdx.z * D_DIM * D_DIM;
    __shared__ float t[32][33];
    int k0 = blockIdx.x * 32, n0 = blockIdx.y * 32;
    int tx = threadIdx.x & 31, ty = threadIdx.x >> 5;   // 32 x 8
#pragma unroll
    for (int r = ty; r < 32; r += 8) t[r][tx] = W[(size_t)(k0 + r) * D_DIM + n0 + tx];
    __syncthreads();
#pragma unroll
    for (int r = ty; r < 32; r += 8) Wt[(size_t)(n0 + r) * D_DIM + k0 + tx] = f2bf(t[tx][r]);
}

__global__ __launch_bounds__(256) void pack_bias(const float* __restrict__ bq, const float* __restrict__ bk,
                                                 const float* __restrict__ bv, float* __restrict__ b3) {
    int i = blockIdx.x * 256 + threadIdx.x;   // grid 2 -> i in [0,512)
    b3[i] = bq[i]; b3[512 + i] = bk[i]; b3[1024 + i] = bv[i];
}

// ---------------- the one GEMM: C = A * Bt^T, 1D grid, XCD-swizzled ----------------
// logical = x + nx*y + nx*ny*z  (x fastest, z slowest -> one batch per XCD chunk)
// A: bf16 [M][lda], Bt: bf16 [N][ldb]
// tile 128x128, BK=32, 4 waves (2x2), 16x16x32 bf16 MFMA, 4x4 frags/wave
// 4-BUFFER counted-vmcnt pipeline (T3+T4): tiles staged 3 ahead; per tile:
//   s_waitcnt vmcnt(8)  (drain ONLY tile t; 8 newer loads stay in flight)
//   s_barrier + compiler fence
//   stage(t+3) into buf[(t+3)&3]   (WAR-safe: last read at compute(t-1),
//                                   finished by all waves before this barrier)
//   compute(buf[t&3])
// Tail peels 2 iters with vmcnt(4)/vmcnt(0). Requires K/32 >= 4.
// LDS k-slot XOR swizzle (slot ^= (row>>1)&3): pre-swizzled global source
// (gl2lds dest stays linear) + swizzled ds_read slot -> zero bank conflicts.
// EPI 0: bf16 out + col bias(aux) | 1: bf16 out + row bias(aux) | 2: f32 out * scale
#define VM_WAIT(N) asm volatile("s_waitcnt vmcnt(" #N ")" ::: "memory")
#define BAR() do { __builtin_amdgcn_s_barrier(); asm volatile("" ::: "memory"); } while (0)

template<int EPI>
__global__ __launch_bounds__(256)
void gemm_bt(const u16* __restrict__ A, const u16* __restrict__ Bt,
             int lda, int ldb, int K, int nx, int ny,
             const float* __restrict__ aux, void* __restrict__ Cv, int ldc, float scale,
             long long zA, long long zB, long long zC, long long zAux) {
    const int logical = xcd_logical();
    const int x = logical % nx;
    const int t2 = logical / nx;
    const int y = t2 % ny;
    const int z = t2 / ny;

    A   += zA * z;
    Bt  += zB * z;
    if (aux) aux += zAux * z;

    __shared__ u16 smem[4 * 8192];     // 4 buffers x (A 4096 + B 4096) u16 = 64 KB
    const int tid  = threadIdx.x;
    const int lane = tid & 63;
    const int wave = tid >> 6;
    const int wr = wave >> 1, wc = wave & 1;
    const int m0 = y * 128, n0 = x * 128;

    f32x4 acc[4][4];
#pragma unroll
    for (int i = 0; i < 4; i++)
#pragma unroll
        for (int j = 0; j < 4; j++) acc[i][j] = (f32x4){0.f, 0.f, 0.f, 0.f};

    // staging: chunk c (16B) -> LDS linear offset c*16B = (row=c>>2, slot=c&3);
    // global k-slot loaded = slot ^ ((row>>1)&3) = (c&3)^((c>>3)&3)  [swizzle]
    const int c0 = tid, c1 = tid + 256;
    const int r0c = c0 >> 2, k0c = (((c0 & 3) ^ ((c0 >> 3) & 3)) << 3);
    const int r1c = c1 >> 2, k1c = (((c1 & 3) ^ ((c1 >> 3) & 3)) << 3);

    auto stage = [&](int b, int k0) {
        u16* dA = smem + b * 8192 + wave * 512;
        u16* dB = smem + b * 8192 + 4096 + wave * 512;
        gl2lds(A + (size_t)(m0 + r0c) * lda + (k0 + k0c), dA);
        gl2lds(A + (size_t)(m0 + r1c) * lda + (k0 + k1c), dA + 2048);
        gl2lds(Bt + (size_t)(n0 + r0c) * ldb + (k0 + k0c), dB);
        gl2lds(Bt + (size_t)(n0 + r1c) * ldb + (k0 + k1c), dB + 2048);
    };
    auto compute = [&](int b) {
        const u16* bA = smem + b * 8192;
        const u16* bB = smem + b * 8192 + 4096;
        const int ks = lane >> 4;
        bf16x8 af[4], bfr[4];
#pragma unroll
        for (int m = 0; m < 4; m++) {
            int r = wr * 64 + m * 16 + (lane & 15);
            int s = ks ^ ((r >> 1) & 3);
            af[m] = *(const bf16x8*)&bA[r * 32 + s * 8];
        }
#pragma unroll
        for (int n = 0; n < 4; n++) {
            int r = wc * 64 + n * 16 + (lane & 15);
            int s = ks ^ ((r >> 1) & 3);
            bfr[n] = *(const bf16x8*)&bB[r * 32 + s * 8];
        }
#pragma unroll
        for (int m = 0; m < 4; m++)
#pragma unroll
            for (int n = 0; n < 4; n++)
                acc[m][n] = __builtin_amdgcn_mfma_f32_16x16x32_bf16(af[m], bfr[n], acc[m][n], 0, 0, 0);
    };

    const int nt = K >> 5;   // >= 4 for all call sites (K in {512, 2048})
    stage(0, 0); stage(1, 32); stage(2, 64);   // 12 loads in flight

    int t = 0;
    for (; t < nt - 2; ++t) {
        VM_WAIT(8);            // drain tile t only
        BAR();
        if (t + 3 < nt) stage((t + 3) & 3, (t + 3) << 5);
        compute(t & 3);
    }
    VM_WAIT(4);                // drain tile nt-2
    BAR();
    compute((nt - 2) & 3);
    VM_WAIT(0);                // drain tile nt-1
    BAR();
    compute((nt - 1) & 3);

    u16*   Cb = (EPI <= 1) ? ((u16*)Cv + zC * z) : nullptr;
    float* Cf = (EPI >= 2) ? ((float*)Cv + zC * z) : nullptr;

    // epilogue: C/D map row=(lane>>4)*4+reg, col=lane&15  [verified m89]
#pragma unroll
    for (int m = 0; m < 4; m++) {
        int rbase = m0 + wr * 64 + m * 16 + ((lane >> 4) << 2);
#pragma unroll
        for (int n = 0; n < 4; n++) {
            int col = n0 + wc * 64 + n * 16 + (lane & 15);
#pragma unroll
            for (int rg = 0; rg < 4; rg++) {
                int row = rbase + rg;
                float v = acc[m][n][rg];
                if (EPI == 0) {
                    Cb[(size_t)row * ldc + col] = f2bf(v + aux[col]);
                } else if (EPI == 1) {
                    Cb[(size_t)row * ldc + col] = f2bf(v + aux[row]);
                } else {
                    Cf[(size_t)row * ldc + col] = v * scale;
                }
            }
        }
    }
}

// ---------------- fused softmax: R = (1-g)*P_glob + g*P_loc, bf16 in place ----------------
// 1D grid (S_LEN * gcnt), XCD-swizzled. Reads the f32 scores row, computes both
// softmaxes' stats, writes the COMBINED gated probability row R as bf16 in place
// (first 4KB of the 8KB row). The PV GEMM then produces the final output directly.
__global__ __launch_bounds__(256)
void softmax_fuse(float* __restrict__ sc, const float* __restrict__ gate) {
    const int logical = xcd_logical();
    const int i = logical & (S_LEN - 1);
    const int z = logical >> 11;
    const int tid = threadIdx.x;
    const int wv = tid >> 6, lane = tid & 63;
    sc   += (size_t)z * S_LEN * S_LEN;
    gate += (size_t)z * S_LEN;

    __shared__ float r0[4], r1[4], mll[2];

    float* scrow = sc + (size_t)i * S_LEN;
    const float4* s4 = (const float4*)scrow;
    float4 a = s4[tid * 2], b = s4[tid * 2 + 1];

    // band bounds; band scores read pre-barrier (in-row only, no cross-block hazard)
    int jlo = i - WIN; if (jlo < 0) jlo = 0;
    int jhi = i + WIN; if (jhi > S_LEN - 1) jhi = S_LEN - 1;
    int cnt = jhi - jlo + 1;
    float bvv = (tid < cnt) ? scrow[jlo + tid] : -3.0e38f;
    float g = gate[i];

    float sv[8] = {a.x, a.y, a.z, a.w, b.x, b.y, b.z, b.w};

    // global row max
    float mx = fmaxf(fmaxf(fmaxf(sv[0], sv[1]), fmaxf(sv[2], sv[3])),
                     fmaxf(fmaxf(sv[4], sv[5]), fmaxf(sv[6], sv[7])));
#pragma unroll
    for (int o = 32; o; o >>= 1) mx = fmaxf(mx, __shfl_xor(mx, o));
    if (lane == 0) r0[wv] = mx;
    __syncthreads();
    float mg = fmaxf(fmaxf(r0[0], r0[1]), fmaxf(r0[2], r0[3]));

    float ev[8];
#pragma unroll
    for (int k = 0; k < 8; k++) ev[k] = __expf(sv[k] - mg);
    float se = ev[0] + ev[1] + ev[2] + ev[3] + ev[4] + ev[5] + ev[6] + ev[7];
#pragma unroll
    for (int o = 32; o; o >>= 1) se += __shfl_xor(se, o);
    if (lane == 0) r1[wv] = se;

    // band softmax stats: wave 0 alone (cnt <= 61, register-resident)
    if (wv == 0) {
        float ml = bvv;
#pragma unroll
        for (int o = 32; o; o >>= 1) ml = fmaxf(ml, __shfl_xor(ml, o));
        float e = (lane < cnt) ? __expf(bvv - ml) : 0.f;
        float s2 = e;
#pragma unroll
        for (int o = 32; o; o >>= 1) s2 += __shfl_xor(s2, o);
        if (lane == 0) { mll[0] = ml; mll[1] = 1.f / s2; }
    }
    __syncthreads();
    float invl = (1.f - g) / (r1[0] + r1[1] + r1[2] + r1[3]);
    float ml  = mll[0];
    float ill = g * mll[1];

    // R[col] = (1-g)*exp(s-mg)/lg + [|col-i|<=WIN] * g*exp(s-ml)/ll, bf16 in place
    const int c0 = tid * 8;
    u32 pk_[4];
#pragma unroll
    for (int h = 0; h < 4; h++) {
        float rA = ev[2 * h] * invl;
        float rB = ev[2 * h + 1] * invl;
        int colA = c0 + 2 * h;
        if ((u32)(colA - i + WIN) <= 2u * WIN)     rA += __expf(sv[2 * h] - ml) * ill;
        if ((u32)(colA + 1 - i + WIN) <= 2u * WIN) rB += __expf(sv[2 * h + 1] - ml) * ill;
        pk_[h] = (u32)f2bf(rA) | ((u32)f2bf(rB) << 16);
    }
    uint4 pw = {pk_[0], pk_[1], pk_[2], pk_[3]};
    ((uint4*)scrow)[tid] = pw;   // post-barrier: all row reads drained at barrier
}

// ---------------- launch ----------------
extern "C" void kernel_launch(void* const* d_in, const int* in_sizes, int n_in,
                              void* d_out, int out_size, void* d_ws, size_t ws_size,
                              hipStream_t stream) {
    const float* X  = (const float*)d_in[0];
    const float* Wq = (const float*)d_in[1];
    const float* bq = (const float*)d_in[2];
    const float* Wk = (const float*)d_in[3];
    const float* bk = (const float*)d_in[4];
    const float* Wv = (const float*)d_in[5];
    const float* bv = (const float*)d_in[6];
    const float* Wg = (const float*)d_in[7];
    const float* bg = (const float*)d_in[8];
    float* out = (float*)d_out;

    char* p = (char*)d_ws;
    u16* Xb    = (u16*)p;  p += (size_t)M_TOT * D_DIM * 2;           // 16 MB
    u16* Wt3   = (u16*)p;  p += (size_t)3 * D_DIM * D_DIM * 2;       // 1.5 MB
    u16* QKV   = (u16*)p;  p += (size_t)3 * M_TOT * D_DIM * 2;       // 48 MB
    u16* Vt    = (u16*)p;  p += (size_t)M_TOT * D_DIM * 2;           // 16 MB
    float* gate  = (float*)p; p += (size_t)M_TOT * 4;                // 64 KB
    float* bias3 = (float*)p; p += (size_t)3 * D_DIM * 4;            // 6 KB
    float* scores = (float*)p;                                       // nbuf * 16 MB
    size_t base_used = (size_t)(p - (char*)d_ws);
    size_t per_batch = (size_t)S_LEN * S_LEN * 4;
    int nbuf = (int)((ws_size - base_used) / per_batch);
    if (nbuf > B_N) nbuf = B_N;
    if (nbuf < 1) nbuf = 1;

    u16* Qb = QKV;
    u16* Kb = QKV + (size_t)M_TOT * D_DIM;

    convert_gate<<<dim3(M_TOT / 4), 256, 0, stream>>>(X, Wg, bg, Xb, gate);
    transpose_w3<<<dim3(16, 16, 3), 256, 0, stream>>>(Wq, Wk, Wv, Wt3);
    pack_bias<<<dim3(2), 256, 0, stream>>>(bq, bk, bv, bias3);

    // Q/K/V projections in one dispatch: z selects weight/bias/output (1536 blocks)
    gemm_bt<0><<<dim3(4 * 128 * 3), 256, 0, stream>>>(
        Xb, Wt3, 512, 512, 512, 4, 128, bias3, QKV, 512, 1.f,
        0LL, (long long)D_DIM * D_DIM, (long long)M_TOT * D_DIM, (long long)D_DIM);

    // Vt[d][t_global] = (Wv^T X^T) + bv[d]   (512 blocks)
    gemm_bt<1><<<dim3(128 * 4), 256, 0, stream>>>(
        Wt3 + (size_t)2 * D_DIM * D_DIM, Xb, 512, 512, 512, 128, 4, bv, Vt, M_TOT, 1.f,
        0LL, 0LL, 0LL, 0LL);

    const float sc = 1.0f / sqrtf((float)D_DIM);
    for (int g0 = 0; g0 < B_N; g0 += nbuf) {
        int gcnt = B_N - g0 < nbuf ? B_N - g0 : nbuf;
        // scores[z][s][t] = (Q.K^T)/sqrt(D), f32  (256 blocks/batch -> one XCD each)
        gemm_bt<2><<<dim3(16 * 16 * gcnt), 256, 0, stream>>>(
            Qb + (size_t)g0 * S_LEN * D_DIM, Kb + (size_t)g0 * S_LEN * D_DIM,
            512, 512, 512, 16, 16, nullptr, scores, S_LEN, sc,
            (long long)S_LEN * D_DIM, (long long)S_LEN * D_DIM,
            (long long)S_LEN * S_LEN, 0LL);
        // fused softmax: R = (1-g)*P_glob + g*P_loc, bf16 in place over scores
        softmax_fuse<<<dim3(S_LEN * gcnt), 256, 0, stream>>>(
            scores, gate + (size_t)g0 * S_LEN);
        // out = R * V  (single PV GEMM produces the final gated output, f32)
        gemm_bt<2><<<dim3(4 * 16 * gcnt), 256, 0, stream>>>(
            (const u16*)scores, Vt + (size_t)g0 * S_LEN,
            2 * S_LEN, M_TOT, S_LEN, 4, 16, nullptr,
            out + (size_t)g0 * S_LEN * D_DIM, 512, 1.f,
            (long long)S_LEN * 2 * S_LEN, (long long)S_LEN,
            (long long)S_LEN * D_DIM, 0LL);
    }
}

// Round 9
// 187.553 us; speedup vs baseline: 5.3738x; 1.0797x over previous
//
#include <hip/hip_runtime.h>
#include <math.h>

#define B_N   8
#define S_LEN 2048
#define D_DIM 512
#define M_TOT (B_N * S_LEN)   // 16384
#define WIN   30

typedef short bf16x8 __attribute__((ext_vector_type(8)));
typedef float f32x4  __attribute__((ext_vector_type(4)));
typedef unsigned short u16;
typedef unsigned int   u32;

__device__ __forceinline__ u16 f2bf(float f) {
    union { float f; u32 u; } v; v.f = f;
    u32 r = v.u + 0x7fffu + ((v.u >> 16) & 1u);
    return (u16)(r >> 16);
}

__device__ __forceinline__ void gl2lds(const u16* g, u16* l) {
    __builtin_amdgcn_global_load_lds((const __attribute__((address_space(1))) void*)g,
                                     (__attribute__((address_space(3))) void*)l,
                                     16, 0, 0);
}

// bijective chunked XCD swizzle: hw block hb -> logical index such that
// XCD (hb%8) owns one contiguous logical chunk. Requires gridDim.x % 8 == 0.
__device__ __forceinline__ int xcd_logical() {
    const int n = gridDim.x;
    const int hb = blockIdx.x;
    return (hb & 7) * (n >> 3) + (hb >> 3);
}

// ---------------- fused convert + gate: Xb = bf16(X); gate = sigmoid(X.Wg+bg) ----------------
// one wave per row (grid M_TOT/4, 256 thr)
__global__ __launch_bounds__(256)
void convert_gate(const float* __restrict__ X, const float* __restrict__ Wg,
                  const float* __restrict__ bg, u16* __restrict__ Xb, float* __restrict__ gate) {
    int wv = threadIdx.x >> 6, lane = threadIdx.x & 63;
    int row = blockIdx.x * 4 + wv;
    const float4* x4 = (const float4*)(X + (size_t)row * D_DIM);
    const float4* w4 = (const float4*)Wg;
    float acc = 0.f;
    ushort4 o0, o1;
    {
        float4 a = x4[lane * 2], w = w4[lane * 2];
        acc += a.x * w.x + a.y * w.y + a.z * w.z + a.w * w.w;
        o0.x = f2bf(a.x); o0.y = f2bf(a.y); o0.z = f2bf(a.z); o0.w = f2bf(a.w);
        float4 b = x4[lane * 2 + 1], v = w4[lane * 2 + 1];
        acc += b.x * v.x + b.y * v.y + b.z * v.z + b.w * v.w;
        o1.x = f2bf(b.x); o1.y = f2bf(b.y); o1.z = f2bf(b.z); o1.w = f2bf(b.w);
    }
    ushort4* xb4 = (ushort4*)(Xb + (size_t)row * D_DIM);
    xb4[lane * 2] = o0;
    xb4[lane * 2 + 1] = o1;
#pragma unroll
    for (int o = 32; o; o >>= 1) acc += __shfl_xor(acc, o);
    if (lane == 0) gate[row] = 1.f / (1.f + __expf(-(acc + bg[0])));
}

// Wt3[z][n][k] = bf16(W_z[k][n]); grid (16,16,3)
__global__ __launch_bounds__(256) void transpose_w3(const float* __restrict__ Wq, const float* __restrict__ Wk,
                                                    const float* __restrict__ Wv, u16* __restrict__ Wt3) {
    const float* W = blockIdx.z == 0 ? Wq : (blockIdx.z == 1 ? Wk : Wv);
    u16* Wt = Wt3 + (size_t)blockIdx.z * D_DIM * D_DIM;
    __shared__ float t[32][33];
    int k0 = blockIdx.x * 32, n0 = blockIdx.y * 32;
    int tx = threadIdx.x & 31, ty = threadIdx.x >> 5;   // 32 x 8
#pragma unroll
    for (int r = ty; r < 32; r += 8) t[r][tx] = W[(size_t)(k0 + r) * D_DIM + n0 + tx];
    __syncthreads();
#pragma unroll
    for (int r = ty; r < 32; r += 8) Wt[(size_t)(n0 + r) * D_DIM + k0 + tx] = f2bf(t[tx][r]);
}

__global__ __launch_bounds__(256) void pack_bias(const float* __restrict__ bq, const float* __restrict__ bk,
                                                 const float* __restrict__ bv, float* __restrict__ b3) {
    int i = blockIdx.x * 256 + threadIdx.x;   // grid 2 -> i in [0,512)
    b3[i] = bq[i]; b3[512 + i] = bk[i]; b3[1024 + i] = bv[i];
}

// ---------------- the one GEMM: C = A * Bt^T, 1D grid, XCD-swizzled ----------------
// logical = x + nx*y + nx*ny*z  (x fastest, z slowest -> one batch per XCD chunk)
// A: bf16 [M][lda], Bt: bf16 [N][ldb]
// tile 128x128, BK=32, 4 waves (2x2), 16x16x32 bf16 MFMA, 4x4 frags/wave
// 3-BUFFER counted-vmcnt pipeline (T3+T4), 48 KB LDS -> 3 blocks/CU:
//   prologue: stage(0), stage(1)            (8 loads in flight)
//   iter t:   s_waitcnt vmcnt(4)            (drain ONLY tile t)
//             s_barrier + fence
//             stage(t+2) into buf[(t+2)%3]  (WAR-safe: last read at compute(t-1),
//                                            finished by all waves pre-barrier)
//             compute(buf[t%3])
//   tail:     vmcnt(0), barrier, compute(nt-1)
// __launch_bounds__(256,6) caps VGPR ~85 so 24 waves/CU materialize.
// LDS k-slot XOR swizzle (slot ^= (row>>1)&3): pre-swizzled global source
// (gl2lds dest stays linear) + swizzled ds_read slot -> zero bank conflicts.
// EPI 0: bf16 out + col bias(aux) | 1: bf16 out + row bias(aux) | 2: f32 out * scale
#define VM_WAIT(N) asm volatile("s_waitcnt vmcnt(" #N ")" ::: "memory")
#define BAR() do { __builtin_amdgcn_s_barrier(); asm volatile("" ::: "memory"); } while (0)

template<int EPI>
__global__ __launch_bounds__(256, 6)
void gemm_bt(const u16* __restrict__ A, const u16* __restrict__ Bt,
             int lda, int ldb, int K, int nx, int ny,
             const float* __restrict__ aux, void* __restrict__ Cv, int ldc, float scale,
             long long zA, long long zB, long long zC, long long zAux) {
    const int logical = xcd_logical();
    const int x = logical % nx;
    const int t2 = logical / nx;
    const int y = t2 % ny;
    const int z = t2 / ny;

    A   += zA * z;
    Bt  += zB * z;
    if (aux) aux += zAux * z;

    __shared__ u16 smem[3 * 8192];     // 3 buffers x (A 4096 + B 4096) u16 = 48 KB
    const int tid  = threadIdx.x;
    const int lane = tid & 63;
    const int wave = tid >> 6;
    const int wr = wave >> 1, wc = wave & 1;
    const int m0 = y * 128, n0 = x * 128;

    f32x4 acc[4][4];
#pragma unroll
    for (int i = 0; i < 4; i++)
#pragma unroll
        for (int j = 0; j < 4; j++) acc[i][j] = (f32x4){0.f, 0.f, 0.f, 0.f};

    // staging: chunk c (16B) -> LDS linear offset c*16B = (row=c>>2, slot=c&3);
    // global k-slot loaded = slot ^ ((row>>1)&3) = (c&3)^((c>>3)&3)  [swizzle]
    const int c0 = tid, c1 = tid + 256;
    const int r0c = c0 >> 2, k0c = (((c0 & 3) ^ ((c0 >> 3) & 3)) << 3);
    const int r1c = c1 >> 2, k1c = (((c1 & 3) ^ ((c1 >> 3) & 3)) << 3);

    auto stage = [&](int b, int k0) {
        u16* dA = smem + b * 8192 + wave * 512;
        u16* dB = smem + b * 8192 + 4096 + wave * 512;
        gl2lds(A + (size_t)(m0 + r0c) * lda + (k0 + k0c), dA);
        gl2lds(A + (size_t)(m0 + r1c) * lda + (k0 + k1c), dA + 2048);
        gl2lds(Bt + (size_t)(n0 + r0c) * ldb + (k0 + k0c), dB);
        gl2lds(Bt + (size_t)(n0 + r1c) * ldb + (k0 + k1c), dB + 2048);
    };
    auto compute = [&](int b) {
        const u16* bA = smem + b * 8192;
        const u16* bB = smem + b * 8192 + 4096;
        const int ks = lane >> 4;
        bf16x8 af[4], bfr[4];
#pragma unroll
        for (int m = 0; m < 4; m++) {
            int r = wr * 64 + m * 16 + (lane & 15);
            int s = ks ^ ((r >> 1) & 3);
            af[m] = *(const bf16x8*)&bA[r * 32 + s * 8];
        }
#pragma unroll
        for (int n = 0; n < 4; n++) {
            int r = wc * 64 + n * 16 + (lane & 15);
            int s = ks ^ ((r >> 1) & 3);
            bfr[n] = *(const bf16x8*)&bB[r * 32 + s * 8];
        }
#pragma unroll
        for (int m = 0; m < 4; m++)
#pragma unroll
            for (int n = 0; n < 4; n++)
                acc[m][n] = __builtin_amdgcn_mfma_f32_16x16x32_bf16(af[m], bfr[n], acc[m][n], 0, 0, 0);
    };

    const int nt = K >> 5;   // >= 4 for all call sites (K in {512, 2048})
    stage(0, 0); stage(1, 32);   // 8 loads in flight

    int t = 0;
    for (; t < nt - 1; ++t) {
        VM_WAIT(4);            // drain tile t only (tile t+1's 4 loads stay in flight)
        BAR();
        if (t + 2 < nt) stage((t + 2) % 3, (t + 2) << 5);
        compute(t % 3);
    }
    VM_WAIT(0);                // drain tile nt-1
    BAR();
    compute((nt - 1) % 3);

    u16*   Cb = (EPI <= 1) ? ((u16*)Cv + zC * z) : nullptr;
    float* Cf = (EPI >= 2) ? ((float*)Cv + zC * z) : nullptr;

    // epilogue: C/D map row=(lane>>4)*4+reg, col=lane&15  [verified m89]
#pragma unroll
    for (int m = 0; m < 4; m++) {
        int rbase = m0 + wr * 64 + m * 16 + ((lane >> 4) << 2);
#pragma unroll
        for (int n = 0; n < 4; n++) {
            int col = n0 + wc * 64 + n * 16 + (lane & 15);
#pragma unroll
            for (int rg = 0; rg < 4; rg++) {
                int row = rbase + rg;
                float v = acc[m][n][rg];
                if (EPI == 0) {
                    Cb[(size_t)row * ldc + col] = f2bf(v + aux[col]);
                } else if (EPI == 1) {
                    Cb[(size_t)row * ldc + col] = f2bf(v + aux[row]);
                } else {
                    Cf[(size_t)row * ldc + col] = v * scale;
                }
            }
        }
    }
}

// ---------------- fused softmax: R = (1-g)*P_glob + g*P_loc, bf16 in place ----------------
// 1D grid (S_LEN * gcnt), XCD-swizzled. Reads the f32 scores row, computes both
// softmaxes' stats, writes the COMBINED gated probability row R as bf16 in place
// (first 4KB of the 8KB row). The PV GEMM then produces the final output directly.
__global__ __launch_bounds__(256)
void softmax_fuse(float* __restrict__ sc, const float* __restrict__ gate) {
    const int logical = xcd_logical();
    const int i = logical & (S_LEN - 1);
    const int z = logical >> 11;
    const int tid = threadIdx.x;
    const int wv = tid >> 6, lane = tid & 63;
    sc   += (size_t)z * S_LEN * S_LEN;
    gate += (size_t)z * S_LEN;

    __shared__ float r0[4], r1[4], mll[2];

    float* scrow = sc + (size_t)i * S_LEN;
    const float4* s4 = (const float4*)scrow;
    float4 a = s4[tid * 2], b = s4[tid * 2 + 1];

    // band bounds; band scores read pre-barrier (in-row only, no cross-block hazard)
    int jlo = i - WIN; if (jlo < 0) jlo = 0;
    int jhi = i + WIN; if (jhi > S_LEN - 1) jhi = S_LEN - 1;
    int cnt = jhi - jlo + 1;
    float bvv = (tid < cnt) ? scrow[jlo + tid] : -3.0e38f;
    float g = gate[i];

    float sv[8] = {a.x, a.y, a.z, a.w, b.x, b.y, b.z, b.w};

    // global row max
    float mx = fmaxf(fmaxf(fmaxf(sv[0], sv[1]), fmaxf(sv[2], sv[3])),
                     fmaxf(fmaxf(sv[4], sv[5]), fmaxf(sv[6], sv[7])));
#pragma unroll
    for (int o = 32; o; o >>= 1) mx = fmaxf(mx, __shfl_xor(mx, o));
    if (lane == 0) r0[wv] = mx;
    __syncthreads();
    float mg = fmaxf(fmaxf(r0[0], r0[1]), fmaxf(r0[2], r0[3]));

    float ev[8];
#pragma unroll
    for (int k = 0; k < 8; k++) ev[k] = __expf(sv[k] - mg);
    float se = ev[0] + ev[1] + ev[2] + ev[3] + ev[4] + ev[5] + ev[6] + ev[7];
#pragma unroll
    for (int o = 32; o; o >>= 1) se += __shfl_xor(se, o);
    if (lane == 0) r1[wv] = se;

    // band softmax stats: wave 0 alone (cnt <= 61, register-resident)
    if (wv == 0) {
        float ml = bvv;
#pragma unroll
        for (int o = 32; o; o >>= 1) ml = fmaxf(ml, __shfl_xor(ml, o));
        float e = (lane < cnt) ? __expf(bvv - ml) : 0.f;
        float s2 = e;
#pragma unroll
        for (int o = 32; o; o >>= 1) s2 += __shfl_xor(s2, o);
        if (lane == 0) { mll[0] = ml; mll[1] = 1.f / s2; }
    }
    __syncthreads();
    float invl = (1.f - g) / (r1[0] + r1[1] + r1[2] + r1[3]);
    float ml  = mll[0];
    float ill = g * mll[1];

    // R[col] = (1-g)*exp(s-mg)/lg + [|col-i|<=WIN] * g*exp(s-ml)/ll, bf16 in place
    const int c0 = tid * 8;
    u32 pk_[4];
#pragma unroll
    for (int h = 0; h < 4; h++) {
        float rA = ev[2 * h] * invl;
        float rB = ev[2 * h + 1] * invl;
        int colA = c0 + 2 * h;
        if ((u32)(colA - i + WIN) <= 2u * WIN)     rA += __expf(sv[2 * h] - ml) * ill;
        if ((u32)(colA + 1 - i + WIN) <= 2u * WIN) rB += __expf(sv[2 * h + 1] - ml) * ill;
        pk_[h] = (u32)f2bf(rA) | ((u32)f2bf(rB) << 16);
    }
    uint4 pw = {pk_[0], pk_[1], pk_[2], pk_[3]};
    ((uint4*)scrow)[tid] = pw;   // post-barrier: all row reads drained at barrier
}

// ---------------- launch ----------------
extern "C" void kernel_launch(void* const* d_in, const int* in_sizes, int n_in,
                              void* d_out, int out_size, void* d_ws, size_t ws_size,
                              hipStream_t stream) {
    const float* X  = (const float*)d_in[0];
    const float* Wq = (const float*)d_in[1];
    const float* bq = (const float*)d_in[2];
    const float* Wk = (const float*)d_in[3];
    const float* bk = (const float*)d_in[4];
    const float* Wv = (const float*)d_in[5];
    const float* bv = (const float*)d_in[6];
    const float* Wg = (const float*)d_in[7];
    const float* bg = (const float*)d_in[8];
    float* out = (float*)d_out;

    char* p = (char*)d_ws;
    u16* Xb    = (u16*)p;  p += (size_t)M_TOT * D_DIM * 2;           // 16 MB
    u16* Wt3   = (u16*)p;  p += (size_t)3 * D_DIM * D_DIM * 2;       // 1.5 MB
    u16* QKV   = (u16*)p;  p += (size_t)2 * M_TOT * D_DIM * 2;       // 32 MB (Q,K only)
    u16* Vt    = (u16*)p;  p += (size_t)M_TOT * D_DIM * 2;           // 16 MB
    float* gate  = (float*)p; p += (size_t)M_TOT * 4;                // 64 KB
    float* bias3 = (float*)p; p += (size_t)3 * D_DIM * 4;            // 6 KB
    float* scores = (float*)p;                                       // nbuf * 16 MB
    size_t base_used = (size_t)(p - (char*)d_ws);
    size_t per_batch = (size_t)S_LEN * S_LEN * 4;
    int nbuf = (int)((ws_size - base_used) / per_batch);
    if (nbuf > B_N) nbuf = B_N;
    if (nbuf < 1) nbuf = 1;

    u16* Qb = QKV;
    u16* Kb = QKV + (size_t)M_TOT * D_DIM;

    convert_gate<<<dim3(M_TOT / 4), 256, 0, stream>>>(X, Wg, bg, Xb, gate);
    transpose_w3<<<dim3(16, 16, 3), 256, 0, stream>>>(Wq, Wk, Wv, Wt3);
    pack_bias<<<dim3(2), 256, 0, stream>>>(bq, bk, bv, bias3);

    // Q/K projections in one dispatch: z selects weight/bias/output (1024 blocks).
    // (V itself is dead — only Vt is consumed by the PV GEMM.)
    gemm_bt<0><<<dim3(4 * 128 * 2), 256, 0, stream>>>(
        Xb, Wt3, 512, 512, 512, 4, 128, bias3, QKV, 512, 1.f,
        0LL, (long long)D_DIM * D_DIM, (long long)M_TOT * D_DIM, (long long)D_DIM);

    // Vt[d][t_global] = (Wv^T X^T) + bv[d]   (512 blocks)
    gemm_bt<1><<<dim3(128 * 4), 256, 0, stream>>>(
        Wt3 + (size_t)2 * D_DIM * D_DIM, Xb, 512, 512, 512, 128, 4, bv, Vt, M_TOT, 1.f,
        0LL, 0LL, 0LL, 0LL);

    const float sc = 1.0f / sqrtf((float)D_DIM);
    for (int g0 = 0; g0 < B_N; g0 += nbuf) {
        int gcnt = B_N - g0 < nbuf ? B_N - g0 : nbuf;
        // scores[z][s][t] = (Q.K^T)/sqrt(D), f32  (256 blocks/batch -> one XCD each)
        gemm_bt<2><<<dim3(16 * 16 * gcnt), 256, 0, stream>>>(
            Qb + (size_t)g0 * S_LEN * D_DIM, Kb + (size_t)g0 * S_LEN * D_DIM,
            512, 512, 512, 16, 16, nullptr, scores, S_LEN, sc,
            (long long)S_LEN * D_DIM, (long long)S_LEN * D_DIM,
            (long long)S_LEN * S_LEN, 0LL);
        // fused softmax: R = (1-g)*P_glob + g*P_loc, bf16 in place over scores
        softmax_fuse<<<dim3(S_LEN * gcnt), 256, 0, stream>>>(
            scores, gate + (size_t)g0 * S_LEN);
        // out = R * V  (single PV GEMM produces the final gated output, f32)
        gemm_bt<2><<<dim3(4 * 16 * gcnt), 256, 0, stream>>>(
            (const u16*)scores, Vt + (size_t)g0 * S_LEN,
            2 * S_LEN, M_TOT, S_LEN, 4, 16, nullptr,
            out + (size_t)g0 * S_LEN * D_DIM, 512, 1.f,
            (long long)S_LEN * 2 * S_LEN, (long long)S_LEN,
            (long long)S_LEN * D_DIM, 0LL);
    }
}

// Round 10
// 177.460 us; speedup vs baseline: 5.6794x; 1.0569x over previous
//
#include <hip/hip_runtime.h>
#include <math.h>

#define B_N   8
#define S_LEN 2048
#define D_DIM 512
#define M_TOT (B_N * S_LEN)   // 16384
#define WIN   30

typedef short bf16x8 __attribute__((ext_vector_type(8)));
typedef float f32x4  __attribute__((ext_vector_type(4)));
typedef unsigned short u16;
typedef unsigned int   u32;

__device__ __forceinline__ u16 f2bf(float f) {
    union { float f; u32 u; } v; v.f = f;
    u32 r = v.u + 0x7fffu + ((v.u >> 16) & 1u);
    return (u16)(r >> 16);
}
__device__ __forceinline__ float bf2f(u16 u) {
    union { u32 u; float f; } v; v.u = ((u32)u) << 16; return v.f;
}

__device__ __forceinline__ void gl2lds(const u16* g, u16* l) {
    __builtin_amdgcn_global_load_lds((const __attribute__((address_space(1))) void*)g,
                                     (__attribute__((address_space(3))) void*)l,
                                     16, 0, 0);
}

// bijective chunked XCD swizzle: hw block hb -> logical index such that
// XCD (hb%8) owns one contiguous logical chunk. Requires gridDim.x % 8 == 0.
__device__ __forceinline__ int xcd_logical() {
    const int n = gridDim.x;
    const int hb = blockIdx.x;
    return (hb & 7) * (n >> 3) + (hb >> 3);
}

// ---------------- fused convert + gate: Xb = bf16(X); gate = sigmoid(X.Wg+bg) ----------------
// one wave per row (grid M_TOT/4, 256 thr)
__global__ __launch_bounds__(256)
void convert_gate(const float* __restrict__ X, const float* __restrict__ Wg,
                  const float* __restrict__ bg, u16* __restrict__ Xb, float* __restrict__ gate) {
    int wv = threadIdx.x >> 6, lane = threadIdx.x & 63;
    int row = blockIdx.x * 4 + wv;
    const float4* x4 = (const float4*)(X + (size_t)row * D_DIM);
    const float4* w4 = (const float4*)Wg;
    float acc = 0.f;
    ushort4 o0, o1;
    {
        float4 a = x4[lane * 2], w = w4[lane * 2];
        acc += a.x * w.x + a.y * w.y + a.z * w.z + a.w * w.w;
        o0.x = f2bf(a.x); o0.y = f2bf(a.y); o0.z = f2bf(a.z); o0.w = f2bf(a.w);
        float4 b = x4[lane * 2 + 1], v = w4[lane * 2 + 1];
        acc += b.x * v.x + b.y * v.y + b.z * v.z + b.w * v.w;
        o1.x = f2bf(b.x); o1.y = f2bf(b.y); o1.z = f2bf(b.z); o1.w = f2bf(b.w);
    }
    ushort4* xb4 = (ushort4*)(Xb + (size_t)row * D_DIM);
    xb4[lane * 2] = o0;
    xb4[lane * 2 + 1] = o1;
#pragma unroll
    for (int o = 32; o; o >>= 1) acc += __shfl_xor(acc, o);
    if (lane == 0) gate[row] = 1.f / (1.f + __expf(-(acc + bg[0])));
}

// Wt3[z][n][k] = bf16(W_z[k][n]); grid (16,16,3)
__global__ __launch_bounds__(256) void transpose_w3(const float* __restrict__ Wq, const float* __restrict__ Wk,
                                                    const float* __restrict__ Wv, u16* __restrict__ Wt3) {
    const float* W = blockIdx.z == 0 ? Wq : (blockIdx.z == 1 ? Wk : Wv);
    u16* Wt = Wt3 + (size_t)blockIdx.z * D_DIM * D_DIM;
    __shared__ float t[32][33];
    int k0 = blockIdx.x * 32, n0 = blockIdx.y * 32;
    int tx = threadIdx.x & 31, ty = threadIdx.x >> 5;   // 32 x 8
#pragma unroll
    for (int r = ty; r < 32; r += 8) t[r][tx] = W[(size_t)(k0 + r) * D_DIM + n0 + tx];
    __syncthreads();
#pragma unroll
    for (int r = ty; r < 32; r += 8) Wt[(size_t)(n0 + r) * D_DIM + k0 + tx] = f2bf(t[tx][r]);
}

__global__ __launch_bounds__(256) void pack_bias(const float* __restrict__ bq, const float* __restrict__ bk,
                                                 const float* __restrict__ bv, float* __restrict__ b3) {
    int i = blockIdx.x * 256 + threadIdx.x;   // grid 2 -> i in [0,512)
    b3[i] = bq[i]; b3[512 + i] = bk[i]; b3[1024 + i] = bv[i];
}

// ---------------- the one GEMM: C = A * Bt^T, 1D grid, XCD-swizzled ----------------
// logical = x + nx*y + nx*ny*z  (x fastest, z slowest -> one batch per XCD chunk)
// A: bf16 [M][lda], Bt: bf16 [N][ldb]
// tile 128x128, BK=32, 4 waves (2x2), 16x16x32 bf16 MFMA, 4x4 frags/wave
// 3-BUFFER counted-vmcnt pipeline (T3+T4), 48 KB LDS -> 3 blocks/CU:
//   prologue: stage(0), stage(1)            (8 loads in flight)
//   iter t:   s_waitcnt vmcnt(4)            (drain ONLY tile t)
//             s_barrier + fence
//             stage(t+2) into buf[(t+2)%3]  (WAR-safe: last read at compute(t-1),
//                                            finished by all waves pre-barrier)
//             compute(buf[t%3])
//   tail:     vmcnt(0), barrier, compute(nt-1)
// LDS k-slot XOR swizzle (slot ^= (row>>1)&3): pre-swizzled global source
// (gl2lds dest stays linear) + swizzled ds_read slot -> zero bank conflicts.
// EPI 0: bf16 out + col bias | 1: bf16 out + row bias | 2: f32 out * scale | 3: bf16 out * scale
#define VM_WAIT(N) asm volatile("s_waitcnt vmcnt(" #N ")" ::: "memory")
#define BAR() do { __builtin_amdgcn_s_barrier(); asm volatile("" ::: "memory"); } while (0)

template<int EPI>
__global__ __launch_bounds__(256, 6)
void gemm_bt(const u16* __restrict__ A, const u16* __restrict__ Bt,
             int lda, int ldb, int K, int nx, int ny,
             const float* __restrict__ aux, void* __restrict__ Cv, int ldc, float scale,
             long long zA, long long zB, long long zC, long long zAux) {
    const int logical = xcd_logical();
    const int x = logical % nx;
    const int t2 = logical / nx;
    const int y = t2 % ny;
    const int z = t2 / ny;

    A   += zA * z;
    Bt  += zB * z;
    if (aux) aux += zAux * z;

    __shared__ u16 smem[3 * 8192];     // 3 buffers x (A 4096 + B 4096) u16 = 48 KB
    const int tid  = threadIdx.x;
    const int lane = tid & 63;
    const int wave = tid >> 6;
    const int wr = wave >> 1, wc = wave & 1;
    const int m0 = y * 128, n0 = x * 128;

    f32x4 acc[4][4];
#pragma unroll
    for (int i = 0; i < 4; i++)
#pragma unroll
        for (int j = 0; j < 4; j++) acc[i][j] = (f32x4){0.f, 0.f, 0.f, 0.f};

    // staging: chunk c (16B) -> LDS linear offset c*16B = (row=c>>2, slot=c&3);
    // global k-slot loaded = slot ^ ((row>>1)&3) = (c&3)^((c>>3)&3)  [swizzle]
    const int c0 = tid, c1 = tid + 256;
    const int r0c = c0 >> 2, k0c = (((c0 & 3) ^ ((c0 >> 3) & 3)) << 3);
    const int r1c = c1 >> 2, k1c = (((c1 & 3) ^ ((c1 >> 3) & 3)) << 3);

    auto stage = [&](int b, int k0) {
        u16* dA = smem + b * 8192 + wave * 512;
        u16* dB = smem + b * 8192 + 4096 + wave * 512;
        gl2lds(A + (size_t)(m0 + r0c) * lda + (k0 + k0c), dA);
        gl2lds(A + (size_t)(m0 + r1c) * lda + (k0 + k1c), dA + 2048);
        gl2lds(Bt + (size_t)(n0 + r0c) * ldb + (k0 + k0c), dB);
        gl2lds(Bt + (size_t)(n0 + r1c) * ldb + (k0 + k1c), dB + 2048);
    };
    auto compute = [&](int b) {
        const u16* bA = smem + b * 8192;
        const u16* bB = smem + b * 8192 + 4096;
        const int ks = lane >> 4;
        bf16x8 af[4], bfr[4];
#pragma unroll
        for (int m = 0; m < 4; m++) {
            int r = wr * 64 + m * 16 + (lane & 15);
            int s = ks ^ ((r >> 1) & 3);
            af[m] = *(const bf16x8*)&bA[r * 32 + s * 8];
        }
#pragma unroll
        for (int n = 0; n < 4; n++) {
            int r = wc * 64 + n * 16 + (lane & 15);
            int s = ks ^ ((r >> 1) & 3);
            bfr[n] = *(const bf16x8*)&bB[r * 32 + s * 8];
        }
#pragma unroll
        for (int m = 0; m < 4; m++)
#pragma unroll
            for (int n = 0; n < 4; n++)
                acc[m][n] = __builtin_amdgcn_mfma_f32_16x16x32_bf16(af[m], bfr[n], acc[m][n], 0, 0, 0);
    };

    const int nt = K >> 5;   // >= 4 for all call sites (K in {512, 2048})
    stage(0, 0); stage(1, 32);   // 8 loads in flight

    int t = 0;
    for (; t < nt - 1; ++t) {
        VM_WAIT(4);            // drain tile t only (tile t+1's 4 loads stay in flight)
        BAR();
        if (t + 2 < nt) stage((t + 2) % 3, (t + 2) << 5);
        compute(t % 3);
    }
    VM_WAIT(0);                // drain tile nt-1
    BAR();
    compute((nt - 1) % 3);

    u16*   Cb = (EPI != 2) ? ((u16*)Cv + zC * z) : nullptr;
    float* Cf = (EPI == 2) ? ((float*)Cv + zC * z) : nullptr;

    // epilogue: C/D map row=(lane>>4)*4+reg, col=lane&15  [verified m89]
#pragma unroll
    for (int m = 0; m < 4; m++) {
        int rbase = m0 + wr * 64 + m * 16 + ((lane >> 4) << 2);
#pragma unroll
        for (int n = 0; n < 4; n++) {
            int col = n0 + wc * 64 + n * 16 + (lane & 15);
#pragma unroll
            for (int rg = 0; rg < 4; rg++) {
                int row = rbase + rg;
                float v = acc[m][n][rg];
                if (EPI == 0) {
                    Cb[(size_t)row * ldc + col] = f2bf(v + aux[col]);
                } else if (EPI == 1) {
                    Cb[(size_t)row * ldc + col] = f2bf(v + aux[row]);
                } else if (EPI == 2) {
                    Cf[(size_t)row * ldc + col] = v * scale;
                } else {
                    Cb[(size_t)row * ldc + col] = f2bf(v * scale);
                }
            }
        }
    }
}

// ---------------- fused softmax: R = (1-g)*P_glob + g*P_loc, bf16 in place ----------------
// 1D grid (S_LEN * gcnt), XCD-swizzled. Reads the bf16 scores row (4 KB), computes
// both softmaxes' stats in f32, writes the COMBINED gated probability row R as bf16
// in place. The PV GEMM then produces the final output directly.
__global__ __launch_bounds__(256)
void softmax_fuse(u16* __restrict__ sc, const float* __restrict__ gate) {
    const int logical = xcd_logical();
    const int i = logical & (S_LEN - 1);
    const int z = logical >> 11;
    const int tid = threadIdx.x;
    const int wv = tid >> 6, lane = tid & 63;
    sc   += (size_t)z * S_LEN * S_LEN;
    gate += (size_t)z * S_LEN;

    __shared__ float r0[4], r1[4], mll[2];

    u16* scrow = sc + (size_t)i * S_LEN;
    uint4 raw = ((const uint4*)scrow)[tid];   // 8 bf16 scores

    // band bounds; band scores read pre-barrier (in-row only, no cross-block hazard)
    int jlo = i - WIN; if (jlo < 0) jlo = 0;
    int jhi = i + WIN; if (jhi > S_LEN - 1) jhi = S_LEN - 1;
    int cnt = jhi - jlo + 1;
    float bvv = (tid < cnt) ? bf2f(scrow[jlo + tid]) : -3.0e38f;
    float g = gate[i];

    float sv[8];
    sv[0] = bf2f((u16)(raw.x & 0xffff)); sv[1] = bf2f((u16)(raw.x >> 16));
    sv[2] = bf2f((u16)(raw.y & 0xffff)); sv[3] = bf2f((u16)(raw.y >> 16));
    sv[4] = bf2f((u16)(raw.z & 0xffff)); sv[5] = bf2f((u16)(raw.z >> 16));
    sv[6] = bf2f((u16)(raw.w & 0xffff)); sv[7] = bf2f((u16)(raw.w >> 16));

    // global row max
    float mx = fmaxf(fmaxf(fmaxf(sv[0], sv[1]), fmaxf(sv[2], sv[3])),
                     fmaxf(fmaxf(sv[4], sv[5]), fmaxf(sv[6], sv[7])));
#pragma unroll
    for (int o = 32; o; o >>= 1) mx = fmaxf(mx, __shfl_xor(mx, o));
    if (lane == 0) r0[wv] = mx;
    __syncthreads();
    float mg = fmaxf(fmaxf(r0[0], r0[1]), fmaxf(r0[2], r0[3]));

    float ev[8];
#pragma unroll
    for (int k = 0; k < 8; k++) ev[k] = __expf(sv[k] - mg);
    float se = ev[0] + ev[1] + ev[2] + ev[3] + ev[4] + ev[5] + ev[6] + ev[7];
#pragma unroll
    for (int o = 32; o; o >>= 1) se += __shfl_xor(se, o);
    if (lane == 0) r1[wv] = se;

    // band softmax stats: wave 0 alone (cnt <= 61, register-resident)
    if (wv == 0) {
        float ml = bvv;
#pragma unroll
        for (int o = 32; o; o >>= 1) ml = fmaxf(ml, __shfl_xor(ml, o));
        float e = (lane < cnt) ? __expf(bvv - ml) : 0.f;
        float s2 = e;
#pragma unroll
        for (int o = 32; o; o >>= 1) s2 += __shfl_xor(s2, o);
        if (lane == 0) { mll[0] = ml; mll[1] = 1.f / s2; }
    }
    __syncthreads();
    float invl = (1.f - g) / (r1[0] + r1[1] + r1[2] + r1[3]);
    float ml  = mll[0];
    float ill = g * mll[1];

    // R[col] = (1-g)*exp(s-mg)/lg + [|col-i|<=WIN] * g*exp(s-ml)/ll, bf16 in place
    const int c0 = tid * 8;
    u32 pk_[4];
#pragma unroll
    for (int h = 0; h < 4; h++) {
        float rA = ev[2 * h] * invl;
        float rB = ev[2 * h + 1] * invl;
        int colA = c0 + 2 * h;
        if ((u32)(colA - i + WIN) <= 2u * WIN)     rA += __expf(sv[2 * h] - ml) * ill;
        if ((u32)(colA + 1 - i + WIN) <= 2u * WIN) rB += __expf(sv[2 * h + 1] - ml) * ill;
        pk_[h] = (u32)f2bf(rA) | ((u32)f2bf(rB) << 16);
    }
    uint4 pw = {pk_[0], pk_[1], pk_[2], pk_[3]};
    ((uint4*)scrow)[tid] = pw;   // post-barrier: all row reads drained at barrier
}

// ---------------- launch ----------------
extern "C" void kernel_launch(void* const* d_in, const int* in_sizes, int n_in,
                              void* d_out, int out_size, void* d_ws, size_t ws_size,
                              hipStream_t stream) {
    const float* X  = (const float*)d_in[0];
    const float* Wq = (const float*)d_in[1];
    const float* bq = (const float*)d_in[2];
    const float* Wk = (const float*)d_in[3];
    const float* bk = (const float*)d_in[4];
    const float* Wv = (const float*)d_in[5];
    const float* bv = (const float*)d_in[6];
    const float* Wg = (const float*)d_in[7];
    const float* bg = (const float*)d_in[8];
    float* out = (float*)d_out;

    char* p = (char*)d_ws;
    u16* Xb    = (u16*)p;  p += (size_t)M_TOT * D_DIM * 2;           // 16 MB
    u16* Wt3   = (u16*)p;  p += (size_t)3 * D_DIM * D_DIM * 2;       // 1.5 MB
    u16* QKV   = (u16*)p;  p += (size_t)2 * M_TOT * D_DIM * 2;       // 32 MB (Q,K only)
    u16* Vt    = (u16*)p;  p += (size_t)M_TOT * D_DIM * 2;           // 16 MB
    float* gate  = (float*)p; p += (size_t)M_TOT * 4;                // 64 KB
    float* bias3 = (float*)p; p += (size_t)3 * D_DIM * 4;            // 6 KB
    u16* scores = (u16*)p;                                           // nbuf * 8 MB (bf16)
    size_t base_used = (size_t)(p - (char*)d_ws);
    size_t per_batch = (size_t)S_LEN * S_LEN * 2;
    int nbuf = (int)((ws_size - base_used) / per_batch);
    if (nbuf > B_N) nbuf = B_N;
    if (nbuf < 1) nbuf = 1;

    u16* Qb = QKV;
    u16* Kb = QKV + (size_t)M_TOT * D_DIM;

    convert_gate<<<dim3(M_TOT / 4), 256, 0, stream>>>(X, Wg, bg, Xb, gate);
    transpose_w3<<<dim3(16, 16, 3), 256, 0, stream>>>(Wq, Wk, Wv, Wt3);
    pack_bias<<<dim3(2), 256, 0, stream>>>(bq, bk, bv, bias3);

    // Q/K projections in one dispatch: z selects weight/bias/output (1024 blocks).
    // (V itself is dead — only Vt is consumed by the PV GEMM.)
    gemm_bt<0><<<dim3(4 * 128 * 2), 256, 0, stream>>>(
        Xb, Wt3, 512, 512, 512, 4, 128, bias3, QKV, 512, 1.f,
        0LL, (long long)D_DIM * D_DIM, (long long)M_TOT * D_DIM, (long long)D_DIM);

    // Vt[d][t_global] = (Wv^T X^T) + bv[d]   (512 blocks)
    gemm_bt<1><<<dim3(128 * 4), 256, 0, stream>>>(
        Wt3 + (size_t)2 * D_DIM * D_DIM, Xb, 512, 512, 512, 128, 4, bv, Vt, M_TOT, 1.f,
        0LL, 0LL, 0LL, 0LL);

    const float sc = 1.0f / sqrtf((float)D_DIM);
    for (int g0 = 0; g0 < B_N; g0 += nbuf) {
        int gcnt = B_N - g0 < nbuf ? B_N - g0 : nbuf;
        // scores[z][s][t] = bf16((Q.K^T)/sqrt(D))  (256 blocks/batch -> one XCD each)
        gemm_bt<3><<<dim3(16 * 16 * gcnt), 256, 0, stream>>>(
            Qb + (size_t)g0 * S_LEN * D_DIM, Kb + (size_t)g0 * S_LEN * D_DIM,
            512, 512, 512, 16, 16, nullptr, scores, S_LEN, sc,
            (long long)S_LEN * D_DIM, (long long)S_LEN * D_DIM,
            (long long)S_LEN * S_LEN, 0LL);
        // fused softmax: R = (1-g)*P_glob + g*P_loc, bf16 in place over scores
        softmax_fuse<<<dim3(S_LEN * gcnt), 256, 0, stream>>>(
            scores, gate + (size_t)g0 * S_LEN);
        // out = R * V  (single PV GEMM produces the final gated output, f32)
        gemm_bt<2><<<dim3(4 * 16 * gcnt), 256, 0, stream>>>(
            scores, Vt + (size_t)g0 * S_LEN,
            S_LEN, M_TOT, S_LEN, 4, 16, nullptr,
            out + (size_t)g0 * S_LEN * D_DIM, 512, 1.f,
            (long long)S_LEN * S_LEN, (long long)S_LEN,
            (long long)S_LEN * D_DIM, 0LL);
    }
}

// Round 11
// 174.138 us; speedup vs baseline: 5.7877x; 1.0191x over previous
//
#include <hip/hip_runtime.h>
#include <math.h>

#define B_N   8
#define S_LEN 2048
#define D_DIM 512
#define M_TOT (B_N * S_LEN)   // 16384
#define WIN   30

typedef short bf16x8 __attribute__((ext_vector_type(8)));
typedef float f32x4  __attribute__((ext_vector_type(4)));
typedef unsigned short u16;
typedef unsigned int   u32;

__device__ __forceinline__ u16 f2bf(float f) {
    union { float f; u32 u; } v; v.f = f;
    u32 r = v.u + 0x7fffu + ((v.u >> 16) & 1u);
    return (u16)(r >> 16);
}
__device__ __forceinline__ float bf2f(u16 u) {
    union { u32 u; float f; } v; v.u = ((u32)u) << 16; return v.f;
}

__device__ __forceinline__ void gl2lds(const u16* g, u16* l) {
    __builtin_amdgcn_global_load_lds((const __attribute__((address_space(1))) void*)g,
                                     (__attribute__((address_space(3))) void*)l,
                                     16, 0, 0);
}

// bijective chunked XCD swizzle: hw block hb -> logical index such that
// XCD (hb%8) owns one contiguous logical chunk. Requires gridDim.x % 8 == 0.
__device__ __forceinline__ int xcd_logical() {
    const int n = gridDim.x;
    const int hb = blockIdx.x;
    return (hb & 7) * (n >> 3) + (hb >> 3);
}

// ---------------- fused convert + gate: Xb = bf16(X); gate = sigmoid(X.Wg+bg) ----------------
// one wave per row (grid M_TOT/4, 256 thr)
__global__ __launch_bounds__(256)
void convert_gate(const float* __restrict__ X, const float* __restrict__ Wg,
                  const float* __restrict__ bg, u16* __restrict__ Xb, float* __restrict__ gate) {
    int wv = threadIdx.x >> 6, lane = threadIdx.x & 63;
    int row = blockIdx.x * 4 + wv;
    const float4* x4 = (const float4*)(X + (size_t)row * D_DIM);
    const float4* w4 = (const float4*)Wg;
    float acc = 0.f;
    ushort4 o0, o1;
    {
        float4 a = x4[lane * 2], w = w4[lane * 2];
        acc += a.x * w.x + a.y * w.y + a.z * w.z + a.w * w.w;
        o0.x = f2bf(a.x); o0.y = f2bf(a.y); o0.z = f2bf(a.z); o0.w = f2bf(a.w);
        float4 b = x4[lane * 2 + 1], v = w4[lane * 2 + 1];
        acc += b.x * v.x + b.y * v.y + b.z * v.z + b.w * v.w;
        o1.x = f2bf(b.x); o1.y = f2bf(b.y); o1.z = f2bf(b.z); o1.w = f2bf(b.w);
    }
    ushort4* xb4 = (ushort4*)(Xb + (size_t)row * D_DIM);
    xb4[lane * 2] = o0;
    xb4[lane * 2 + 1] = o1;
#pragma unroll
    for (int o = 32; o; o >>= 1) acc += __shfl_xor(acc, o);
    if (lane == 0) gate[row] = 1.f / (1.f + __expf(-(acc + bg[0])));
}

// Wt3[z][n][k] = bf16(W_z[k][n]); grid (16,16,3)
__global__ __launch_bounds__(256) void transpose_w3(const float* __restrict__ Wq, const float* __restrict__ Wk,
                                                    const float* __restrict__ Wv, u16* __restrict__ Wt3) {
    const float* W = blockIdx.z == 0 ? Wq : (blockIdx.z == 1 ? Wk : Wv);
    u16* Wt = Wt3 + (size_t)blockIdx.z * D_DIM * D_DIM;
    __shared__ float t[32][33];
    int k0 = blockIdx.x * 32, n0 = blockIdx.y * 32;
    int tx = threadIdx.x & 31, ty = threadIdx.x >> 5;   // 32 x 8
#pragma unroll
    for (int r = ty; r < 32; r += 8) t[r][tx] = W[(size_t)(k0 + r) * D_DIM + n0 + tx];
    __syncthreads();
#pragma unroll
    for (int r = ty; r < 32; r += 8) Wt[(size_t)(n0 + r) * D_DIM + k0 + tx] = f2bf(t[tx][r]);
}

__global__ __launch_bounds__(256) void pack_bias(const float* __restrict__ bq, const float* __restrict__ bk,
                                                 const float* __restrict__ bv, float* __restrict__ b3) {
    int i = blockIdx.x * 256 + threadIdx.x;   // grid 2 -> i in [0,512)
    b3[i] = bq[i]; b3[512 + i] = bk[i]; b3[1024 + i] = bv[i];
}

// ---------------- the one GEMM: C = A * Bt^T, 1D grid, XCD-swizzled ----------------
// logical = x + nx*y + nx*ny*z  (x fastest, z slowest -> one batch per XCD chunk)
// A: bf16 [M][lda], Bt: bf16 [N][ldb]
// Block tile (32*MFR) x 128, 4 waves (2x2), wave tile (16*MFR) x 64, BK=32.
//   MFR=4: 128x128, 48 KB LDS, 3 blocks/CU (proven).
//   MFR=8: 256x128, 72 KB LDS, 2 blocks/CU — 1.37x FLOP per LDS byte
//          (12 KB ds_read feeds 32 MFMA/wave/K-step), rebalances the
//          LDS-read-throughput bottleneck vs the matrix pipe.
// 3-BUFFER counted-vmcnt pipeline (T3+T4):
//   prologue: stage(0), stage(1)            (2L loads in flight)
//   iter t:   s_waitcnt vmcnt(L)            (drain ONLY tile t)
//             s_barrier + fence
//             stage(t+2) into buf[(t+2)%3]  (WAR-safe)
//             compute(buf[t%3])
//   tail:     vmcnt(0), barrier, compute(nt-1)
// LDS k-slot XOR swizzle (slot ^= (row>>1)&3): pre-swizzled global source
// (gl2lds dest stays linear) + swizzled ds_read slot -> zero bank conflicts.
// EPI 0: bf16 out + col bias | 1: bf16 out + row bias | 2: f32 out * scale | 3: bf16 out * scale
#define VM_WAIT(N) asm volatile("s_waitcnt vmcnt(" #N ")" ::: "memory")
#define BAR() do { __builtin_amdgcn_s_barrier(); asm volatile("" ::: "memory"); } while (0)

template<int EPI, int MFR>
__global__ __launch_bounds__(256, (MFR == 8 ? 2 : 6))
void gemm_bt(const u16* __restrict__ A, const u16* __restrict__ Bt,
             int lda, int ldb, int K, int nx, int ny,
             const float* __restrict__ aux, void* __restrict__ Cv, int ldc, float scale,
             long long zA, long long zB, long long zC, long long zAux) {
    constexpr int BM     = 32 * MFR;           // block rows
    constexpr int BUFU16 = (BM + 128) * 32;    // u16 per buffer (A then B)
    constexpr int L      = (BM + 128) / 64;    // gl2lds per thread per stage (4 or 6)

    const int logical = xcd_logical();
    const int x = logical % nx;
    const int t2 = logical / nx;
    const int y = t2 % ny;
    const int z = t2 / ny;

    A   += zA * z;
    Bt  += zB * z;
    if (aux) aux += zAux * z;

    __shared__ u16 smem[3 * BUFU16];
    const int tid  = threadIdx.x;
    const int lane = tid & 63;
    const int wave = tid >> 6;
    const int wr = wave >> 1, wc = wave & 1;
    const int m0 = y * BM, n0 = x * 128;

    f32x4 acc[MFR][4];
#pragma unroll
    for (int i = 0; i < MFR; i++)
#pragma unroll
        for (int j = 0; j < 4; j++) acc[i][j] = (f32x4){0.f, 0.f, 0.f, 0.f};

    // staging: chunk c (16B) -> LDS linear offset c*16B = (row=c>>2, slot=c&3);
    // global k-slot loaded = (c&3)^((row>>1)&3)  [swizzle]; rows [0,BM) = A,
    // rows [BM,BM+128) = B. Per-j branch is compile-time (256 | BM*4).
    auto stage = [&](int b, int k0) {
        u16* base = smem + b * BUFU16 + wave * 512;
#pragma unroll
        for (int j = 0; j < L; j++) {
            int c = j * 256 + tid;
            int r = c >> 2;
            int s = ((c & 3) ^ ((c >> 3) & 3)) << 3;
            const u16* src = (j * 256 < BM * 4)
                ? A  + (size_t)(m0 + r) * lda + (k0 + s)
                : Bt + (size_t)(n0 + (r - BM)) * ldb + (k0 + s);
            gl2lds(src, base + j * 2048);
        }
    };
    auto compute = [&](int b) {
        const u16* bA = smem + b * BUFU16;
        const u16* bB = smem + b * BUFU16 + BM * 32;
        const int ks = lane >> 4;
        bf16x8 af[MFR], bfr[4];
#pragma unroll
        for (int m = 0; m < MFR; m++) {
            int r = wr * (16 * MFR) + m * 16 + (lane & 15);
            int s = ks ^ ((r >> 1) & 3);
            af[m] = *(const bf16x8*)&bA[r * 32 + s * 8];
        }
#pragma unroll
        for (int n = 0; n < 4; n++) {
            int r = wc * 64 + n * 16 + (lane & 15);
            int s = ks ^ ((r >> 1) & 3);
            bfr[n] = *(const bf16x8*)&bB[r * 32 + s * 8];
        }
#pragma unroll
        for (int m = 0; m < MFR; m++)
#pragma unroll
            for (int n = 0; n < 4; n++)
                acc[m][n] = __builtin_amdgcn_mfma_f32_16x16x32_bf16(af[m], bfr[n], acc[m][n], 0, 0, 0);
    };

    const int nt = K >> 5;   // >= 4 for all call sites (K in {512, 2048})
    stage(0, 0); stage(1, 32);   // 2L loads in flight

    int t = 0;
    for (; t < nt - 1; ++t) {
        if constexpr (L == 4) VM_WAIT(4); else VM_WAIT(6);   // drain tile t only
        BAR();
        if (t + 2 < nt) stage((t + 2) % 3, (t + 2) << 5);
        compute(t % 3);
    }
    VM_WAIT(0);                // drain tile nt-1
    BAR();
    compute((nt - 1) % 3);

    u16*   Cb = (EPI != 2) ? ((u16*)Cv + zC * z) : nullptr;
    float* Cf = (EPI == 2) ? ((float*)Cv + zC * z) : nullptr;

    // epilogue: C/D map row=(lane>>4)*4+reg, col=lane&15  [verified m89]
#pragma unroll
    for (int m = 0; m < MFR; m++) {
        int rbase = m0 + wr * (16 * MFR) + m * 16 + ((lane >> 4) << 2);
#pragma unroll
        for (int n = 0; n < 4; n++) {
            int col = n0 + wc * 64 + n * 16 + (lane & 15);
#pragma unroll
            for (int rg = 0; rg < 4; rg++) {
                int row = rbase + rg;
                float v = acc[m][n][rg];
                if (EPI == 0) {
                    Cb[(size_t)row * ldc + col] = f2bf(v + aux[col]);
                } else if (EPI == 1) {
                    Cb[(size_t)row * ldc + col] = f2bf(v + aux[row]);
                } else if (EPI == 2) {
                    Cf[(size_t)row * ldc + col] = v * scale;
                } else {
                    Cb[(size_t)row * ldc + col] = f2bf(v * scale);
                }
            }
        }
    }
}

// ---------------- fused softmax: R = (1-g)*P_glob + g*P_loc, bf16 in place ----------------
// 1D grid (S_LEN * gcnt), XCD-swizzled. Reads the bf16 scores row (4 KB), computes
// both softmaxes' stats in f32, writes the COMBINED gated probability row R as bf16
// in place. The PV GEMM then produces the final output directly.
__global__ __launch_bounds__(256)
void softmax_fuse(u16* __restrict__ sc, const float* __restrict__ gate) {
    const int logical = xcd_logical();
    const int i = logical & (S_LEN - 1);
    const int z = logical >> 11;
    const int tid = threadIdx.x;
    const int wv = tid >> 6, lane = tid & 63;
    sc   += (size_t)z * S_LEN * S_LEN;
    gate += (size_t)z * S_LEN;

    __shared__ float r0[4], r1[4], mll[2];

    u16* scrow = sc + (size_t)i * S_LEN;
    uint4 raw = ((const uint4*)scrow)[tid];   // 8 bf16 scores

    // band bounds; band scores read pre-barrier (in-row only, no cross-block hazard)
    int jlo = i - WIN; if (jlo < 0) jlo = 0;
    int jhi = i + WIN; if (jhi > S_LEN - 1) jhi = S_LEN - 1;
    int cnt = jhi - jlo + 1;
    float bvv = (tid < cnt) ? bf2f(scrow[jlo + tid]) : -3.0e38f;
    float g = gate[i];

    float sv[8];
    sv[0] = bf2f((u16)(raw.x & 0xffff)); sv[1] = bf2f((u16)(raw.x >> 16));
    sv[2] = bf2f((u16)(raw.y & 0xffff)); sv[3] = bf2f((u16)(raw.y >> 16));
    sv[4] = bf2f((u16)(raw.z & 0xffff)); sv[5] = bf2f((u16)(raw.z >> 16));
    sv[6] = bf2f((u16)(raw.w & 0xffff)); sv[7] = bf2f((u16)(raw.w >> 16));

    // global row max
    float mx = fmaxf(fmaxf(fmaxf(sv[0], sv[1]), fmaxf(sv[2], sv[3])),
                     fmaxf(fmaxf(sv[4], sv[5]), fmaxf(sv[6], sv[7])));
#pragma unroll
    for (int o = 32; o; o >>= 1) mx = fmaxf(mx, __shfl_xor(mx, o));
    if (lane == 0) r0[wv] = mx;
    __syncthreads();
    float mg = fmaxf(fmaxf(r0[0], r0[1]), fmaxf(r0[2], r0[3]));

    float ev[8];
#pragma unroll
    for (int k = 0; k < 8; k++) ev[k] = __expf(sv[k] - mg);
    float se = ev[0] + ev[1] + ev[2] + ev[3] + ev[4] + ev[5] + ev[6] + ev[7];
#pragma unroll
    for (int o = 32; o; o >>= 1) se += __shfl_xor(se, o);
    if (lane == 0) r1[wv] = se;

    // band softmax stats: wave 0 alone (cnt <= 61, register-resident)
    if (wv == 0) {
        float ml = bvv;
#pragma unroll
        for (int o = 32; o; o >>= 1) ml = fmaxf(ml, __shfl_xor(ml, o));
        float e = (lane < cnt) ? __expf(bvv - ml) : 0.f;
        float s2 = e;
#pragma unroll
        for (int o = 32; o; o >>= 1) s2 += __shfl_xor(s2, o);
        if (lane == 0) { mll[0] = ml; mll[1] = 1.f / s2; }
    }
    __syncthreads();
    float invl = (1.f - g) / (r1[0] + r1[1] + r1[2] + r1[3]);
    float ml  = mll[0];
    float ill = g * mll[1];

    // R[col] = (1-g)*exp(s-mg)/lg + [|col-i|<=WIN] * g*exp(s-ml)/ll, bf16 in place
    const int c0 = tid * 8;
    u32 pk_[4];
#pragma unroll
    for (int h = 0; h < 4; h++) {
        float rA = ev[2 * h] * invl;
        float rB = ev[2 * h + 1] * invl;
        int colA = c0 + 2 * h;
        if ((u32)(colA - i + WIN) <= 2u * WIN)     rA += __expf(sv[2 * h] - ml) * ill;
        if ((u32)(colA + 1 - i + WIN) <= 2u * WIN) rB += __expf(sv[2 * h + 1] - ml) * ill;
        pk_[h] = (u32)f2bf(rA) | ((u32)f2bf(rB) << 16);
    }
    uint4 pw = {pk_[0], pk_[1], pk_[2], pk_[3]};
    ((uint4*)scrow)[tid] = pw;   // post-barrier: all row reads drained at barrier
}

// ---------------- launch ----------------
extern "C" void kernel_launch(void* const* d_in, const int* in_sizes, int n_in,
                              void* d_out, int out_size, void* d_ws, size_t ws_size,
                              hipStream_t stream) {
    const float* X  = (const float*)d_in[0];
    const float* Wq = (const float*)d_in[1];
    const float* bq = (const float*)d_in[2];
    const float* Wk = (const float*)d_in[3];
    const float* bk = (const float*)d_in[4];
    const float* Wv = (const float*)d_in[5];
    const float* bv = (const float*)d_in[6];
    const float* Wg = (const float*)d_in[7];
    const float* bg = (const float*)d_in[8];
    float* out = (float*)d_out;

    char* p = (char*)d_ws;
    u16* Xb    = (u16*)p;  p += (size_t)M_TOT * D_DIM * 2;           // 16 MB
    u16* Wt3   = (u16*)p;  p += (size_t)3 * D_DIM * D_DIM * 2;       // 1.5 MB
    u16* QKV   = (u16*)p;  p += (size_t)2 * M_TOT * D_DIM * 2;       // 32 MB (Q,K only)
    u16* Vt    = (u16*)p;  p += (size_t)M_TOT * D_DIM * 2;           // 16 MB
    float* gate  = (float*)p; p += (size_t)M_TOT * 4;                // 64 KB
    float* bias3 = (float*)p; p += (size_t)3 * D_DIM * 4;            // 6 KB
    u16* scores = (u16*)p;                                           // nbuf * 8 MB (bf16)
    size_t base_used = (size_t)(p - (char*)d_ws);
    size_t per_batch = (size_t)S_LEN * S_LEN * 2;
    int nbuf = (int)((ws_size - base_used) / per_batch);
    if (nbuf > B_N) nbuf = B_N;
    if (nbuf < 1) nbuf = 1;

    u16* Qb = QKV;
    u16* Kb = QKV + (size_t)M_TOT * D_DIM;

    convert_gate<<<dim3(M_TOT / 4), 256, 0, stream>>>(X, Wg, bg, Xb, gate);
    transpose_w3<<<dim3(16, 16, 3), 256, 0, stream>>>(Wq, Wk, Wv, Wt3);
    pack_bias<<<dim3(2), 256, 0, stream>>>(bq, bk, bv, bias3);

    // Q/K projections in one dispatch, 256x128 tile: z selects weight/bias/output.
    // (V itself is dead — only Vt is consumed by the PV GEMM.)  512 blocks.
    gemm_bt<0, 8><<<dim3(4 * 64 * 2), 256, 0, stream>>>(
        Xb, Wt3, 512, 512, 512, 4, 64, bias3, QKV, 512, 1.f,
        0LL, (long long)D_DIM * D_DIM, (long long)M_TOT * D_DIM, (long long)D_DIM);

    // Vt[d][t_global] = (Wv^T X^T) + bv[d]   (512 blocks, 128x128)
    gemm_bt<1, 4><<<dim3(128 * 4), 256, 0, stream>>>(
        Wt3 + (size_t)2 * D_DIM * D_DIM, Xb, 512, 512, 512, 128, 4, bv, Vt, M_TOT, 1.f,
        0LL, 0LL, 0LL, 0LL);

    const float sc = 1.0f / sqrtf((float)D_DIM);
    for (int g0 = 0; g0 < B_N; g0 += nbuf) {
        int gcnt = B_N - g0 < nbuf ? B_N - g0 : nbuf;
        // scores[z][s][t] = bf16((Q.K^T)/sqrt(D)), 256x128 tile
        // (128 blocks/batch -> one XCD each at gcnt=8)
        gemm_bt<3, 8><<<dim3(16 * 8 * gcnt), 256, 0, stream>>>(
            Qb + (size_t)g0 * S_LEN * D_DIM, Kb + (size_t)g0 * S_LEN * D_DIM,
            512, 512, 512, 16, 8, nullptr, scores, S_LEN, sc,
            (long long)S_LEN * D_DIM, (long long)S_LEN * D_DIM,
            (long long)S_LEN * S_LEN, 0LL);
        // fused softmax: R = (1-g)*P_glob + g*P_loc, bf16 in place over scores
        softmax_fuse<<<dim3(S_LEN * gcnt), 256, 0, stream>>>(
            scores, gate + (size_t)g0 * S_LEN);
        // out = R * V  (single PV GEMM produces the final gated output, f32)
        gemm_bt<2, 4><<<dim3(4 * 16 * gcnt), 256, 0, stream>>>(
            scores, Vt + (size_t)g0 * S_LEN,
            S_LEN, M_TOT, S_LEN, 4, 16, nullptr,
            out + (size_t)g0 * S_LEN * D_DIM, 512, 1.f,
            (long long)S_LEN * S_LEN, (long long)S_LEN,
            (long long)S_LEN * D_DIM, 0LL);
    }
}